// Round 6
// baseline (349.051 us; speedup 1.0000x reference)
//
#include <hip/hip_runtime.h>
#include <hip/hip_bf16.h>
#include <math.h>

// Problem constants
#define TT 32
#define NN 512
#define DD 128
#define FF_ 2048
#define HH 8
#define LL 2
#define WND_ 8
#define TOK (TT*NN)          // 16384 tokens
#define DH 16                // head dim

typedef __hip_bfloat16 bf16;
typedef __attribute__((ext_vector_type(8))) short bf16x8;   // 8 bf16 (4 VGPRs)
typedef __attribute__((ext_vector_type(4))) float f32x4;    // 4 fp32

// global_load_lds: 16B per lane, LDS dest = wave-uniform base + lane*16 (linear)
#define GLD_LDS16(gp, lp) __builtin_amdgcn_global_load_lds( \
    (const __attribute__((address_space(1))) unsigned int*)(gp), \
    (__attribute__((address_space(3))) unsigned int*)(lp), 16, 0, 0)

#define MFMA16(a, b, c) __builtin_amdgcn_mfma_f32_16x16x32_bf16((a), (b), (c), 0, 0, 0)

__device__ inline short f2bs(float f) {
    __hip_bfloat16 h = __float2bfloat16(f);
    return *reinterpret_cast<short*>(&h);
}

// ---------------------------------------------------------------------------
// bf16 MFMA GEMM: C[M,N] = A[M,K] @ W[N,K]^T + bias (+relu). Output bf16.
// Tile BM x BN, BK=32, 256 threads = 4 waves in 2x2.
// ---------------------------------------------------------------------------
template<int BM, int BN>
__global__ __launch_bounds__(256) void mfma_gemm(
    const bf16* __restrict__ A, int lda,
    const bf16* __restrict__ W,              // [N,K] row-major (= B^T)
    const float* __restrict__ bias,          // [N]
    bf16* __restrict__ C, int ldc,
    int K, int relu)
{
    constexpr int WM = BM / 2, WN = BN / 2;
    constexpr int FM = WM / 16, FN = WN / 16;
    constexpr int LA = (BM * 64) / (256 * 16);
    constexpr int LB = (BN * 64) / (256 * 16);

    __shared__ bf16 As[BM * 32];
    __shared__ bf16 Bs[BN * 32];

    const int tid  = threadIdx.x;
    const int lane = tid & 63;
    const int wave = tid >> 6;
    const int wm = wave >> 1, wn = wave & 1;
    const int bm = blockIdx.y * BM, bn = blockIdx.x * BN;

    f32x4 acc[FM][FN];
    #pragma unroll
    for (int m = 0; m < FM; m++)
        #pragma unroll
        for (int n = 0; n < FN; n++)
            acc[m][n] = (f32x4){0.f, 0.f, 0.f, 0.f};

    for (int k0 = 0; k0 < K; k0 += 32) {
        #pragma unroll
        for (int i = 0; i < LA; i++) {
            const int o = (tid + i * 256) * 16;
            const int row = o >> 6;
            const int ce  = (o & 63) >> 1;
            GLD_LDS16(A + (size_t)(bm + row) * lda + k0 + ce, (char*)As + o);
        }
        #pragma unroll
        for (int i = 0; i < LB; i++) {
            const int o = (tid + i * 256) * 16;
            const int row = o >> 6;
            const int ce  = (o & 63) >> 1;
            GLD_LDS16(W + (size_t)(bn + row) * K + k0 + ce, (char*)Bs + o);
        }
        __syncthreads();

        bf16x8 af[FM], bfr[FN];
        #pragma unroll
        for (int m = 0; m < FM; m++)
            af[m] = *(const bf16x8*)(As + (wm * WM + m * 16 + (lane & 15)) * 32 + (lane >> 4) * 8);
        #pragma unroll
        for (int n = 0; n < FN; n++)
            bfr[n] = *(const bf16x8*)(Bs + (wn * WN + n * 16 + (lane & 15)) * 32 + (lane >> 4) * 8);
        #pragma unroll
        for (int m = 0; m < FM; m++)
            #pragma unroll
            for (int n = 0; n < FN; n++)
                acc[m][n] = MFMA16(af[m], bfr[n], acc[m][n]);
        __syncthreads();
    }

    // C/D layout: col = lane&15, row = (lane>>4)*4 + reg
    #pragma unroll
    for (int n = 0; n < FN; n++) {
        const int col = bn + wn * WN + n * 16 + (lane & 15);
        const float bv = bias[col];
        #pragma unroll
        for (int m = 0; m < FM; m++) {
            #pragma unroll
            for (int r = 0; r < 4; r++) {
                const int row = bm + wm * WM + m * 16 + (lane >> 4) * 4 + r;
                float v = acc[m][n][r] + bv;
                if (relu) v = fmaxf(v, 0.f);
                C[(size_t)row * ldc + col] = __float2bfloat16(v);
            }
        }
    }
}

// ---------------------------------------------------------------------------
// Fused GEMM + bias + residual + LayerNorm (out_proj path, K small).
// BM=64, BN=128 (full LN row). 256 threads, waves 2x2, each wave 32x64.
// ---------------------------------------------------------------------------
__global__ __launch_bounds__(256) void mfma_gemm_ln(
    const bf16* __restrict__ A, int lda,
    const bf16* __restrict__ W,              // [128,K]
    const float* __restrict__ bias,          // [128]
    const bf16* __restrict__ R,              // residual [M,128] bf16
    const float* __restrict__ lng, const float* __restrict__ lnb,
    bf16* __restrict__ Y,                    // [M,128] bf16
    int K)
{
    constexpr int BM = 64, WM = 32, WN = 64, FM = 2, FN = 4;

    __shared__ bf16 As[BM * 32];
    __shared__ bf16 Bs[128 * 32];
    __shared__ float rsum[BM][2];
    __shared__ float rsq[BM][2];

    const int tid  = threadIdx.x;
    const int lane = tid & 63;
    const int wave = tid >> 6;
    const int wm = wave >> 1, wn = wave & 1;
    const int bm = blockIdx.x * BM;

    f32x4 acc[FM][FN];
    #pragma unroll
    for (int m = 0; m < FM; m++)
        #pragma unroll
        for (int n = 0; n < FN; n++)
            acc[m][n] = (f32x4){0.f, 0.f, 0.f, 0.f};

    for (int k0 = 0; k0 < K; k0 += 32) {
        {   // A tile: 64 rows x 32 cols
            const int o = tid * 16;
            const int row = o >> 6;
            const int ce  = (o & 63) >> 1;
            GLD_LDS16(A + (size_t)(bm + row) * lda + k0 + ce, (char*)As + o);
        }
        #pragma unroll
        for (int i = 0; i < 2; i++) {       // B tile: 128 rows
            const int o = (tid + i * 256) * 16;
            const int row = o >> 6;
            const int ce  = (o & 63) >> 1;
            GLD_LDS16(W + (size_t)row * K + k0 + ce, (char*)Bs + o);
        }
        __syncthreads();

        bf16x8 af[FM], bfr[FN];
        #pragma unroll
        for (int m = 0; m < FM; m++)
            af[m] = *(const bf16x8*)(As + (wm * WM + m * 16 + (lane & 15)) * 32 + (lane >> 4) * 8);
        #pragma unroll
        for (int n = 0; n < FN; n++)
            bfr[n] = *(const bf16x8*)(Bs + (wn * WN + n * 16 + (lane & 15)) * 32 + (lane >> 4) * 8);
        #pragma unroll
        for (int m = 0; m < FM; m++)
            #pragma unroll
            for (int n = 0; n < FN; n++)
                acc[m][n] = MFMA16(af[m], bfr[n], acc[m][n]);
        __syncthreads();
    }

    // bias + residual
    #pragma unroll
    for (int n = 0; n < FN; n++) {
        const int col = wn * WN + n * 16 + (lane & 15);
        const float bv = bias[col];
        #pragma unroll
        for (int m = 0; m < FM; m++) {
            #pragma unroll
            for (int r = 0; r < 4; r++) {
                const int rl = wm * WM + m * 16 + (lane >> 4) * 4 + r;
                acc[m][n][r] += bv + __bfloat162float(R[(size_t)(bm + rl) * 128 + col]);
            }
        }
    }

    // row sums
    #pragma unroll
    for (int m = 0; m < FM; m++) {
        #pragma unroll
        for (int r = 0; r < 4; r++) {
            float s = 0.f, q = 0.f;
            #pragma unroll
            for (int n = 0; n < FN; n++) { float v = acc[m][n][r]; s += v; q += v * v; }
            #pragma unroll
            for (int off = 1; off < 16; off <<= 1) {
                s += __shfl_xor(s, off);
                q += __shfl_xor(q, off);
            }
            const int rl = wm * WM + m * 16 + (lane >> 4) * 4 + r;
            if ((lane & 15) == 0) { rsum[rl][wn] = s; rsq[rl][wn] = q; }
        }
    }
    __syncthreads();

    #pragma unroll
    for (int m = 0; m < FM; m++) {
        #pragma unroll
        for (int r = 0; r < 4; r++) {
            const int rl = wm * WM + m * 16 + (lane >> 4) * 4 + r;
            const float S = rsum[rl][0] + rsum[rl][1];
            const float Q = rsq[rl][0] + rsq[rl][1];
            const float mean = S * (1.0f / 128.0f);
            const float var  = Q * (1.0f / 128.0f) - mean * mean;
            const float rstd = rsqrtf(var + 1e-5f);
            #pragma unroll
            for (int n = 0; n < FN; n++) {
                const int col = wn * WN + n * 16 + (lane & 15);
                const float y = (acc[m][n][r] - mean) * rstd * lng[col] + lnb[col];
                Y[(size_t)(bm + rl) * 128 + col] = __float2bfloat16(y);
            }
        }
    }
}

// ---------------------------------------------------------------------------
// FULLY FUSED FFN: Y = LN( A + (relu(A@W1^T + b1) @ W2^T + b2) ) [* head]
// One block = 32 token rows. 4 waves. Hidden 32x2048 bf16 lives in LDS (128KB),
// never touches HBM. A tile (and residual) in LDS, XOR-swizzled (byte ^=
// (row&7)<<4) so stride-256B/4096B ds_read_b128 is conflict-free (2-way).
// Phase 1: wave computes hidden cols [wv*512, wv*512+512).
// Phase 2: wave computes output cols [wv*32, wv*32+32) over K=2048.
// W1/W2 fragments read global->reg (16 rows x 64B contiguous per step; L2-hot).
// HEAD: final layer emits out[row] = dot(ln_row, hw) instead of Y.
// ---------------------------------------------------------------------------
template<bool HEAD>
__global__ __launch_bounds__(256) void ffn_fused(
    const bf16* __restrict__ A,              // [M,128]  input = residual
    const bf16* __restrict__ W1, const float* __restrict__ b1,   // [2048,128],[2048]
    const bf16* __restrict__ W2, const float* __restrict__ b2,   // [128,2048],[128]
    const float* __restrict__ lng, const float* __restrict__ lnb,
    bf16* __restrict__ Y,                    // [M,128] (unused if HEAD)
    const float* __restrict__ hw, float* __restrict__ hout)
{
    __shared__ bf16 As_[32 * 128];           // 8 KB, swizzled
    __shared__ bf16 Hs[32 * 2048];           // 128 KB, swizzled
    __shared__ float rsum[32][4];
    __shared__ float rsq[32][4];

    const int tid  = threadIdx.x;
    const int lane = tid & 63;
    const int wv   = tid >> 6;
    const int l4   = lane & 15;
    const int g    = lane >> 4;
    const int bm   = blockIdx.x * 32;

    // ---- stage A (32x128, swizzled) ----
    #pragma unroll
    for (int i = 0; i < 2; i++) {
        int e = tid + i * 256;
        int r = e >> 4, cb = e & 15;
        uint4 v = *(const uint4*)((const char*)A + (size_t)(bm + r) * 256 + cb * 16);
        int byt = (r * 256 + cb * 16) ^ ((r & 7) << 4);
        *(uint4*)((char*)As_ + byt) = v;
    }
    __syncthreads();

    // A fragments (reused across all of phase 1): row = m*16+l4, k = ks*32+g*8
    bf16x8 af[2][4];
    #pragma unroll
    for (int m = 0; m < 2; m++)
        #pragma unroll
        for (int ks = 0; ks < 4; ks++) {
            int row = m * 16 + l4;
            int byt = (row * 256 + ks * 64 + g * 16) ^ ((row & 7) << 4);
            af[m][ks] = *(const bf16x8*)((const char*)As_ + byt);
        }

    // ---- phase 1: hidden = relu(A @ W1^T + b1), cols owned per wave ----
    const int cbase = wv * 512;
    #pragma unroll 2
    for (int ch = 0; ch < 32; ch++) {
        const int c0 = cbase + ch * 16;
        const bf16* wp = W1 + (size_t)(c0 + l4) * 128 + g * 8;
        bf16x8 wf0 = *(const bf16x8*)(wp);
        bf16x8 wf1 = *(const bf16x8*)(wp + 32);
        bf16x8 wf2 = *(const bf16x8*)(wp + 64);
        bf16x8 wf3 = *(const bf16x8*)(wp + 96);
        f32x4 a0 = (f32x4){0.f,0.f,0.f,0.f};
        f32x4 a1 = (f32x4){0.f,0.f,0.f,0.f};
        a0 = MFMA16(af[0][0], wf0, a0); a1 = MFMA16(af[1][0], wf0, a1);
        a0 = MFMA16(af[0][1], wf1, a0); a1 = MFMA16(af[1][1], wf1, a1);
        a0 = MFMA16(af[0][2], wf2, a0); a1 = MFMA16(af[1][2], wf2, a1);
        a0 = MFMA16(af[0][3], wf3, a0); a1 = MFMA16(af[1][3], wf3, a1);
        const float bv = b1[c0 + l4];
        #pragma unroll
        for (int r = 0; r < 4; r++) {
            int row0 = g * 4 + r;
            int row1 = 16 + row0;
            int byt0 = (row0 * 4096 + (c0 + l4) * 2) ^ ((row0 & 7) << 4);
            int byt1 = (row1 * 4096 + (c0 + l4) * 2) ^ ((row1 & 7) << 4);
            *(bf16*)((char*)Hs + byt0) = __float2bfloat16(fmaxf(a0[r] + bv, 0.f));
            *(bf16*)((char*)Hs + byt1) = __float2bfloat16(fmaxf(a1[r] + bv, 0.f));
        }
    }
    __syncthreads();

    // ---- phase 2: out = H @ W2^T, wave owns 32 output cols ----
    const int obase = wv * 32;
    f32x4 c00 = (f32x4){0.f,0.f,0.f,0.f}, c01 = c00, c10 = c00, c11 = c00;
    const bf16* w2p0 = W2 + (size_t)(obase + l4) * 2048 + g * 8;
    const bf16* w2p1 = W2 + (size_t)(obase + 16 + l4) * 2048 + g * 8;
    #pragma unroll 4
    for (int ks = 0; ks < 64; ks++) {
        int byt0 = (l4 * 4096 + ks * 64 + g * 16) ^ ((l4 & 7) << 4);
        int byt1 = byt0 + 16 * 4096;         // row 16+l4: same (row&7) -> same XOR
        bf16x8 h0 = *(const bf16x8*)((const char*)Hs + byt0);
        bf16x8 h1 = *(const bf16x8*)((const char*)Hs + byt1);
        bf16x8 w0 = *(const bf16x8*)(w2p0 + ks * 32);
        bf16x8 w1 = *(const bf16x8*)(w2p1 + ks * 32);
        c00 = MFMA16(h0, w0, c00); c01 = MFMA16(h0, w1, c01);
        c10 = MFMA16(h1, w0, c10); c11 = MFMA16(h1, w1, c11);
    }

    // ---- bias + residual (from LDS A tile) ----
    float vv[2][2][4];
    #pragma unroll
    for (int m = 0; m < 2; m++) {
        #pragma unroll
        for (int n = 0; n < 2; n++) {
            const int col = obase + n * 16 + l4;
            const float bv = b2[col];
            #pragma unroll
            for (int r = 0; r < 4; r++) {
                const int row = m * 16 + g * 4 + r;
                int byt = (row * 256 + col * 2) ^ ((row & 7) << 4);
                float resid = __bfloat162float(*(const bf16*)((const char*)As_ + byt));
                const f32x4& a = m == 0 ? (n == 0 ? c00 : c01) : (n == 0 ? c10 : c11);
                vv[m][n][r] = a[r] + bv + resid;
            }
        }
    }

    // ---- LN row statistics ----
    #pragma unroll
    for (int m = 0; m < 2; m++) {
        #pragma unroll
        for (int r = 0; r < 4; r++) {
            float s = vv[m][0][r] + vv[m][1][r];
            float q = vv[m][0][r] * vv[m][0][r] + vv[m][1][r] * vv[m][1][r];
            #pragma unroll
            for (int off = 1; off < 16; off <<= 1) {
                s += __shfl_xor(s, off);
                q += __shfl_xor(q, off);
            }
            const int row = m * 16 + g * 4 + r;
            if (l4 == 0) { rsum[row][wv] = s; rsq[row][wv] = q; }
        }
    }
    __syncthreads();

    float hacc[2][4];
    #pragma unroll
    for (int m = 0; m < 2; m++)
        #pragma unroll
        for (int r = 0; r < 4; r++) hacc[m][r] = 0.f;

    #pragma unroll
    for (int m = 0; m < 2; m++) {
        #pragma unroll
        for (int r = 0; r < 4; r++) {
            const int row = m * 16 + g * 4 + r;
            const float S = (rsum[row][0] + rsum[row][1]) + (rsum[row][2] + rsum[row][3]);
            const float Q = (rsq[row][0] + rsq[row][1]) + (rsq[row][2] + rsq[row][3]);
            const float mean = S * (1.0f / 128.0f);
            const float var  = Q * (1.0f / 128.0f) - mean * mean;
            const float rstd = rsqrtf(var + 1e-5f);
            #pragma unroll
            for (int n = 0; n < 2; n++) {
                const int col = obase + n * 16 + l4;
                const float y = (vv[m][n][r] - mean) * rstd * lng[col] + lnb[col];
                if (HEAD) hacc[m][r] += y * hw[col];
                else Y[(size_t)(bm + row) * 128 + col] = __float2bfloat16(y);
            }
        }
    }

    if (HEAD) {
        __syncthreads();       // reuse rsum
        #pragma unroll
        for (int m = 0; m < 2; m++) {
            #pragma unroll
            for (int r = 0; r < 4; r++) {
                float h = hacc[m][r];
                #pragma unroll
                for (int off = 1; off < 16; off <<= 1) h += __shfl_xor(h, off);
                const int row = m * 16 + g * 4 + r;
                if (l4 == 0) rsum[row][wv] = h;
            }
        }
        __syncthreads();
        if (tid < 32)
            hout[bm + tid] = (rsum[tid][0] + rsum[tid][1]) + (rsum[tid][2] + rsum[tid][3]);
    }
}

// ---------------------------------------------------------------------------
// Merged fp32->bf16 conversion of all weights + x, plus t2v table (segment 9).
// ---------------------------------------------------------------------------
struct ConvDesc {
    const float *x, *s1, *s2, *s3, *s4, *s5, *s6, *s7, *s8;
    bf16 *dx, *d1, *d2, *d3, *d4, *d5, *d6, *d7, *d8;
    const float *w, *b, *w0, *b0;
    float* tbl;
};

__device__ inline void cvt4(const float* s, bf16* d, int j) {
    float4 v = ((const float4*)s)[j];
    ushort4 o;
    o.x = (unsigned short)f2bs(v.x); o.y = (unsigned short)f2bs(v.y);
    o.z = (unsigned short)f2bs(v.z); o.w = (unsigned short)f2bs(v.w);
    *(ushort4*)((unsigned short*)d + j * 4) = o;
}

// prefix sums in float4 units
#define CP0 524288   // x            (2097152)
#define CP1 536576   // enc_in_w     (49152)
#define CP2 540672   // enc_out_w    (16384)
#define CP3 606208   // enc_l1w      (262144)
#define CP4 671744   // enc_l2w      (262144)
#define CP5 696320   // qk_in_w      (98304)
#define CP6 704512   // qk_out_w     (32768)
#define CP7 835584   // qk_l1w       (524288)
#define CP8 966656   // qk_l2w       (524288)
#define CP9 967680   // t2v table    (4096 fp32)

__global__ __launch_bounds__(256) void conv_all_kernel(ConvDesc cd)
{
    int i = blockIdx.x * 256 + threadIdx.x;
    if (i < CP0)      cvt4(cd.x,  cd.dx, i);
    else if (i < CP1) cvt4(cd.s1, cd.d1, i - CP0);
    else if (i < CP2) cvt4(cd.s2, cd.d2, i - CP1);
    else if (i < CP3) cvt4(cd.s3, cd.d3, i - CP2);
    else if (i < CP4) cvt4(cd.s4, cd.d4, i - CP3);
    else if (i < CP5) cvt4(cd.s5, cd.d5, i - CP4);
    else if (i < CP6) cvt4(cd.s6, cd.d6, i - CP5);
    else if (i < CP7) cvt4(cd.s7, cd.d7, i - CP6);
    else if (i < CP8) cvt4(cd.s8, cd.d8, i - CP7);
    else if (i < CP9) {
        int e = (i - CP8) * 4;
        int t = e >> 7;
        float tau = (float)(t + 1);
        float4 o;
        #pragma unroll
        for (int k = 0; k < 4; k++) {
            int d = (e + k) & 127;
            ((float*)&o)[k] = (d < 127) ? sinf(tau * cd.w[d] + cd.b[d])
                                        : (tau * cd.w0[0] + cd.b0[0]);
        }
        *(float4*)(cd.tbl + e) = o;
    }
}

// ---------------------------------------------------------------------------
// Stage-1 attention via MFMA (flash, maxless). One block per (t,h).
// ---------------------------------------------------------------------------
__global__ __launch_bounds__(256) void attn_full_mfma(
    const bf16* __restrict__ Qkv, bf16* __restrict__ C)
{
    __shared__ bf16 Qs[512 * 16];
    __shared__ bf16 Ks[512 * 16];
    __shared__ bf16 Vt[16 * 520];
    __shared__ bf16 Zero[32];          // 64B broadcast zero block

    const int t = blockIdx.x >> 3;
    const int h = blockIdx.x & 7;
    const int tid = threadIdx.x;

    if (tid < 32) ((unsigned short*)Zero)[tid] = 0;

    for (int n = tid; n < 512; n += 256) {
        const unsigned short* row = (const unsigned short*)Qkv + (size_t)(t * 512 + n) * 384 + h * 16;
        uint4 q0 = *(const uint4*)(row);
        uint4 q1 = *(const uint4*)(row + 8);
        uint4 k0 = *(const uint4*)(row + 128);
        uint4 k1 = *(const uint4*)(row + 136);
        uint4 v0 = *(const uint4*)(row + 256);
        uint4 v1 = *(const uint4*)(row + 264);
        *(uint4*)((unsigned short*)Qs + n * 16)     = q0;
        *(uint4*)((unsigned short*)Qs + n * 16 + 8) = q1;
        *(uint4*)((unsigned short*)Ks + n * 16)     = k0;
        *(uint4*)((unsigned short*)Ks + n * 16 + 8) = k1;
        union { uint4 u[2]; unsigned short s[16]; } vb;
        vb.u[0] = v0; vb.u[1] = v1;
        #pragma unroll
        for (int f = 0; f < 16; f++)
            ((unsigned short*)Vt)[f * 520 + n] = vb.s[f];
    }
    __syncthreads();

    const int lane = tid & 63;
    const int wv   = tid >> 6;
    const int l4   = lane & 15;
    const int g    = lane >> 4;
    const int qbase = wv * 128;
    const bf16* zp = Zero + (g & 1) * 8;
    const int p0 = ((l4 >> 2) << 3) | (l4 & 3);      // pi0 key permutation

    bf16x8 qf[8];
    #pragma unroll
    for (int qt = 0; qt < 8; qt++) {
        const bf16* ap = (g < 2) ? (Qs + (qbase + qt * 16 + l4) * 16 + g * 8) : zp;
        qf[qt] = *(const bf16x8*)ap;
    }

    f32x4 Oacc[8];
    float lsum[8];
    #pragma unroll
    for (int qt = 0; qt < 8; qt++) { Oacc[qt] = (f32x4){0.f,0.f,0.f,0.f}; lsum[qt] = 0.f; }

    const float cexp = 0.25f * 1.44269504088896f;   // scale * log2(e)

    for (int kt = 0; kt < 16; kt++) {               // 32 keys per iteration
        const bf16* k0p = (g < 2) ? (Ks + (kt * 32 + p0)     * 16 + g * 8) : zp;
        const bf16* k1p = (g < 2) ? (Ks + (kt * 32 + p0 + 4) * 16 + g * 8) : zp;
        bf16x8 kf0 = *(const bf16x8*)k0p;
        bf16x8 kf1 = *(const bf16x8*)k1p;
        bf16x8 vf  = *(const bf16x8*)(Vt + l4 * 520 + kt * 32 + g * 8);

        #pragma unroll
        for (int qt = 0; qt < 8; qt++) {
            f32x4 z = (f32x4){0.f,0.f,0.f,0.f};
            f32x4 s0 = MFMA16(kf0, qf[qt], z);
            f32x4 s1 = MFMA16(kf1, qf[qt], z);
            float e[8];
            #pragma unroll
            for (int r = 0; r < 4; r++) {
                e[r]     = exp2f(s0[r] * cexp);
                e[4 + r] = exp2f(s1[r] * cexp);
            }
            lsum[qt] += ((e[0]+e[1])+(e[2]+e[3])) + ((e[4]+e[5])+(e[6]+e[7]));
            bf16x8 pf;
            #pragma unroll
            for (int i = 0; i < 8; i++) pf[i] = f2bs(e[i]);
            Oacc[qt] = MFMA16(pf, vf, Oacc[qt]);
        }
    }

    #pragma unroll
    for (int qt = 0; qt < 8; qt++) {
        float ls = lsum[qt];
        ls += __shfl_xor(ls, 16);
        ls += __shfl_xor(ls, 32);
        #pragma unroll
        for (int r = 0; r < 4; r++) {
            float lq = __shfl(ls, g * 4 + r);
            float o = Oacc[qt][r] / lq;
            int qrow = t * 512 + qbase + qt * 16 + g * 4 + r;
            C[(size_t)qrow * 128 + h * 16 + l4] = __float2bfloat16(o);
        }
    }
}

// ---------------------------------------------------------------------------
// Stage-3 banded attention: window j in [i-7, i]. bf16 q/k/v in, bf16 out.
// ---------------------------------------------------------------------------
__global__ __launch_bounds__(256) void attn_banded_kernel(
    const bf16* __restrict__ Qkv, const bf16* __restrict__ Vb, bf16* __restrict__ C)
{
    __shared__ float Qs[TT][129];
    __shared__ float Ksh[TT][129];
    __shared__ float Vs[TT][129];
    const int n = blockIdx.x;
    const int tid = threadIdx.x;

    for (int e = tid; e < TT * DD; e += 256) {
        int t = e >> 7, d = e & 127;
        const bf16* row = Qkv + (size_t)(t * NN + n) * 384;
        Qs[t][d]  = __bfloat162float(row[d]);
        Ksh[t][d] = __bfloat162float(row[128 + d]);
        Vs[t][d]  = __bfloat162float(Vb[(size_t)(t * NN + n) * DD + d]);
    }
    __syncthreads();

    const int h = tid >> 5, i = tid & 31;
    const int hb = h * DH;

    float s[WND_];
    #pragma unroll
    for (int kk = 0; kk < WND_; kk++) {
        int j = i - (WND_ - 1) + kk;
        int jc = j < 0 ? 0 : j;
        float d = 0.f;
        #pragma unroll
        for (int f = 0; f < DH; f++) d += Qs[i][hb + f] * Ksh[jc][hb + f];
        s[kk] = (j >= 0) ? d * 0.25f : -1e30f;
    }
    float m = s[0];
    #pragma unroll
    for (int kk = 1; kk < WND_; kk++) m = fmaxf(m, s[kk]);
    float l = 0.f, p[WND_];
    #pragma unroll
    for (int kk = 0; kk < WND_; kk++) { p[kk] = __expf(s[kk] - m); l += p[kk]; }
    float inv = 1.f / l;
    float acc[DH] = {};
    #pragma unroll
    for (int kk = 0; kk < WND_; kk++) {
        int j = i - (WND_ - 1) + kk;
        int jc = j < 0 ? 0 : j;
        float pw = p[kk] * inv;
        #pragma unroll
        for (int f = 0; f < DH; f++) acc[f] += pw * Vs[jc][hb + f];
    }
    bf16* cp = C + (size_t)(i * NN + n) * DD + hb;
    #pragma unroll
    for (int f = 0; f < DH; f++) cp[f] = __float2bfloat16(acc[f]);
}

// ---------------------------------------------------------------------------
// time2vec add: Y = bf16(x + tbl[t, d])
// ---------------------------------------------------------------------------
__global__ __launch_bounds__(256) void t2v_add_kernel(
    const float* __restrict__ x, const float* __restrict__ tbl, bf16* __restrict__ Y)
{
    int i = blockIdx.x * 256 + threadIdx.x;     // float4 groups
    int e = i * 4;
    float4 xv = ((const float4*)x)[i];
    int ti = ((e >> 16) << 7) | (e & 127);
    float4 tv = *(const float4*)(tbl + ti);
    ushort4 o;
    o.x = (unsigned short)f2bs(xv.x + tv.x);
    o.y = (unsigned short)f2bs(xv.y + tv.y);
    o.z = (unsigned short)f2bs(xv.z + tv.z);
    o.w = (unsigned short)f2bs(xv.w + tv.w);
    *(ushort4*)((unsigned short*)Y + e) = o;
}

// ---------------------------------------------------------------------------

extern "C" void kernel_launch(void* const* d_in, const int* in_sizes, int n_in,
                              void* d_out, int out_size, void* d_ws, size_t ws_size,
                              hipStream_t stream) {
    const float* x           = (const float*)d_in[0];
    const float* enc_in_w    = (const float*)d_in[1];
    const float* enc_in_b    = (const float*)d_in[2];
    const float* enc_out_w   = (const float*)d_in[3];
    const float* enc_out_b   = (const float*)d_in[4];
    const float* enc_l1w     = (const float*)d_in[5];
    const float* enc_l1b     = (const float*)d_in[6];
    const float* enc_l2w     = (const float*)d_in[7];
    const float* enc_l2b     = (const float*)d_in[8];
    const float* enc_ln1w    = (const float*)d_in[9];
    const float* enc_ln1b    = (const float*)d_in[10];
    const float* enc_ln2w    = (const float*)d_in[11];
    const float* enc_ln2b    = (const float*)d_in[12];
    const float* qk_in_w     = (const float*)d_in[13];
    const float* qk_in_b     = (const float*)d_in[14];
    const float* qk_out_w    = (const float*)d_in[15];
    const float* qk_out_b    = (const float*)d_in[16];
    const float* qk_l1w      = (const float*)d_in[17];
    const float* qk_l1b      = (const float*)d_in[18];
    const float* qk_l2w      = (const float*)d_in[19];
    const float* qk_l2b      = (const float*)d_in[20];
    const float* qk_ln1w     = (const float*)d_in[21];
    const float* qk_ln1b     = (const float*)d_in[22];
    const float* qk_ln2w     = (const float*)d_in[23];
    const float* qk_ln2b     = (const float*)d_in[24];
    const float* t2v_w       = (const float*)d_in[25];
    const float* t2v_b       = (const float*)d_in[26];
    const float* t2v_w0      = (const float*)d_in[27];
    const float* t2v_b0      = (const float*)d_in[28];
    const float* out_w       = (const float*)d_in[29];
    float* out = (float*)d_out;

    // ---------------- workspace layout (bytes) ------------------------------
    char* ws = (char*)d_ws;
    const size_t TOKD = (size_t)TOK * DD;
    size_t off = 0;
    auto alloc = [&](size_t bytes) { char* p = ws + off; off += (bytes + 255) & ~(size_t)255; return p; };

    bf16*  Qb   = (bf16*)alloc((size_t)TOK * 384 * 2);   // qkv bf16
    bf16*  Vb   = (bf16*)alloc(TOKD * 2);                // v-projection bf16
    bf16*  xb   = (bf16*)alloc(TOKD * 2);                // bf16 copy of x
    bf16*  bufA = (bf16*)alloc(TOKD * 2);                // residual stream bf16
    bf16*  Zb   = (bf16*)alloc(TOKD * 2);                // outs_zs bf16
    bf16*  Cb   = (bf16*)alloc(TOKD * 2);                // attn context bf16
    float* t2vt = (float*)alloc((size_t)TT * DD * 4);    // time2vec table
    bf16* enc_in_wb  = (bf16*)alloc(384 * DD * 2);
    bf16* enc_out_wb = (bf16*)alloc(DD * DD * 2);
    bf16* enc_l1wb   = (bf16*)alloc((size_t)FF_ * DD * 2);
    bf16* enc_l2wb   = (bf16*)alloc((size_t)DD * FF_ * 2);
    bf16* qk_in_wb   = (bf16*)alloc((size_t)LL * 384 * DD * 2);
    bf16* qk_out_wb  = (bf16*)alloc((size_t)LL * DD * DD * 2);
    bf16* qk_l1wb    = (bf16*)alloc((size_t)LL * FF_ * DD * 2);
    bf16* qk_l2wb    = (bf16*)alloc((size_t)LL * DD * FF_ * 2);

    // ---------------- one-shot conversion of all weights + x + t2v table ----
    ConvDesc cd;
    cd.x  = x;        cd.dx = xb;
    cd.s1 = enc_in_w; cd.d1 = enc_in_wb;
    cd.s2 = enc_out_w;cd.d2 = enc_out_wb;
    cd.s3 = enc_l1w;  cd.d3 = enc_l1wb;
    cd.s4 = enc_l2w;  cd.d4 = enc_l2wb;
    cd.s5 = qk_in_w;  cd.d5 = qk_in_wb;
    cd.s6 = qk_out_w; cd.d6 = qk_out_wb;
    cd.s7 = qk_l1w;   cd.d7 = qk_l1wb;
    cd.s8 = qk_l2w;   cd.d8 = qk_l2wb;
    cd.w = t2v_w; cd.b = t2v_b; cd.w0 = t2v_w0; cd.b0 = t2v_b0; cd.tbl = t2vt;
    conv_all_kernel<<<(CP9 + 255) / 256, 256, 0, stream>>>(cd);

    auto gemm128 = [&](const bf16* A, int lda, const bf16* W, const float* bias,
                       bf16* C, int ldc, int M, int N, int K, int relu) {
        dim3 grid(N / 128, M / 128);
        mfma_gemm<128, 128><<<grid, 256, 0, stream>>>(A, lda, W, bias, C, ldc, K, relu);
    };
    auto gemm64 = [&](const bf16* A, int lda, const bf16* W, const float* bias,
                      bf16* C, int ldc, int M, int N, int K, int relu) {
        dim3 grid(N / 64, M / 64);
        mfma_gemm<64, 64><<<grid, 256, 0, stream>>>(A, lda, W, bias, C, ldc, K, relu);
    };
    auto gemm_ln = [&](const bf16* A, int lda, const bf16* W, const float* bias,
                       const bf16* R, const float* lng, const float* lnb,
                       bf16* Y, int M, int K) {
        mfma_gemm_ln<<<M / 64, 256, 0, stream>>>(A, lda, W, bias, R, lng, lnb, Y, K);
    };

    // ---------------- stage 1: plain encoder (attend over N, batch T) -------
    gemm128(xb, DD, enc_in_wb, enc_in_b, Qb, 384, TOK, 384, DD, 0);
    attn_full_mfma<<<TT * HH, 256, 0, stream>>>(Qb, Cb);
    gemm_ln(Cb, DD, enc_out_wb, enc_out_b, xb, enc_ln1w, enc_ln1b, bufA, TOK, DD);
    ffn_fused<false><<<TOK / 32, 256, 0, stream>>>(
        bufA, enc_l1wb, enc_l1b, enc_l2wb, enc_l2b,
        enc_ln2w, enc_ln2b, Zb, nullptr, nullptr);

    // ---------------- stage 2: time2vec -------------------------------------
    t2v_add_kernel<<<(TOK * DD / 4) / 256, 256, 0, stream>>>(x, t2vt, bufA);

    // ---------------- stage 3: qk encoder stack (banded window attn) ---------
    for (int l = 0; l < LL; l++) {
        const bf16* iw   = qk_in_wb  + (size_t)l * 384 * DD;
        const float* ib  = qk_in_b   + (size_t)l * 384;
        const bf16* owt  = qk_out_wb + (size_t)l * DD * DD;
        const float* ob  = qk_out_b  + (size_t)l * DD;
        const bf16* l1w  = qk_l1wb   + (size_t)l * FF_ * DD;
        const float* l1b = qk_l1b    + (size_t)l * FF_;
        const bf16* l2w  = qk_l2wb   + (size_t)l * DD * FF_;
        const float* l2b = qk_l2b    + (size_t)l * DD;

        gemm128(bufA, DD, iw, ib, Qb, 384, TOK, 256, DD, 0);
        gemm64(Zb, DD, iw + (size_t)256 * DD, ib + 256, Vb, DD, TOK, DD, DD, 0);
        attn_banded_kernel<<<NN, 256, 0, stream>>>(Qb, Vb, Cb);
        gemm_ln(Cb, DD, owt, ob, bufA, qk_ln1w + l * DD, qk_ln1b + l * DD, bufA, TOK, DD);
        if (l == LL - 1) {
            ffn_fused<true><<<TOK / 32, 256, 0, stream>>>(
                bufA, l1w, l1b, l2w, l2b,
                qk_ln2w + l * DD, qk_ln2b + l * DD, nullptr, out_w, out);
        } else {
            ffn_fused<false><<<TOK / 32, 256, 0, stream>>>(
                bufA, l1w, l1b, l2w, l2b,
                qk_ln2w + l * DD, qk_ln2b + l * DD, bufA, nullptr, nullptr);
        }
    }
}

// Round 7
// 323.839 us; speedup vs baseline: 1.0779x; 1.0779x over previous
//
#include <hip/hip_runtime.h>
#include <hip/hip_bf16.h>
#include <math.h>

// Problem constants
#define TT 32
#define NN 512
#define DD 128
#define FF_ 2048
#define HH 8
#define LL 2
#define WND_ 8
#define TOK (TT*NN)          // 16384 tokens
#define DH 16                // head dim

typedef __hip_bfloat16 bf16;
typedef __attribute__((ext_vector_type(8))) short bf16x8;   // 8 bf16 (4 VGPRs)
typedef __attribute__((ext_vector_type(4))) float f32x4;    // 4 fp32

// global_load_lds: 16B per lane, LDS dest = wave-uniform base + lane*16 (linear)
#define GLD_LDS16(gp, lp) __builtin_amdgcn_global_load_lds( \
    (const __attribute__((address_space(1))) unsigned int*)(gp), \
    (__attribute__((address_space(3))) unsigned int*)(lp), 16, 0, 0)

#define MFMA16(a, b, c) __builtin_amdgcn_mfma_f32_16x16x32_bf16((a), (b), (c), 0, 0, 0)

__device__ inline short f2bs(float f) {
    __hip_bfloat16 h = __float2bfloat16(f);
    return *reinterpret_cast<short*>(&h);
}

// ---------------------------------------------------------------------------
// bf16 MFMA GEMM: C[M,N] = A[M,K] @ W[N,K]^T + bias (+relu). Output bf16.
// Tile BM x BN, BK=32, 256 threads = 4 waves in 2x2.
// ---------------------------------------------------------------------------
template<int BM, int BN>
__global__ __launch_bounds__(256) void mfma_gemm(
    const bf16* __restrict__ A, int lda,
    const bf16* __restrict__ W,              // [N,K] row-major (= B^T)
    const float* __restrict__ bias,          // [N]
    bf16* __restrict__ C, int ldc,
    int K, int relu)
{
    constexpr int WM = BM / 2, WN = BN / 2;
    constexpr int FM = WM / 16, FN = WN / 16;
    constexpr int LA = (BM * 64) / (256 * 16);
    constexpr int LB = (BN * 64) / (256 * 16);

    __shared__ bf16 As[BM * 32];
    __shared__ bf16 Bs[BN * 32];

    const int tid  = threadIdx.x;
    const int lane = tid & 63;
    const int wave = tid >> 6;
    const int wm = wave >> 1, wn = wave & 1;
    const int bm = blockIdx.y * BM, bn = blockIdx.x * BN;

    f32x4 acc[FM][FN];
    #pragma unroll
    for (int m = 0; m < FM; m++)
        #pragma unroll
        for (int n = 0; n < FN; n++)
            acc[m][n] = (f32x4){0.f, 0.f, 0.f, 0.f};

    for (int k0 = 0; k0 < K; k0 += 32) {
        #pragma unroll
        for (int i = 0; i < LA; i++) {
            const int o = (tid + i * 256) * 16;
            const int row = o >> 6;
            const int ce  = (o & 63) >> 1;
            GLD_LDS16(A + (size_t)(bm + row) * lda + k0 + ce, (char*)As + o);
        }
        #pragma unroll
        for (int i = 0; i < LB; i++) {
            const int o = (tid + i * 256) * 16;
            const int row = o >> 6;
            const int ce  = (o & 63) >> 1;
            GLD_LDS16(W + (size_t)(bn + row) * K + k0 + ce, (char*)Bs + o);
        }
        __syncthreads();

        bf16x8 af[FM], bfr[FN];
        #pragma unroll
        for (int m = 0; m < FM; m++)
            af[m] = *(const bf16x8*)(As + (wm * WM + m * 16 + (lane & 15)) * 32 + (lane >> 4) * 8);
        #pragma unroll
        for (int n = 0; n < FN; n++)
            bfr[n] = *(const bf16x8*)(Bs + (wn * WN + n * 16 + (lane & 15)) * 32 + (lane >> 4) * 8);
        #pragma unroll
        for (int m = 0; m < FM; m++)
            #pragma unroll
            for (int n = 0; n < FN; n++)
                acc[m][n] = MFMA16(af[m], bfr[n], acc[m][n]);
        __syncthreads();
    }

    // C/D layout: col = lane&15, row = (lane>>4)*4 + reg
    #pragma unroll
    for (int n = 0; n < FN; n++) {
        const int col = bn + wn * WN + n * 16 + (lane & 15);
        const float bv = bias[col];
        #pragma unroll
        for (int m = 0; m < FM; m++) {
            #pragma unroll
            for (int r = 0; r < 4; r++) {
                const int row = bm + wm * WM + m * 16 + (lane >> 4) * 4 + r;
                float v = acc[m][n][r] + bv;
                if (relu) v = fmaxf(v, 0.f);
                C[(size_t)row * ldc + col] = __float2bfloat16(v);
            }
        }
    }
}

// ---------------------------------------------------------------------------
// Fused GEMM + bias + residual + LayerNorm (out_proj path, K small).
// BM=64, BN=128 (full LN row). 256 threads, waves 2x2, each wave 32x64.
// ---------------------------------------------------------------------------
__global__ __launch_bounds__(256) void mfma_gemm_ln(
    const bf16* __restrict__ A, int lda,
    const bf16* __restrict__ W,              // [128,K]
    const float* __restrict__ bias,          // [128]
    const bf16* __restrict__ R,              // residual [M,128] bf16
    const float* __restrict__ lng, const float* __restrict__ lnb,
    bf16* __restrict__ Y,                    // [M,128] bf16
    int K)
{
    constexpr int BM = 64, WM = 32, WN = 64, FM = 2, FN = 4;

    __shared__ bf16 As[BM * 32];
    __shared__ bf16 Bs[128 * 32];
    __shared__ float rsum[BM][2];
    __shared__ float rsq[BM][2];

    const int tid  = threadIdx.x;
    const int lane = tid & 63;
    const int wave = tid >> 6;
    const int wm = wave >> 1, wn = wave & 1;
    const int bm = blockIdx.x * BM;

    f32x4 acc[FM][FN];
    #pragma unroll
    for (int m = 0; m < FM; m++)
        #pragma unroll
        for (int n = 0; n < FN; n++)
            acc[m][n] = (f32x4){0.f, 0.f, 0.f, 0.f};

    for (int k0 = 0; k0 < K; k0 += 32) {
        {   // A tile: 64 rows x 32 cols
            const int o = tid * 16;
            const int row = o >> 6;
            const int ce  = (o & 63) >> 1;
            GLD_LDS16(A + (size_t)(bm + row) * lda + k0 + ce, (char*)As + o);
        }
        #pragma unroll
        for (int i = 0; i < 2; i++) {       // B tile: 128 rows
            const int o = (tid + i * 256) * 16;
            const int row = o >> 6;
            const int ce  = (o & 63) >> 1;
            GLD_LDS16(W + (size_t)row * K + k0 + ce, (char*)Bs + o);
        }
        __syncthreads();

        bf16x8 af[FM], bfr[FN];
        #pragma unroll
        for (int m = 0; m < FM; m++)
            af[m] = *(const bf16x8*)(As + (wm * WM + m * 16 + (lane & 15)) * 32 + (lane >> 4) * 8);
        #pragma unroll
        for (int n = 0; n < FN; n++)
            bfr[n] = *(const bf16x8*)(Bs + (wn * WN + n * 16 + (lane & 15)) * 32 + (lane >> 4) * 8);
        #pragma unroll
        for (int m = 0; m < FM; m++)
            #pragma unroll
            for (int n = 0; n < FN; n++)
                acc[m][n] = MFMA16(af[m], bfr[n], acc[m][n]);
        __syncthreads();
    }

    // bias + residual
    #pragma unroll
    for (int n = 0; n < FN; n++) {
        const int col = wn * WN + n * 16 + (lane & 15);
        const float bv = bias[col];
        #pragma unroll
        for (int m = 0; m < FM; m++) {
            #pragma unroll
            for (int r = 0; r < 4; r++) {
                const int rl = wm * WM + m * 16 + (lane >> 4) * 4 + r;
                acc[m][n][r] += bv + __bfloat162float(R[(size_t)(bm + rl) * 128 + col]);
            }
        }
    }

    // row sums
    #pragma unroll
    for (int m = 0; m < FM; m++) {
        #pragma unroll
        for (int r = 0; r < 4; r++) {
            float s = 0.f, q = 0.f;
            #pragma unroll
            for (int n = 0; n < FN; n++) { float v = acc[m][n][r]; s += v; q += v * v; }
            #pragma unroll
            for (int off = 1; off < 16; off <<= 1) {
                s += __shfl_xor(s, off);
                q += __shfl_xor(q, off);
            }
            const int rl = wm * WM + m * 16 + (lane >> 4) * 4 + r;
            if ((lane & 15) == 0) { rsum[rl][wn] = s; rsq[rl][wn] = q; }
        }
    }
    __syncthreads();

    #pragma unroll
    for (int m = 0; m < FM; m++) {
        #pragma unroll
        for (int r = 0; r < 4; r++) {
            const int rl = wm * WM + m * 16 + (lane >> 4) * 4 + r;
            const float S = rsum[rl][0] + rsum[rl][1];
            const float Q = rsq[rl][0] + rsq[rl][1];
            const float mean = S * (1.0f / 128.0f);
            const float var  = Q * (1.0f / 128.0f) - mean * mean;
            const float rstd = rsqrtf(var + 1e-5f);
            #pragma unroll
            for (int n = 0; n < FN; n++) {
                const int col = wn * WN + n * 16 + (lane & 15);
                const float y = (acc[m][n][r] - mean) * rstd * lng[col] + lnb[col];
                Y[(size_t)(bm + rl) * 128 + col] = __float2bfloat16(y);
            }
        }
    }
}

// ---------------------------------------------------------------------------
// FUSED FFN (chunked): Y = LN( A + (relu(A@W1^T+b1) @ W2^T + b2) ) [* head]
// One block = 32 token rows, 4 waves. Hidden processed in 4 chunks of 32x512
// bf16 held in a 32 KB LDS buffer (never HBM); lin2 accumulators persist in
// registers across chunks. LDS total ~42 KB -> 2 blocks/CU co-resident
// (vs 137 KB/1 block in the previous version -> the occupancy fix).
// XOR swizzle byte^=(row&7)<<4 on A and H tiles keeps ds_read_b128
// conflict-free (16+l4 shares (row&7) with l4, so byt1 = byt0 + 16KB row
// stride holds).
// Phase 1 (per chunk): wave computes hidden cols [wv*128 .. wv*128+128).
// Phase 2 (per chunk): wave accumulates output cols [wv*32 .. wv*32+32).
// W1/W2 fragments read global->reg (L2-resident, 1 MB reused by all blocks).
// HEAD: final layer emits out[row] = dot(ln_row, hw) instead of Y.
// ---------------------------------------------------------------------------
template<bool HEAD>
__global__ __launch_bounds__(256) void ffn_fused(
    const bf16* __restrict__ A,              // [M,128]  input = residual
    const bf16* __restrict__ W1, const float* __restrict__ b1,   // [2048,128],[2048]
    const bf16* __restrict__ W2, const float* __restrict__ b2,   // [128,2048],[128]
    const float* __restrict__ lng, const float* __restrict__ lnb,
    bf16* __restrict__ Y,                    // [M,128] (unused if HEAD)
    const float* __restrict__ hw, float* __restrict__ hout)
{
    __shared__ bf16 As_[32 * 128];           // 8 KB, swizzled
    __shared__ bf16 Hs[32 * 512];            // 32 KB chunk, swizzled
    __shared__ float rsum[32][4];
    __shared__ float rsq[32][4];

    const int tid  = threadIdx.x;
    const int lane = tid & 63;
    const int wv   = tid >> 6;
    const int l4   = lane & 15;
    const int g    = lane >> 4;
    const int bm   = blockIdx.x * 32;

    // ---- stage A (32x128, swizzled) ----
    #pragma unroll
    for (int i = 0; i < 2; i++) {
        int e = tid + i * 256;
        int r = e >> 4, cb = e & 15;
        uint4 v = *(const uint4*)((const char*)A + (size_t)(bm + r) * 256 + cb * 16);
        int byt = (r * 256 + cb * 16) ^ ((r & 7) << 4);
        *(uint4*)((char*)As_ + byt) = v;
    }
    __syncthreads();

    // A fragments (reused all of phase 1): row = m*16+l4, k = ks*32+g*8
    bf16x8 af[2][4];
    #pragma unroll
    for (int m = 0; m < 2; m++)
        #pragma unroll
        for (int ks = 0; ks < 4; ks++) {
            int row = m * 16 + l4;
            int byt = (row * 256 + ks * 64 + g * 16) ^ ((row & 7) << 4);
            af[m][ks] = *(const bf16x8*)((const char*)As_ + byt);
        }

    const int obase = wv * 32;
    f32x4 c00 = (f32x4){0.f,0.f,0.f,0.f}, c01 = c00, c10 = c00, c11 = c00;

    for (int c = 0; c < 4; c++) {
        // ---- phase 1: hidden chunk cols [c*512, c*512+512), wave owns 128 ----
        const int cbase = c * 512 + wv * 128;
        #pragma unroll
        for (int ch = 0; ch < 8; ch++) {
            const int c0 = cbase + ch * 16;                  // global hidden col
            const bf16* wp = W1 + (size_t)(c0 + l4) * 128 + g * 8;
            bf16x8 wf0 = *(const bf16x8*)(wp);
            bf16x8 wf1 = *(const bf16x8*)(wp + 32);
            bf16x8 wf2 = *(const bf16x8*)(wp + 64);
            bf16x8 wf3 = *(const bf16x8*)(wp + 96);
            f32x4 a0 = (f32x4){0.f,0.f,0.f,0.f};
            f32x4 a1 = (f32x4){0.f,0.f,0.f,0.f};
            a0 = MFMA16(af[0][0], wf0, a0); a1 = MFMA16(af[1][0], wf0, a1);
            a0 = MFMA16(af[0][1], wf1, a0); a1 = MFMA16(af[1][1], wf1, a1);
            a0 = MFMA16(af[0][2], wf2, a0); a1 = MFMA16(af[1][2], wf2, a1);
            a0 = MFMA16(af[0][3], wf3, a0); a1 = MFMA16(af[1][3], wf3, a1);
            const float bv = b1[c0 + l4];
            const int lcol = wv * 128 + ch * 16 + l4;        // chunk-local col
            #pragma unroll
            for (int r = 0; r < 4; r++) {
                int row0 = g * 4 + r;
                int row1 = 16 + row0;
                int byt0 = (row0 * 1024 + lcol * 2) ^ ((row0 & 7) << 4);
                int byt1 = (row1 * 1024 + lcol * 2) ^ ((row1 & 7) << 4);
                *(bf16*)((char*)Hs + byt0) = __float2bfloat16(fmaxf(a0[r] + bv, 0.f));
                *(bf16*)((char*)Hs + byt1) = __float2bfloat16(fmaxf(a1[r] + bv, 0.f));
            }
        }
        __syncthreads();

        // ---- phase 2: accumulate out over this chunk's K=512 ----
        const bf16* w2p0 = W2 + (size_t)(obase + l4) * 2048 + c * 512 + g * 8;
        const bf16* w2p1 = W2 + (size_t)(obase + 16 + l4) * 2048 + c * 512 + g * 8;
        #pragma unroll
        for (int ks = 0; ks < 16; ks++) {
            int byt0 = (l4 * 1024 + ks * 64 + g * 16) ^ ((l4 & 7) << 4);
            int byt1 = byt0 + 16 * 1024;     // row 16+l4: same (row&7) -> same XOR
            bf16x8 h0 = *(const bf16x8*)((const char*)Hs + byt0);
            bf16x8 h1 = *(const bf16x8*)((const char*)Hs + byt1);
            bf16x8 w0 = *(const bf16x8*)(w2p0 + ks * 32);
            bf16x8 w1 = *(const bf16x8*)(w2p1 + ks * 32);
            c00 = MFMA16(h0, w0, c00); c01 = MFMA16(h0, w1, c01);
            c10 = MFMA16(h1, w0, c10); c11 = MFMA16(h1, w1, c11);
        }
        __syncthreads();                     // before overwriting Hs next chunk
    }

    // ---- bias + residual (from LDS A tile) ----
    float vv[2][2][4];
    #pragma unroll
    for (int m = 0; m < 2; m++) {
        #pragma unroll
        for (int n = 0; n < 2; n++) {
            const int col = obase + n * 16 + l4;
            const float bv = b2[col];
            #pragma unroll
            for (int r = 0; r < 4; r++) {
                const int row = m * 16 + g * 4 + r;
                int byt = (row * 256 + col * 2) ^ ((row & 7) << 4);
                float resid = __bfloat162float(*(const bf16*)((const char*)As_ + byt));
                const f32x4& a = m == 0 ? (n == 0 ? c00 : c01) : (n == 0 ? c10 : c11);
                vv[m][n][r] = a[r] + bv + resid;
            }
        }
    }

    // ---- LN row statistics ----
    #pragma unroll
    for (int m = 0; m < 2; m++) {
        #pragma unroll
        for (int r = 0; r < 4; r++) {
            float s = vv[m][0][r] + vv[m][1][r];
            float q = vv[m][0][r] * vv[m][0][r] + vv[m][1][r] * vv[m][1][r];
            #pragma unroll
            for (int off = 1; off < 16; off <<= 1) {
                s += __shfl_xor(s, off);
                q += __shfl_xor(q, off);
            }
            const int row = m * 16 + g * 4 + r;
            if (l4 == 0) { rsum[row][wv] = s; rsq[row][wv] = q; }
        }
    }
    __syncthreads();

    float hacc[2][4];
    #pragma unroll
    for (int m = 0; m < 2; m++)
        #pragma unroll
        for (int r = 0; r < 4; r++) hacc[m][r] = 0.f;

    #pragma unroll
    for (int m = 0; m < 2; m++) {
        #pragma unroll
        for (int r = 0; r < 4; r++) {
            const int row = m * 16 + g * 4 + r;
            const float S = (rsum[row][0] + rsum[row][1]) + (rsum[row][2] + rsum[row][3]);
            const float Q = (rsq[row][0] + rsq[row][1]) + (rsq[row][2] + rsq[row][3]);
            const float mean = S * (1.0f / 128.0f);
            const float var  = Q * (1.0f / 128.0f) - mean * mean;
            const float rstd = rsqrtf(var + 1e-5f);
            #pragma unroll
            for (int n = 0; n < 2; n++) {
                const int col = obase + n * 16 + l4;
                const float y = (vv[m][n][r] - mean) * rstd * lng[col] + lnb[col];
                if (HEAD) hacc[m][r] += y * hw[col];
                else Y[(size_t)(bm + row) * 128 + col] = __float2bfloat16(y);
            }
        }
    }

    if (HEAD) {
        __syncthreads();       // reuse rsum
        #pragma unroll
        for (int m = 0; m < 2; m++) {
            #pragma unroll
            for (int r = 0; r < 4; r++) {
                float h = hacc[m][r];
                #pragma unroll
                for (int off = 1; off < 16; off <<= 1) h += __shfl_xor(h, off);
                const int row = m * 16 + g * 4 + r;
                if (l4 == 0) rsum[row][wv] = h;
            }
        }
        __syncthreads();
        if (tid < 32)
            hout[bm + tid] = (rsum[tid][0] + rsum[tid][1]) + (rsum[tid][2] + rsum[tid][3]);
    }
}

// ---------------------------------------------------------------------------
// Merged fp32->bf16 conversion of all weights + x, plus t2v table (segment 9).
// ---------------------------------------------------------------------------
struct ConvDesc {
    const float *x, *s1, *s2, *s3, *s4, *s5, *s6, *s7, *s8;
    bf16 *dx, *d1, *d2, *d3, *d4, *d5, *d6, *d7, *d8;
    const float *w, *b, *w0, *b0;
    float* tbl;
};

__device__ inline void cvt4(const float* s, bf16* d, int j) {
    float4 v = ((const float4*)s)[j];
    ushort4 o;
    o.x = (unsigned short)f2bs(v.x); o.y = (unsigned short)f2bs(v.y);
    o.z = (unsigned short)f2bs(v.z); o.w = (unsigned short)f2bs(v.w);
    *(ushort4*)((unsigned short*)d + j * 4) = o;
}

// prefix sums in float4 units
#define CP0 524288   // x            (2097152)
#define CP1 536576   // enc_in_w     (49152)
#define CP2 540672   // enc_out_w    (16384)
#define CP3 606208   // enc_l1w      (262144)
#define CP4 671744   // enc_l2w      (262144)
#define CP5 696320   // qk_in_w      (98304)
#define CP6 704512   // qk_out_w     (32768)
#define CP7 835584   // qk_l1w       (524288)
#define CP8 966656   // qk_l2w       (524288)
#define CP9 967680   // t2v table    (4096 fp32)

__global__ __launch_bounds__(256) void conv_all_kernel(ConvDesc cd)
{
    int i = blockIdx.x * 256 + threadIdx.x;
    if (i < CP0)      cvt4(cd.x,  cd.dx, i);
    else if (i < CP1) cvt4(cd.s1, cd.d1, i - CP0);
    else if (i < CP2) cvt4(cd.s2, cd.d2, i - CP1);
    else if (i < CP3) cvt4(cd.s3, cd.d3, i - CP2);
    else if (i < CP4) cvt4(cd.s4, cd.d4, i - CP3);
    else if (i < CP5) cvt4(cd.s5, cd.d5, i - CP4);
    else if (i < CP6) cvt4(cd.s6, cd.d6, i - CP5);
    else if (i < CP7) cvt4(cd.s7, cd.d7, i - CP6);
    else if (i < CP8) cvt4(cd.s8, cd.d8, i - CP7);
    else if (i < CP9) {
        int e = (i - CP8) * 4;
        int t = e >> 7;
        float tau = (float)(t + 1);
        float4 o;
        #pragma unroll
        for (int k = 0; k < 4; k++) {
            int d = (e + k) & 127;
            ((float*)&o)[k] = (d < 127) ? sinf(tau * cd.w[d] + cd.b[d])
                                        : (tau * cd.w0[0] + cd.b0[0]);
        }
        *(float4*)(cd.tbl + e) = o;
    }
}

// ---------------------------------------------------------------------------
// Stage-1 attention via MFMA (flash, maxless). One block per (t,h).
// ---------------------------------------------------------------------------
__global__ __launch_bounds__(256) void attn_full_mfma(
    const bf16* __restrict__ Qkv, bf16* __restrict__ C)
{
    __shared__ bf16 Qs[512 * 16];
    __shared__ bf16 Ks[512 * 16];
    __shared__ bf16 Vt[16 * 520];
    __shared__ bf16 Zero[32];          // 64B broadcast zero block

    const int t = blockIdx.x >> 3;
    const int h = blockIdx.x & 7;
    const int tid = threadIdx.x;

    if (tid < 32) ((unsigned short*)Zero)[tid] = 0;

    for (int n = tid; n < 512; n += 256) {
        const unsigned short* row = (const unsigned short*)Qkv + (size_t)(t * 512 + n) * 384 + h * 16;
        uint4 q0 = *(const uint4*)(row);
        uint4 q1 = *(const uint4*)(row + 8);
        uint4 k0 = *(const uint4*)(row + 128);
        uint4 k1 = *(const uint4*)(row + 136);
        uint4 v0 = *(const uint4*)(row + 256);
        uint4 v1 = *(const uint4*)(row + 264);
        *(uint4*)((unsigned short*)Qs + n * 16)     = q0;
        *(uint4*)((unsigned short*)Qs + n * 16 + 8) = q1;
        *(uint4*)((unsigned short*)Ks + n * 16)     = k0;
        *(uint4*)((unsigned short*)Ks + n * 16 + 8) = k1;
        union { uint4 u[2]; unsigned short s[16]; } vb;
        vb.u[0] = v0; vb.u[1] = v1;
        #pragma unroll
        for (int f = 0; f < 16; f++)
            ((unsigned short*)Vt)[f * 520 + n] = vb.s[f];
    }
    __syncthreads();

    const int lane = tid & 63;
    const int wv   = tid >> 6;
    const int l4   = lane & 15;
    const int g    = lane >> 4;
    const int qbase = wv * 128;
    const bf16* zp = Zero + (g & 1) * 8;
    const int p0 = ((l4 >> 2) << 3) | (l4 & 3);      // pi0 key permutation

    bf16x8 qf[8];
    #pragma unroll
    for (int qt = 0; qt < 8; qt++) {
        const bf16* ap = (g < 2) ? (Qs + (qbase + qt * 16 + l4) * 16 + g * 8) : zp;
        qf[qt] = *(const bf16x8*)ap;
    }

    f32x4 Oacc[8];
    float lsum[8];
    #pragma unroll
    for (int qt = 0; qt < 8; qt++) { Oacc[qt] = (f32x4){0.f,0.f,0.f,0.f}; lsum[qt] = 0.f; }

    const float cexp = 0.25f * 1.44269504088896f;   // scale * log2(e)

    for (int kt = 0; kt < 16; kt++) {               // 32 keys per iteration
        const bf16* k0p = (g < 2) ? (Ks + (kt * 32 + p0)     * 16 + g * 8) : zp;
        const bf16* k1p = (g < 2) ? (Ks + (kt * 32 + p0 + 4) * 16 + g * 8) : zp;
        bf16x8 kf0 = *(const bf16x8*)k0p;
        bf16x8 kf1 = *(const bf16x8*)k1p;
        bf16x8 vf  = *(const bf16x8*)(Vt + l4 * 520 + kt * 32 + g * 8);

        #pragma unroll
        for (int qt = 0; qt < 8; qt++) {
            f32x4 z = (f32x4){0.f,0.f,0.f,0.f};
            f32x4 s0 = MFMA16(kf0, qf[qt], z);
            f32x4 s1 = MFMA16(kf1, qf[qt], z);
            float e[8];
            #pragma unroll
            for (int r = 0; r < 4; r++) {
                e[r]     = exp2f(s0[r] * cexp);
                e[4 + r] = exp2f(s1[r] * cexp);
            }
            lsum[qt] += ((e[0]+e[1])+(e[2]+e[3])) + ((e[4]+e[5])+(e[6]+e[7]));
            bf16x8 pf;
            #pragma unroll
            for (int i = 0; i < 8; i++) pf[i] = f2bs(e[i]);
            Oacc[qt] = MFMA16(pf, vf, Oacc[qt]);
        }
    }

    #pragma unroll
    for (int qt = 0; qt < 8; qt++) {
        float ls = lsum[qt];
        ls += __shfl_xor(ls, 16);
        ls += __shfl_xor(ls, 32);
        #pragma unroll
        for (int r = 0; r < 4; r++) {
            float lq = __shfl(ls, g * 4 + r);
            float o = Oacc[qt][r] / lq;
            int qrow = t * 512 + qbase + qt * 16 + g * 4 + r;
            C[(size_t)qrow * 128 + h * 16 + l4] = __float2bfloat16(o);
        }
    }
}

// ---------------------------------------------------------------------------
// Stage-3 banded attention: window j in [i-7, i]. bf16 q/k/v in, bf16 out.
// ---------------------------------------------------------------------------
__global__ __launch_bounds__(256) void attn_banded_kernel(
    const bf16* __restrict__ Qkv, const bf16* __restrict__ Vb, bf16* __restrict__ C)
{
    __shared__ float Qs[TT][129];
    __shared__ float Ksh[TT][129];
    __shared__ float Vs[TT][129];
    const int n = blockIdx.x;
    const int tid = threadIdx.x;

    for (int e = tid; e < TT * DD; e += 256) {
        int t = e >> 7, d = e & 127;
        const bf16* row = Qkv + (size_t)(t * NN + n) * 384;
        Qs[t][d]  = __bfloat162float(row[d]);
        Ksh[t][d] = __bfloat162float(row[128 + d]);
        Vs[t][d]  = __bfloat162float(Vb[(size_t)(t * NN + n) * DD + d]);
    }
    __syncthreads();

    const int h = tid >> 5, i = tid & 31;
    const int hb = h * DH;

    float s[WND_];
    #pragma unroll
    for (int kk = 0; kk < WND_; kk++) {
        int j = i - (WND_ - 1) + kk;
        int jc = j < 0 ? 0 : j;
        float d = 0.f;
        #pragma unroll
        for (int f = 0; f < DH; f++) d += Qs[i][hb + f] * Ksh[jc][hb + f];
        s[kk] = (j >= 0) ? d * 0.25f : -1e30f;
    }
    float m = s[0];
    #pragma unroll
    for (int kk = 1; kk < WND_; kk++) m = fmaxf(m, s[kk]);
    float l = 0.f, p[WND_];
    #pragma unroll
    for (int kk = 0; kk < WND_; kk++) { p[kk] = __expf(s[kk] - m); l += p[kk]; }
    float inv = 1.f / l;
    float acc[DH] = {};
    #pragma unroll
    for (int kk = 0; kk < WND_; kk++) {
        int j = i - (WND_ - 1) + kk;
        int jc = j < 0 ? 0 : j;
        float pw = p[kk] * inv;
        #pragma unroll
        for (int f = 0; f < DH; f++) acc[f] += pw * Vs[jc][hb + f];
    }
    bf16* cp = C + (size_t)(i * NN + n) * DD + hb;
    #pragma unroll
    for (int f = 0; f < DH; f++) cp[f] = __float2bfloat16(acc[f]);
}

// ---------------------------------------------------------------------------
// time2vec add: Y = bf16(x + tbl[t, d])
// ---------------------------------------------------------------------------
__global__ __launch_bounds__(256) void t2v_add_kernel(
    const float* __restrict__ x, const float* __restrict__ tbl, bf16* __restrict__ Y)
{
    int i = blockIdx.x * 256 + threadIdx.x;     // float4 groups
    int e = i * 4;
    float4 xv = ((const float4*)x)[i];
    int ti = ((e >> 16) << 7) | (e & 127);
    float4 tv = *(const float4*)(tbl + ti);
    ushort4 o;
    o.x = (unsigned short)f2bs(xv.x + tv.x);
    o.y = (unsigned short)f2bs(xv.y + tv.y);
    o.z = (unsigned short)f2bs(xv.z + tv.z);
    o.w = (unsigned short)f2bs(xv.w + tv.w);
    *(ushort4*)((unsigned short*)Y + e) = o;
}

// ---------------------------------------------------------------------------

extern "C" void kernel_launch(void* const* d_in, const int* in_sizes, int n_in,
                              void* d_out, int out_size, void* d_ws, size_t ws_size,
                              hipStream_t stream) {
    const float* x           = (const float*)d_in[0];
    const float* enc_in_w    = (const float*)d_in[1];
    const float* enc_in_b    = (const float*)d_in[2];
    const float* enc_out_w   = (const float*)d_in[3];
    const float* enc_out_b   = (const float*)d_in[4];
    const float* enc_l1w     = (const float*)d_in[5];
    const float* enc_l1b     = (const float*)d_in[6];
    const float* enc_l2w     = (const float*)d_in[7];
    const float* enc_l2b     = (const float*)d_in[8];
    const float* enc_ln1w    = (const float*)d_in[9];
    const float* enc_ln1b    = (const float*)d_in[10];
    const float* enc_ln2w    = (const float*)d_in[11];
    const float* enc_ln2b    = (const float*)d_in[12];
    const float* qk_in_w     = (const float*)d_in[13];
    const float* qk_in_b     = (const float*)d_in[14];
    const float* qk_out_w    = (const float*)d_in[15];
    const float* qk_out_b    = (const float*)d_in[16];
    const float* qk_l1w      = (const float*)d_in[17];
    const float* qk_l1b      = (const float*)d_in[18];
    const float* qk_l2w      = (const float*)d_in[19];
    const float* qk_l2b      = (const float*)d_in[20];
    const float* qk_ln1w     = (const float*)d_in[21];
    const float* qk_ln1b     = (const float*)d_in[22];
    const float* qk_ln2w     = (const float*)d_in[23];
    const float* qk_ln2b     = (const float*)d_in[24];
    const float* t2v_w       = (const float*)d_in[25];
    const float* t2v_b       = (const float*)d_in[26];
    const float* t2v_w0      = (const float*)d_in[27];
    const float* t2v_b0      = (const float*)d_in[28];
    const float* out_w       = (const float*)d_in[29];
    float* out = (float*)d_out;

    // ---------------- workspace layout (bytes) ------------------------------
    char* ws = (char*)d_ws;
    const size_t TOKD = (size_t)TOK * DD;
    size_t off = 0;
    auto alloc = [&](size_t bytes) { char* p = ws + off; off += (bytes + 255) & ~(size_t)255; return p; };

    bf16*  Qb   = (bf16*)alloc((size_t)TOK * 384 * 2);   // qkv bf16
    bf16*  Vb   = (bf16*)alloc(TOKD * 2);                // v-projection bf16
    bf16*  xb   = (bf16*)alloc(TOKD * 2);                // bf16 copy of x
    bf16*  bufA = (bf16*)alloc(TOKD * 2);                // residual stream bf16
    bf16*  Zb   = (bf16*)alloc(TOKD * 2);                // outs_zs bf16
    bf16*  Cb   = (bf16*)alloc(TOKD * 2);                // attn context bf16
    float* t2vt = (float*)alloc((size_t)TT * DD * 4);    // time2vec table
    bf16* enc_in_wb  = (bf16*)alloc(384 * DD * 2);
    bf16* enc_out_wb = (bf16*)alloc(DD * DD * 2);
    bf16* enc_l1wb   = (bf16*)alloc((size_t)FF_ * DD * 2);
    bf16* enc_l2wb   = (bf16*)alloc((size_t)DD * FF_ * 2);
    bf16* qk_in_wb   = (bf16*)alloc((size_t)LL * 384 * DD * 2);
    bf16* qk_out_wb  = (bf16*)alloc((size_t)LL * DD * DD * 2);
    bf16* qk_l1wb    = (bf16*)alloc((size_t)LL * FF_ * DD * 2);
    bf16* qk_l2wb    = (bf16*)alloc((size_t)LL * DD * FF_ * 2);

    // ---------------- one-shot conversion of all weights + x + t2v table ----
    ConvDesc cd;
    cd.x  = x;        cd.dx = xb;
    cd.s1 = enc_in_w; cd.d1 = enc_in_wb;
    cd.s2 = enc_out_w;cd.d2 = enc_out_wb;
    cd.s3 = enc_l1w;  cd.d3 = enc_l1wb;
    cd.s4 = enc_l2w;  cd.d4 = enc_l2wb;
    cd.s5 = qk_in_w;  cd.d5 = qk_in_wb;
    cd.s6 = qk_out_w; cd.d6 = qk_out_wb;
    cd.s7 = qk_l1w;   cd.d7 = qk_l1wb;
    cd.s8 = qk_l2w;   cd.d8 = qk_l2wb;
    cd.w = t2v_w; cd.b = t2v_b; cd.w0 = t2v_w0; cd.b0 = t2v_b0; cd.tbl = t2vt;
    conv_all_kernel<<<(CP9 + 255) / 256, 256, 0, stream>>>(cd);

    auto gemm128 = [&](const bf16* A, int lda, const bf16* W, const float* bias,
                       bf16* C, int ldc, int M, int N, int K, int relu) {
        dim3 grid(N / 128, M / 128);
        mfma_gemm<128, 128><<<grid, 256, 0, stream>>>(A, lda, W, bias, C, ldc, K, relu);
    };
    auto gemm64 = [&](const bf16* A, int lda, const bf16* W, const float* bias,
                      bf16* C, int ldc, int M, int N, int K, int relu) {
        dim3 grid(N / 64, M / 64);
        mfma_gemm<64, 64><<<grid, 256, 0, stream>>>(A, lda, W, bias, C, ldc, K, relu);
    };
    auto gemm_ln = [&](const bf16* A, int lda, const bf16* W, const float* bias,
                       const bf16* R, const float* lng, const float* lnb,
                       bf16* Y, int M, int K) {
        mfma_gemm_ln<<<M / 64, 256, 0, stream>>>(A, lda, W, bias, R, lng, lnb, Y, K);
    };

    // ---------------- stage 1: plain encoder (attend over N, batch T) -------
    gemm128(xb, DD, enc_in_wb, enc_in_b, Qb, 384, TOK, 384, DD, 0);
    attn_full_mfma<<<TT * HH, 256, 0, stream>>>(Qb, Cb);
    gemm_ln(Cb, DD, enc_out_wb, enc_out_b, xb, enc_ln1w, enc_ln1b, bufA, TOK, DD);
    ffn_fused<false><<<TOK / 32, 256, 0, stream>>>(
        bufA, enc_l1wb, enc_l1b, enc_l2wb, enc_l2b,
        enc_ln2w, enc_ln2b, Zb, nullptr, nullptr);

    // ---------------- stage 2: time2vec -------------------------------------
    t2v_add_kernel<<<(TOK * DD / 4) / 256, 256, 0, stream>>>(x, t2vt, bufA);

    // ---------------- stage 3: qk encoder stack (banded window attn) ---------
    for (int l = 0; l < LL; l++) {
        const bf16* iw   = qk_in_wb  + (size_t)l * 384 * DD;
        const float* ib  = qk_in_b   + (size_t)l * 384;
        const bf16* owt  = qk_out_wb + (size_t)l * DD * DD;
        const float* ob  = qk_out_b  + (size_t)l * DD;
        const bf16* l1w  = qk_l1wb   + (size_t)l * FF_ * DD;
        const float* l1b = qk_l1b    + (size_t)l * FF_;
        const bf16* l2w  = qk_l2wb   + (size_t)l * DD * FF_;
        const float* l2b = qk_l2b    + (size_t)l * DD;

        gemm128(bufA, DD, iw, ib, Qb, 384, TOK, 256, DD, 0);
        gemm64(Zb, DD, iw + (size_t)256 * DD, ib + 256, Vb, DD, TOK, DD, DD, 0);
        attn_banded_kernel<<<NN, 256, 0, stream>>>(Qb, Vb, Cb);
        gemm_ln(Cb, DD, owt, ob, bufA, qk_ln1w + l * DD, qk_ln1b + l * DD, bufA, TOK, DD);
        if (l == LL - 1) {
            ffn_fused<true><<<TOK / 32, 256, 0, stream>>>(
                bufA, l1w, l1b, l2w, l2b,
                qk_ln2w + l * DD, qk_ln2b + l * DD, nullptr, out_w, out);
        } else {
            ffn_fused<false><<<TOK / 32, 256, 0, stream>>>(
                bufA, l1w, l1b, l2w, l2b,
                qk_ln2w + l * DD, qk_ln2b + l * DD, bufA, nullptr, nullptr);
        }
    }
}

// Round 8
// 252.937 us; speedup vs baseline: 1.3800x; 1.2803x over previous
//
#include <hip/hip_runtime.h>
#include <hip/hip_bf16.h>
#include <math.h>

// Problem constants
#define TT 32
#define NN 512
#define DD 128
#define FF_ 2048
#define HH 8
#define LL 2
#define WND_ 8
#define TOK (TT*NN)          // 16384 tokens
#define DH 16                // head dim

typedef __hip_bfloat16 bf16;
typedef __attribute__((ext_vector_type(8))) short bf16x8;   // 8 bf16 (4 VGPRs)
typedef __attribute__((ext_vector_type(4))) float f32x4;    // 4 fp32

// global_load_lds: 16B per lane, LDS dest = wave-uniform base + lane*16 (linear)
#define GLD_LDS16(gp, lp) __builtin_amdgcn_global_load_lds( \
    (const __attribute__((address_space(1))) unsigned int*)(gp), \
    (__attribute__((address_space(3))) unsigned int*)(lp), 16, 0, 0)

#define MFMA16(a, b, c) __builtin_amdgcn_mfma_f32_16x16x32_bf16((a), (b), (c), 0, 0, 0)

__device__ inline short f2bs(float f) {
    __hip_bfloat16 h = __float2bfloat16(f);
    return *reinterpret_cast<short*>(&h);
}

// ---------------------------------------------------------------------------
// bf16 MFMA GEMM: C[M,N] = A[M,K] @ W[N,K]^T + bias (+relu). Output bf16.
// Tile BM x BN, BK=32, 256 threads = 4 waves in 2x2.
// ---------------------------------------------------------------------------
template<int BM, int BN>
__global__ __launch_bounds__(256) void mfma_gemm(
    const bf16* __restrict__ A, int lda,
    const bf16* __restrict__ W,              // [N,K] row-major (= B^T)
    const float* __restrict__ bias,          // [N]
    bf16* __restrict__ C, int ldc,
    int K, int relu)
{
    constexpr int WM = BM / 2, WN = BN / 2;
    constexpr int FM = WM / 16, FN = WN / 16;
    constexpr int LA = (BM * 64) / (256 * 16);
    constexpr int LB = (BN * 64) / (256 * 16);

    __shared__ bf16 As[BM * 32];
    __shared__ bf16 Bs[BN * 32];

    const int tid  = threadIdx.x;
    const int lane = tid & 63;
    const int wave = tid >> 6;
    const int wm = wave >> 1, wn = wave & 1;
    const int bm = blockIdx.y * BM, bn = blockIdx.x * BN;

    f32x4 acc[FM][FN];
    #pragma unroll
    for (int m = 0; m < FM; m++)
        #pragma unroll
        for (int n = 0; n < FN; n++)
            acc[m][n] = (f32x4){0.f, 0.f, 0.f, 0.f};

    for (int k0 = 0; k0 < K; k0 += 32) {
        #pragma unroll
        for (int i = 0; i < LA; i++) {
            const int o = (tid + i * 256) * 16;
            const int row = o >> 6;
            const int ce  = (o & 63) >> 1;
            GLD_LDS16(A + (size_t)(bm + row) * lda + k0 + ce, (char*)As + o);
        }
        #pragma unroll
        for (int i = 0; i < LB; i++) {
            const int o = (tid + i * 256) * 16;
            const int row = o >> 6;
            const int ce  = (o & 63) >> 1;
            GLD_LDS16(W + (size_t)(bn + row) * K + k0 + ce, (char*)Bs + o);
        }
        __syncthreads();

        bf16x8 af[FM], bfr[FN];
        #pragma unroll
        for (int m = 0; m < FM; m++)
            af[m] = *(const bf16x8*)(As + (wm * WM + m * 16 + (lane & 15)) * 32 + (lane >> 4) * 8);
        #pragma unroll
        for (int n = 0; n < FN; n++)
            bfr[n] = *(const bf16x8*)(Bs + (wn * WN + n * 16 + (lane & 15)) * 32 + (lane >> 4) * 8);
        #pragma unroll
        for (int m = 0; m < FM; m++)
            #pragma unroll
            for (int n = 0; n < FN; n++)
                acc[m][n] = MFMA16(af[m], bfr[n], acc[m][n]);
        __syncthreads();
    }

    // C/D layout: col = lane&15, row = (lane>>4)*4 + reg
    #pragma unroll
    for (int n = 0; n < FN; n++) {
        const int col = bn + wn * WN + n * 16 + (lane & 15);
        const float bv = bias[col];
        #pragma unroll
        for (int m = 0; m < FM; m++) {
            #pragma unroll
            for (int r = 0; r < 4; r++) {
                const int row = bm + wm * WM + m * 16 + (lane >> 4) * 4 + r;
                float v = acc[m][n][r] + bv;
                if (relu) v = fmaxf(v, 0.f);
                C[(size_t)row * ldc + col] = __float2bfloat16(v);
            }
        }
    }
}

// ---------------------------------------------------------------------------
// Fused GEMM + bias + residual + LayerNorm (out_proj path, K small).
// BM=64, BN=128 (full LN row). 256 threads, waves 2x2, each wave 32x64.
// ---------------------------------------------------------------------------
__global__ __launch_bounds__(256) void mfma_gemm_ln(
    const bf16* __restrict__ A, int lda,
    const bf16* __restrict__ W,              // [128,K]
    const float* __restrict__ bias,          // [128]
    const bf16* __restrict__ R,              // residual [M,128] bf16
    const float* __restrict__ lng, const float* __restrict__ lnb,
    bf16* __restrict__ Y,                    // [M,128] bf16
    int K)
{
    constexpr int BM = 64, WM = 32, WN = 64, FM = 2, FN = 4;

    __shared__ bf16 As[BM * 32];
    __shared__ bf16 Bs[128 * 32];
    __shared__ float rsum[BM][2];
    __shared__ float rsq[BM][2];

    const int tid  = threadIdx.x;
    const int lane = tid & 63;
    const int wave = tid >> 6;
    const int wm = wave >> 1, wn = wave & 1;
    const int bm = blockIdx.x * BM;

    f32x4 acc[FM][FN];
    #pragma unroll
    for (int m = 0; m < FM; m++)
        #pragma unroll
        for (int n = 0; n < FN; n++)
            acc[m][n] = (f32x4){0.f, 0.f, 0.f, 0.f};

    for (int k0 = 0; k0 < K; k0 += 32) {
        {   // A tile: 64 rows x 32 cols
            const int o = tid * 16;
            const int row = o >> 6;
            const int ce  = (o & 63) >> 1;
            GLD_LDS16(A + (size_t)(bm + row) * lda + k0 + ce, (char*)As + o);
        }
        #pragma unroll
        for (int i = 0; i < 2; i++) {       // B tile: 128 rows
            const int o = (tid + i * 256) * 16;
            const int row = o >> 6;
            const int ce  = (o & 63) >> 1;
            GLD_LDS16(W + (size_t)row * K + k0 + ce, (char*)Bs + o);
        }
        __syncthreads();

        bf16x8 af[FM], bfr[FN];
        #pragma unroll
        for (int m = 0; m < FM; m++)
            af[m] = *(const bf16x8*)(As + (wm * WM + m * 16 + (lane & 15)) * 32 + (lane >> 4) * 8);
        #pragma unroll
        for (int n = 0; n < FN; n++)
            bfr[n] = *(const bf16x8*)(Bs + (wn * WN + n * 16 + (lane & 15)) * 32 + (lane >> 4) * 8);
        #pragma unroll
        for (int m = 0; m < FM; m++)
            #pragma unroll
            for (int n = 0; n < FN; n++)
                acc[m][n] = MFMA16(af[m], bfr[n], acc[m][n]);
        __syncthreads();
    }

    // bias + residual
    #pragma unroll
    for (int n = 0; n < FN; n++) {
        const int col = wn * WN + n * 16 + (lane & 15);
        const float bv = bias[col];
        #pragma unroll
        for (int m = 0; m < FM; m++) {
            #pragma unroll
            for (int r = 0; r < 4; r++) {
                const int rl = wm * WM + m * 16 + (lane >> 4) * 4 + r;
                acc[m][n][r] += bv + __bfloat162float(R[(size_t)(bm + rl) * 128 + col]);
            }
        }
    }

    // row sums
    #pragma unroll
    for (int m = 0; m < FM; m++) {
        #pragma unroll
        for (int r = 0; r < 4; r++) {
            float s = 0.f, q = 0.f;
            #pragma unroll
            for (int n = 0; n < FN; n++) { float v = acc[m][n][r]; s += v; q += v * v; }
            #pragma unroll
            for (int off = 1; off < 16; off <<= 1) {
                s += __shfl_xor(s, off);
                q += __shfl_xor(q, off);
            }
            const int rl = wm * WM + m * 16 + (lane >> 4) * 4 + r;
            if ((lane & 15) == 0) { rsum[rl][wn] = s; rsq[rl][wn] = q; }
        }
    }
    __syncthreads();

    #pragma unroll
    for (int m = 0; m < FM; m++) {
        #pragma unroll
        for (int r = 0; r < 4; r++) {
            const int rl = wm * WM + m * 16 + (lane >> 4) * 4 + r;
            const float S = rsum[rl][0] + rsum[rl][1];
            const float Q = rsq[rl][0] + rsq[rl][1];
            const float mean = S * (1.0f / 128.0f);
            const float var  = Q * (1.0f / 128.0f) - mean * mean;
            const float rstd = rsqrtf(var + 1e-5f);
            #pragma unroll
            for (int n = 0; n < FN; n++) {
                const int col = wn * WN + n * 16 + (lane & 15);
                const float y = (acc[m][n][r] - mean) * rstd * lng[col] + lnb[col];
                Y[(size_t)(bm + rl) * 128 + col] = __float2bfloat16(y);
            }
        }
    }
}

// ---------------------------------------------------------------------------
// FFN v3: Y = LN( A + (relu(A@W1^T+b1) @ W2^T + b2) ) [* head]
// Grid 256 x 512 threads. Block = 64 tokens; 8 waves = 4 token-tiles (tt) x
// 2 hidden-halves (hh). Hidden activations NEVER touch LDS or HBM: phase-1
// computes H^T = MFMA(W1rows, tokens) with W1 rows staged pi-permuted
// (pi(q) = (q>>2)*8 + (q&3), +4 for rows 16..31) so each lane's packed 8 H
// values are exactly k-elements 8g..8g+7 -> the phase-2 A-fragment directly
// (attention kernel's P->PV trick). Weights staged per 32-col window into LDS
// via global_load_lds (linear dest, XOR-swizzled W1 SOURCE col, swizzled
// read: conflict-free b128), double-buffered, one barrier/iter (m97 style).
// Half-partials reduced via 32 KB LDS; epilogue bias+residual+LN (+head).
// ---------------------------------------------------------------------------
template<bool HEAD>
__global__ __launch_bounds__(512) void ffn_fused(
    const bf16* __restrict__ A,              // [M,128]  input = residual
    const bf16* __restrict__ W1, const float* __restrict__ b1,   // [2048,128],[2048]
    const bf16* __restrict__ W2, const float* __restrict__ b2,   // [128,2048],[128]
    const float* __restrict__ lng, const float* __restrict__ lnb,
    bf16* __restrict__ Y,                    // [M,128] (unused if HEAD)
    const float* __restrict__ hw, float* __restrict__ hout)
{
    __shared__ bf16  W1s[2][2][32 * 128];    // [dbuf][half]  8 KB each -> 32 KB
    __shared__ bf16  W2s[2][2][128 * 32];    // 32 KB
    __shared__ float Red[4][16 * 128];       // 32 KB half-reduce

    const int tid  = threadIdx.x;
    const int lane = tid & 63;
    const int wv   = tid >> 6;               // 0..7
    const int tt   = wv & 3;                 // token tile (16 tokens)
    const int hh   = wv >> 2;                // hidden half
    const int l4   = lane & 15;
    const int g    = lane >> 4;
    const int bm   = blockIdx.x * 64;

    // token B-fragments (lane&15 = token col, k = j*32 + g*8), L2-hot
    bf16x8 tf[4];
    #pragma unroll
    for (int j = 0; j < 4; j++)
        tf[j] = *(const bf16x8*)(A + (size_t)(bm + tt * 16 + l4) * 128 + j * 32 + g * 8);

    // staging geometry (per thread, one 16B gld per buffer)
    const int q    = tid >> 4;                                   // W1 LDS row slot 0..31
    const int qq   = q & 15;
    const int piq  = (((qq >> 2) << 3) | (qq & 3)) + ((q >> 4) << 2);  // pi(q)
    const int w1cb = ((tid & 15) * 16) ^ ((q & 7) << 4);         // swizzled source byte
    const int w2row = tid >> 2;
    const int w2ce  = (tid & 3) * 8;

    auto STAGE = [&](int d, int s) {
        #pragma unroll
        for (int hx = 0; hx < 2; hx++) {
            const int c0 = hx * 1024 + s * 32;
            GLD_LDS16((const char*)W1 + (size_t)(c0 + piq) * 256 + w1cb,
                      (char*)W1s[d][hx] + tid * 16);
            GLD_LDS16(W2 + (size_t)w2row * 2048 + c0 + w2ce,
                      (char*)W2s[d][hx] + tid * 16);
        }
    };

    f32x4 Oacc[8];
    #pragma unroll
    for (int ot = 0; ot < 8; ot++) Oacc[ot] = (f32x4){0.f, 0.f, 0.f, 0.f};

    const f32x4 zz = (f32x4){0.f, 0.f, 0.f, 0.f};
    const int xsw = (l4 & 7) << 4;

    STAGE(0, 0);
    for (int s = 0; s < 32; s++) {
        __syncthreads();                     // drains staged loads for buf s&1
        if (s < 31) STAGE((s + 1) & 1, s + 1);   // async, flies during compute
        const int d  = s & 1;
        const int c0 = hh * 1024 + s * 32;
        const bf16* w1b = W1s[d][hh];
        const bf16* w2b = W2s[d][hh];

        // phase 1: H^T for 32 hidden cols (rows pi-permuted in LDS)
        f32x4 sa0 = zz, sa1 = zz;
        #pragma unroll
        for (int j = 0; j < 4; j++) {
            const int xo = (j * 64 + g * 16) ^ xsw;
            bf16x8 w10 = *(const bf16x8*)((const char*)w1b + l4 * 256 + xo);
            bf16x8 w11 = *(const bf16x8*)((const char*)w1b + (16 + l4) * 256 + xo);
            sa0 = MFMA16(w10, tf[j], sa0);
            sa1 = MFMA16(w11, tf[j], sa1);
        }
        // bias + relu + pack: lane holds hidden cols c0 + 8g + {0..7}
        float4 bv0 = *(const float4*)(b1 + c0 + g * 8);
        float4 bv1 = *(const float4*)(b1 + c0 + g * 8 + 4);
        bf16x8 pf;
        pf[0] = f2bs(fmaxf(sa0[0] + bv0.x, 0.f));
        pf[1] = f2bs(fmaxf(sa0[1] + bv0.y, 0.f));
        pf[2] = f2bs(fmaxf(sa0[2] + bv0.z, 0.f));
        pf[3] = f2bs(fmaxf(sa0[3] + bv0.w, 0.f));
        pf[4] = f2bs(fmaxf(sa1[0] + bv1.x, 0.f));
        pf[5] = f2bs(fmaxf(sa1[1] + bv1.y, 0.f));
        pf[6] = f2bs(fmaxf(sa1[2] + bv1.z, 0.f));
        pf[7] = f2bs(fmaxf(sa1[3] + bv1.w, 0.f));

        // phase 2: accumulate all 128 output cols over this k-window
        #pragma unroll
        for (int ot = 0; ot < 8; ot++) {
            bf16x8 w2f = *(const bf16x8*)((const char*)w2b + (ot * 16 + l4) * 64 + g * 16);
            Oacc[ot] = MFMA16(pf, w2f, Oacc[ot]);
        }
    }

    // ---- reduce hidden halves ----
    __syncthreads();
    if (hh == 1) {
        #pragma unroll
        for (int ot = 0; ot < 8; ot++)
            *(f32x4*)((char*)Red + tt * 8192 + ot * 1024 + lane * 16) = Oacc[ot];
    }
    __syncthreads();
    if (hh == 0) {
        #pragma unroll
        for (int ot = 0; ot < 8; ot++) {
            f32x4 o2 = *(const f32x4*)((const char*)Red + tt * 8192 + ot * 1024 + lane * 16);
            Oacc[ot][0] += o2[0]; Oacc[ot][1] += o2[1];
            Oacc[ot][2] += o2[2]; Oacc[ot][3] += o2[3];
        }

        // bias + residual;  lane: col = ot*16 + l4, token = tt*16 + 4g + r
        float vv[8][4];
        #pragma unroll
        for (int ot = 0; ot < 8; ot++) {
            const int col = ot * 16 + l4;
            const float bv = b2[col];
            #pragma unroll
            for (int r = 0; r < 4; r++) {
                const int trow = bm + tt * 16 + 4 * g + r;
                vv[ot][r] = Oacc[ot][r] + bv
                          + __bfloat162float(A[(size_t)trow * 128 + col]);
            }
        }

        // LN row stats: in-lane over ot, shfl over 16-lane col group
        #pragma unroll
        for (int r = 0; r < 4; r++) {
            float sm = 0.f, qs = 0.f;
            #pragma unroll
            for (int ot = 0; ot < 8; ot++) { float v = vv[ot][r]; sm += v; qs += v * v; }
            #pragma unroll
            for (int off = 1; off < 16; off <<= 1) {
                sm += __shfl_xor(sm, off);
                qs += __shfl_xor(qs, off);
            }
            const float mean = sm * (1.0f / 128.0f);
            const float var  = qs * (1.0f / 128.0f) - mean * mean;
            const float rstd = rsqrtf(var + 1e-5f);
            const int trow = bm + tt * 16 + 4 * g + r;
            float hacc = 0.f;
            #pragma unroll
            for (int ot = 0; ot < 8; ot++) {
                const int col = ot * 16 + l4;
                const float y = (vv[ot][r] - mean) * rstd * lng[col] + lnb[col];
                if (HEAD) hacc += y * hw[col];
                else Y[(size_t)trow * 128 + col] = __float2bfloat16(y);
            }
            if (HEAD) {
                #pragma unroll
                for (int off = 1; off < 16; off <<= 1) hacc += __shfl_xor(hacc, off);
                if (l4 == 0) hout[trow] = hacc;
            }
        }
    }
}

// ---------------------------------------------------------------------------
// Merged fp32->bf16 conversion of all weights + x, plus t2v table (segment 9).
// ---------------------------------------------------------------------------
struct ConvDesc {
    const float *x, *s1, *s2, *s3, *s4, *s5, *s6, *s7, *s8;
    bf16 *dx, *d1, *d2, *d3, *d4, *d5, *d6, *d7, *d8;
    const float *w, *b, *w0, *b0;
    float* tbl;
};

__device__ inline void cvt4(const float* s, bf16* d, int j) {
    float4 v = ((const float4*)s)[j];
    ushort4 o;
    o.x = (unsigned short)f2bs(v.x); o.y = (unsigned short)f2bs(v.y);
    o.z = (unsigned short)f2bs(v.z); o.w = (unsigned short)f2bs(v.w);
    *(ushort4*)((unsigned short*)d + j * 4) = o;
}

// prefix sums in float4 units
#define CP0 524288   // x            (2097152)
#define CP1 536576   // enc_in_w     (49152)
#define CP2 540672   // enc_out_w    (16384)
#define CP3 606208   // enc_l1w      (262144)
#define CP4 671744   // enc_l2w      (262144)
#define CP5 696320   // qk_in_w      (98304)
#define CP6 704512   // qk_out_w     (32768)
#define CP7 835584   // qk_l1w       (524288)
#define CP8 966656   // qk_l2w       (524288)
#define CP9 967680   // t2v table    (4096 fp32)

__global__ __launch_bounds__(256) void conv_all_kernel(ConvDesc cd)
{
    int i = blockIdx.x * 256 + threadIdx.x;
    if (i < CP0)      cvt4(cd.x,  cd.dx, i);
    else if (i < CP1) cvt4(cd.s1, cd.d1, i - CP0);
    else if (i < CP2) cvt4(cd.s2, cd.d2, i - CP1);
    else if (i < CP3) cvt4(cd.s3, cd.d3, i - CP2);
    else if (i < CP4) cvt4(cd.s4, cd.d4, i - CP3);
    else if (i < CP5) cvt4(cd.s5, cd.d5, i - CP4);
    else if (i < CP6) cvt4(cd.s6, cd.d6, i - CP5);
    else if (i < CP7) cvt4(cd.s7, cd.d7, i - CP6);
    else if (i < CP8) cvt4(cd.s8, cd.d8, i - CP7);
    else if (i < CP9) {
        int e = (i - CP8) * 4;
        int t = e >> 7;
        float tau = (float)(t + 1);
        float4 o;
        #pragma unroll
        for (int k = 0; k < 4; k++) {
            int d = (e + k) & 127;
            ((float*)&o)[k] = (d < 127) ? sinf(tau * cd.w[d] + cd.b[d])
                                        : (tau * cd.w0[0] + cd.b0[0]);
        }
        *(float4*)(cd.tbl + e) = o;
    }
}

// ---------------------------------------------------------------------------
// Stage-1 attention via MFMA (flash, maxless). One block per (t,h).
// ---------------------------------------------------------------------------
__global__ __launch_bounds__(256) void attn_full_mfma(
    const bf16* __restrict__ Qkv, bf16* __restrict__ C)
{
    __shared__ bf16 Qs[512 * 16];
    __shared__ bf16 Ks[512 * 16];
    __shared__ bf16 Vt[16 * 520];
    __shared__ bf16 Zero[32];          // 64B broadcast zero block

    const int t = blockIdx.x >> 3;
    const int h = blockIdx.x & 7;
    const int tid = threadIdx.x;

    if (tid < 32) ((unsigned short*)Zero)[tid] = 0;

    for (int n = tid; n < 512; n += 256) {
        const unsigned short* row = (const unsigned short*)Qkv + (size_t)(t * 512 + n) * 384 + h * 16;
        uint4 q0 = *(const uint4*)(row);
        uint4 q1 = *(const uint4*)(row + 8);
        uint4 k0 = *(const uint4*)(row + 128);
        uint4 k1 = *(const uint4*)(row + 136);
        uint4 v0 = *(const uint4*)(row + 256);
        uint4 v1 = *(const uint4*)(row + 264);
        *(uint4*)((unsigned short*)Qs + n * 16)     = q0;
        *(uint4*)((unsigned short*)Qs + n * 16 + 8) = q1;
        *(uint4*)((unsigned short*)Ks + n * 16)     = k0;
        *(uint4*)((unsigned short*)Ks + n * 16 + 8) = k1;
        union { uint4 u[2]; unsigned short s[16]; } vb;
        vb.u[0] = v0; vb.u[1] = v1;
        #pragma unroll
        for (int f = 0; f < 16; f++)
            ((unsigned short*)Vt)[f * 520 + n] = vb.s[f];
    }
    __syncthreads();

    const int lane = tid & 63;
    const int wv   = tid >> 6;
    const int l4   = lane & 15;
    const int g    = lane >> 4;
    const int qbase = wv * 128;
    const bf16* zp = Zero + (g & 1) * 8;
    const int p0 = ((l4 >> 2) << 3) | (l4 & 3);      // pi0 key permutation

    bf16x8 qf[8];
    #pragma unroll
    for (int qt = 0; qt < 8; qt++) {
        const bf16* ap = (g < 2) ? (Qs + (qbase + qt * 16 + l4) * 16 + g * 8) : zp;
        qf[qt] = *(const bf16x8*)ap;
    }

    f32x4 Oacc[8];
    float lsum[8];
    #pragma unroll
    for (int qt = 0; qt < 8; qt++) { Oacc[qt] = (f32x4){0.f,0.f,0.f,0.f}; lsum[qt] = 0.f; }

    const float cexp = 0.25f * 1.44269504088896f;   // scale * log2(e)

    for (int kt = 0; kt < 16; kt++) {               // 32 keys per iteration
        const bf16* k0p = (g < 2) ? (Ks + (kt * 32 + p0)     * 16 + g * 8) : zp;
        const bf16* k1p = (g < 2) ? (Ks + (kt * 32 + p0 + 4) * 16 + g * 8) : zp;
        bf16x8 kf0 = *(const bf16x8*)k0p;
        bf16x8 kf1 = *(const bf16x8*)k1p;
        bf16x8 vf  = *(const bf16x8*)(Vt + l4 * 520 + kt * 32 + g * 8);

        #pragma unroll
        for (int qt = 0; qt < 8; qt++) {
            f32x4 z = (f32x4){0.f,0.f,0.f,0.f};
            f32x4 s0 = MFMA16(kf0, qf[qt], z);
            f32x4 s1 = MFMA16(kf1, qf[qt], z);
            float e[8];
            #pragma unroll
            for (int r = 0; r < 4; r++) {
                e[r]     = exp2f(s0[r] * cexp);
                e[4 + r] = exp2f(s1[r] * cexp);
            }
            lsum[qt] += ((e[0]+e[1])+(e[2]+e[3])) + ((e[4]+e[5])+(e[6]+e[7]));
            bf16x8 pf;
            #pragma unroll
            for (int i = 0; i < 8; i++) pf[i] = f2bs(e[i]);
            Oacc[qt] = MFMA16(pf, vf, Oacc[qt]);
        }
    }

    #pragma unroll
    for (int qt = 0; qt < 8; qt++) {
        float ls = lsum[qt];
        ls += __shfl_xor(ls, 16);
        ls += __shfl_xor(ls, 32);
        #pragma unroll
        for (int r = 0; r < 4; r++) {
            float lq = __shfl(ls, g * 4 + r);
            float o = Oacc[qt][r] / lq;
            int qrow = t * 512 + qbase + qt * 16 + g * 4 + r;
            C[(size_t)qrow * 128 + h * 16 + l4] = __float2bfloat16(o);
        }
    }
}

// ---------------------------------------------------------------------------
// Stage-3 banded attention: window j in [i-7, i]. bf16 q/k/v in, bf16 out.
// ---------------------------------------------------------------------------
__global__ __launch_bounds__(256) void attn_banded_kernel(
    const bf16* __restrict__ Qkv, const bf16* __restrict__ Vb, bf16* __restrict__ C)
{
    __shared__ float Qs[TT][129];
    __shared__ float Ksh[TT][129];
    __shared__ float Vs[TT][129];
    const int n = blockIdx.x;
    const int tid = threadIdx.x;

    for (int e = tid; e < TT * DD; e += 256) {
        int t = e >> 7, d = e & 127;
        const bf16* row = Qkv + (size_t)(t * NN + n) * 384;
        Qs[t][d]  = __bfloat162float(row[d]);
        Ksh[t][d] = __bfloat162float(row[128 + d]);
        Vs[t][d]  = __bfloat162float(Vb[(size_t)(t * NN + n) * DD + d]);
    }
    __syncthreads();

    const int h = tid >> 5, i = tid & 31;
    const int hb = h * DH;

    float s[WND_];
    #pragma unroll
    for (int kk = 0; kk < WND_; kk++) {
        int j = i - (WND_ - 1) + kk;
        int jc = j < 0 ? 0 : j;
        float d = 0.f;
        #pragma unroll
        for (int f = 0; f < DH; f++) d += Qs[i][hb + f] * Ksh[jc][hb + f];
        s[kk] = (j >= 0) ? d * 0.25f : -1e30f;
    }
    float m = s[0];
    #pragma unroll
    for (int kk = 1; kk < WND_; kk++) m = fmaxf(m, s[kk]);
    float l = 0.f, p[WND_];
    #pragma unroll
    for (int kk = 0; kk < WND_; kk++) { p[kk] = __expf(s[kk] - m); l += p[kk]; }
    float inv = 1.f / l;
    float acc[DH] = {};
    #pragma unroll
    for (int kk = 0; kk < WND_; kk++) {
        int j = i - (WND_ - 1) + kk;
        int jc = j < 0 ? 0 : j;
        float pw = p[kk] * inv;
        #pragma unroll
        for (int f = 0; f < DH; f++) acc[f] += pw * Vs[jc][hb + f];
    }
    bf16* cp = C + (size_t)(i * NN + n) * DD + hb;
    #pragma unroll
    for (int f = 0; f < DH; f++) cp[f] = __float2bfloat16(acc[f]);
}

// ---------------------------------------------------------------------------
// time2vec add: Y = bf16(x + tbl[t, d])
// ---------------------------------------------------------------------------
__global__ __launch_bounds__(256) void t2v_add_kernel(
    const float* __restrict__ x, const float* __restrict__ tbl, bf16* __restrict__ Y)
{
    int i = blockIdx.x * 256 + threadIdx.x;     // float4 groups
    int e = i * 4;
    float4 xv = ((const float4*)x)[i];
    int ti = ((e >> 16) << 7) | (e & 127);
    float4 tv = *(const float4*)(tbl + ti);
    ushort4 o;
    o.x = (unsigned short)f2bs(xv.x + tv.x);
    o.y = (unsigned short)f2bs(xv.y + tv.y);
    o.z = (unsigned short)f2bs(xv.z + tv.z);
    o.w = (unsigned short)f2bs(xv.w + tv.w);
    *(ushort4*)((unsigned short*)Y + e) = o;
}

// ---------------------------------------------------------------------------

extern "C" void kernel_launch(void* const* d_in, const int* in_sizes, int n_in,
                              void* d_out, int out_size, void* d_ws, size_t ws_size,
                              hipStream_t stream) {
    const float* x           = (const float*)d_in[0];
    const float* enc_in_w    = (const float*)d_in[1];
    const float* enc_in_b    = (const float*)d_in[2];
    const float* enc_out_w   = (const float*)d_in[3];
    const float* enc_out_b   = (const float*)d_in[4];
    const float* enc_l1w     = (const float*)d_in[5];
    const float* enc_l1b     = (const float*)d_in[6];
    const float* enc_l2w     = (const float*)d_in[7];
    const float* enc_l2b     = (const float*)d_in[8];
    const float* enc_ln1w    = (const float*)d_in[9];
    const float* enc_ln1b    = (const float*)d_in[10];
    const float* enc_ln2w    = (const float*)d_in[11];
    const float* enc_ln2b    = (const float*)d_in[12];
    const float* qk_in_w     = (const float*)d_in[13];
    const float* qk_in_b     = (const float*)d_in[14];
    const float* qk_out_w    = (const float*)d_in[15];
    const float* qk_out_b    = (const float*)d_in[16];
    const float* qk_l1w      = (const float*)d_in[17];
    const float* qk_l1b      = (const float*)d_in[18];
    const float* qk_l2w      = (const float*)d_in[19];
    const float* qk_l2b      = (const float*)d_in[20];
    const float* qk_ln1w     = (const float*)d_in[21];
    const float* qk_ln1b     = (const float*)d_in[22];
    const float* qk_ln2w     = (const float*)d_in[23];
    const float* qk_ln2b     = (const float*)d_in[24];
    const float* t2v_w       = (const float*)d_in[25];
    const float* t2v_b       = (const float*)d_in[26];
    const float* t2v_w0      = (const float*)d_in[27];
    const float* t2v_b0      = (const float*)d_in[28];
    const float* out_w       = (const float*)d_in[29];
    float* out = (float*)d_out;

    // ---------------- workspace layout (bytes) ------------------------------
    char* ws = (char*)d_ws;
    const size_t TOKD = (size_t)TOK * DD;
    size_t off = 0;
    auto alloc = [&](size_t bytes) { char* p = ws + off; off += (bytes + 255) & ~(size_t)255; return p; };

    bf16*  Qb   = (bf16*)alloc((size_t)TOK * 384 * 2);   // qkv bf16
    bf16*  Vb   = (bf16*)alloc(TOKD * 2);                // v-projection bf16
    bf16*  xb   = (bf16*)alloc(TOKD * 2);                // bf16 copy of x
    bf16*  bufA = (bf16*)alloc(TOKD * 2);                // residual stream bf16
    bf16*  Zb   = (bf16*)alloc(TOKD * 2);                // outs_zs bf16
    bf16*  Cb   = (bf16*)alloc(TOKD * 2);                // attn context bf16
    float* t2vt = (float*)alloc((size_t)TT * DD * 4);    // time2vec table
    bf16* enc_in_wb  = (bf16*)alloc(384 * DD * 2);
    bf16* enc_out_wb = (bf16*)alloc(DD * DD * 2);
    bf16* enc_l1wb   = (bf16*)alloc((size_t)FF_ * DD * 2);
    bf16* enc_l2wb   = (bf16*)alloc((size_t)DD * FF_ * 2);
    bf16* qk_in_wb   = (bf16*)alloc((size_t)LL * 384 * DD * 2);
    bf16* qk_out_wb  = (bf16*)alloc((size_t)LL * DD * DD * 2);
    bf16* qk_l1wb    = (bf16*)alloc((size_t)LL * FF_ * DD * 2);
    bf16* qk_l2wb    = (bf16*)alloc((size_t)LL * DD * FF_ * 2);

    // ---------------- one-shot conversion of all weights + x + t2v table ----
    ConvDesc cd;
    cd.x  = x;        cd.dx = xb;
    cd.s1 = enc_in_w; cd.d1 = enc_in_wb;
    cd.s2 = enc_out_w;cd.d2 = enc_out_wb;
    cd.s3 = enc_l1w;  cd.d3 = enc_l1wb;
    cd.s4 = enc_l2w;  cd.d4 = enc_l2wb;
    cd.s5 = qk_in_w;  cd.d5 = qk_in_wb;
    cd.s6 = qk_out_w; cd.d6 = qk_out_wb;
    cd.s7 = qk_l1w;   cd.d7 = qk_l1wb;
    cd.s8 = qk_l2w;   cd.d8 = qk_l2wb;
    cd.w = t2v_w; cd.b = t2v_b; cd.w0 = t2v_w0; cd.b0 = t2v_b0; cd.tbl = t2vt;
    conv_all_kernel<<<(CP9 + 255) / 256, 256, 0, stream>>>(cd);

    auto gemm128 = [&](const bf16* A, int lda, const bf16* W, const float* bias,
                       bf16* C, int ldc, int M, int N, int K, int relu) {
        dim3 grid(N / 128, M / 128);
        mfma_gemm<128, 128><<<grid, 256, 0, stream>>>(A, lda, W, bias, C, ldc, K, relu);
    };
    auto gemm64 = [&](const bf16* A, int lda, const bf16* W, const float* bias,
                      bf16* C, int ldc, int M, int N, int K, int relu) {
        dim3 grid(N / 64, M / 64);
        mfma_gemm<64, 64><<<grid, 256, 0, stream>>>(A, lda, W, bias, C, ldc, K, relu);
    };
    auto gemm_ln = [&](const bf16* A, int lda, const bf16* W, const float* bias,
                       const bf16* R, const float* lng, const float* lnb,
                       bf16* Y, int M, int K) {
        mfma_gemm_ln<<<M / 64, 256, 0, stream>>>(A, lda, W, bias, R, lng, lnb, Y, K);
    };

    // ---------------- stage 1: plain encoder (attend over N, batch T) -------
    gemm128(xb, DD, enc_in_wb, enc_in_b, Qb, 384, TOK, 384, DD, 0);
    attn_full_mfma<<<TT * HH, 256, 0, stream>>>(Qb, Cb);
    gemm_ln(Cb, DD, enc_out_wb, enc_out_b, xb, enc_ln1w, enc_ln1b, bufA, TOK, DD);
    ffn_fused<false><<<TOK / 64, 512, 0, stream>>>(
        bufA, enc_l1wb, enc_l1b, enc_l2wb, enc_l2b,
        enc_ln2w, enc_ln2b, Zb, nullptr, nullptr);

    // ---------------- stage 2: time2vec -------------------------------------
    t2v_add_kernel<<<(TOK * DD / 4) / 256, 256, 0, stream>>>(x, t2vt, bufA);

    // ---------------- stage 3: qk encoder stack (banded window attn) ---------
    for (int l = 0; l < LL; l++) {
        const bf16* iw   = qk_in_wb  + (size_t)l * 384 * DD;
        const float* ib  = qk_in_b   + (size_t)l * 384;
        const bf16* owt  = qk_out_wb + (size_t)l * DD * DD;
        const float* ob  = qk_out_b  + (size_t)l * DD;
        const bf16* l1w  = qk_l1wb   + (size_t)l * FF_ * DD;
        const float* l1b = qk_l1b    + (size_t)l * FF_;
        const bf16* l2w  = qk_l2wb   + (size_t)l * DD * FF_;
        const float* l2b = qk_l2b    + (size_t)l * DD;

        gemm128(bufA, DD, iw, ib, Qb, 384, TOK, 256, DD, 0);
        gemm64(Zb, DD, iw + (size_t)256 * DD, ib + 256, Vb, DD, TOK, DD, DD, 0);
        attn_banded_kernel<<<NN, 256, 0, stream>>>(Qb, Vb, Cb);
        gemm_ln(Cb, DD, owt, ob, bufA, qk_ln1w + l * DD, qk_ln1b + l * DD, bufA, TOK, DD);
        if (l == LL - 1) {
            ffn_fused<true><<<TOK / 64, 512, 0, stream>>>(
                bufA, l1w, l1b, l2w, l2b,
                qk_ln2w + l * DD, qk_ln2b + l * DD, nullptr, out_w, out);
        } else {
            ffn_fused<false><<<TOK / 64, 512, 0, stream>>>(
                bufA, l1w, l1b, l2w, l2b,
                qk_ln2w + l * DD, qk_ln2b + l * DD, bufA, nullptr, nullptr);
        }
    }
}

// Round 9
// 226.224 us; speedup vs baseline: 1.5429x; 1.1181x over previous
//
#include <hip/hip_runtime.h>
#include <hip/hip_bf16.h>
#include <math.h>

// Problem constants
#define TT 32
#define NN 512
#define DD 128
#define FF_ 2048
#define HH 8
#define LL 2
#define WND_ 8
#define TOK (TT*NN)          // 16384 tokens
#define DH 16                // head dim

typedef __hip_bfloat16 bf16;
typedef __attribute__((ext_vector_type(8))) short bf16x8;   // 8 bf16 (4 VGPRs)
typedef __attribute__((ext_vector_type(4))) float f32x4;    // 4 fp32

// global_load_lds: 16B per lane, LDS dest = wave-uniform base + lane*16 (linear)
#define GLD_LDS16(gp, lp) __builtin_amdgcn_global_load_lds( \
    (const __attribute__((address_space(1))) unsigned int*)(gp), \
    (__attribute__((address_space(3))) unsigned int*)(lp), 16, 0, 0)

#define MFMA16(a, b, c) __builtin_amdgcn_mfma_f32_16x16x32_bf16((a), (b), (c), 0, 0, 0)

__device__ inline short f2bs(float f) {
    __hip_bfloat16 h = __float2bfloat16(f);
    return *reinterpret_cast<short*>(&h);
}

// ---------------------------------------------------------------------------
// bf16 MFMA GEMM: C[M,N] = A[M,K] @ W[N,K]^T + bias (+relu). Output bf16.
// Tile BM x BN, BK=32, 256 threads = 4 waves in 2x2.
// ---------------------------------------------------------------------------
template<int BM, int BN>
__global__ __launch_bounds__(256) void mfma_gemm(
    const bf16* __restrict__ A, int lda,
    const bf16* __restrict__ W,              // [N,K] row-major (= B^T)
    const float* __restrict__ bias,          // [N]
    bf16* __restrict__ C, int ldc,
    int K, int relu)
{
    constexpr int WM = BM / 2, WN = BN / 2;
    constexpr int FM = WM / 16, FN = WN / 16;
    constexpr int LA = (BM * 64) / (256 * 16);
    constexpr int LB = (BN * 64) / (256 * 16);

    __shared__ bf16 As[BM * 32];
    __shared__ bf16 Bs[BN * 32];

    const int tid  = threadIdx.x;
    const int lane = tid & 63;
    const int wave = tid >> 6;
    const int wm = wave >> 1, wn = wave & 1;
    const int bm = blockIdx.y * BM, bn = blockIdx.x * BN;

    f32x4 acc[FM][FN];
    #pragma unroll
    for (int m = 0; m < FM; m++)
        #pragma unroll
        for (int n = 0; n < FN; n++)
            acc[m][n] = (f32x4){0.f, 0.f, 0.f, 0.f};

    for (int k0 = 0; k0 < K; k0 += 32) {
        #pragma unroll
        for (int i = 0; i < LA; i++) {
            const int o = (tid + i * 256) * 16;
            const int row = o >> 6;
            const int ce  = (o & 63) >> 1;
            GLD_LDS16(A + (size_t)(bm + row) * lda + k0 + ce, (char*)As + o);
        }
        #pragma unroll
        for (int i = 0; i < LB; i++) {
            const int o = (tid + i * 256) * 16;
            const int row = o >> 6;
            const int ce  = (o & 63) >> 1;
            GLD_LDS16(W + (size_t)(bn + row) * K + k0 + ce, (char*)Bs + o);
        }
        __syncthreads();

        bf16x8 af[FM], bfr[FN];
        #pragma unroll
        for (int m = 0; m < FM; m++)
            af[m] = *(const bf16x8*)(As + (wm * WM + m * 16 + (lane & 15)) * 32 + (lane >> 4) * 8);
        #pragma unroll
        for (int n = 0; n < FN; n++)
            bfr[n] = *(const bf16x8*)(Bs + (wn * WN + n * 16 + (lane & 15)) * 32 + (lane >> 4) * 8);
        #pragma unroll
        for (int m = 0; m < FM; m++)
            #pragma unroll
            for (int n = 0; n < FN; n++)
                acc[m][n] = MFMA16(af[m], bfr[n], acc[m][n]);
        __syncthreads();
    }

    // C/D layout: col = lane&15, row = (lane>>4)*4 + reg
    #pragma unroll
    for (int n = 0; n < FN; n++) {
        const int col = bn + wn * WN + n * 16 + (lane & 15);
        const float bv = bias[col];
        #pragma unroll
        for (int m = 0; m < FM; m++) {
            #pragma unroll
            for (int r = 0; r < 4; r++) {
                const int row = bm + wm * WM + m * 16 + (lane >> 4) * 4 + r;
                float v = acc[m][n][r] + bv;
                if (relu) v = fmaxf(v, 0.f);
                C[(size_t)row * ldc + col] = __float2bfloat16(v);
            }
        }
    }
}

// ---------------------------------------------------------------------------
// Fused GEMM + bias + residual + LayerNorm (out_proj path, K small).
// BM=64, BN=128 (full LN row). 256 threads, waves 2x2, each wave 32x64.
// ---------------------------------------------------------------------------
__global__ __launch_bounds__(256) void mfma_gemm_ln(
    const bf16* __restrict__ A, int lda,
    const bf16* __restrict__ W,              // [128,K]
    const float* __restrict__ bias,          // [128]
    const bf16* __restrict__ R,              // residual [M,128] bf16
    const float* __restrict__ lng, const float* __restrict__ lnb,
    bf16* __restrict__ Y,                    // [M,128] bf16
    int K)
{
    constexpr int BM = 64, WM = 32, WN = 64, FM = 2, FN = 4;

    __shared__ bf16 As[BM * 32];
    __shared__ bf16 Bs[128 * 32];
    __shared__ float rsum[BM][2];
    __shared__ float rsq[BM][2];

    const int tid  = threadIdx.x;
    const int lane = tid & 63;
    const int wave = tid >> 6;
    const int wm = wave >> 1, wn = wave & 1;
    const int bm = blockIdx.x * BM;

    f32x4 acc[FM][FN];
    #pragma unroll
    for (int m = 0; m < FM; m++)
        #pragma unroll
        for (int n = 0; n < FN; n++)
            acc[m][n] = (f32x4){0.f, 0.f, 0.f, 0.f};

    for (int k0 = 0; k0 < K; k0 += 32) {
        {   // A tile: 64 rows x 32 cols
            const int o = tid * 16;
            const int row = o >> 6;
            const int ce  = (o & 63) >> 1;
            GLD_LDS16(A + (size_t)(bm + row) * lda + k0 + ce, (char*)As + o);
        }
        #pragma unroll
        for (int i = 0; i < 2; i++) {       // B tile: 128 rows
            const int o = (tid + i * 256) * 16;
            const int row = o >> 6;
            const int ce  = (o & 63) >> 1;
            GLD_LDS16(W + (size_t)row * K + k0 + ce, (char*)Bs + o);
        }
        __syncthreads();

        bf16x8 af[FM], bfr[FN];
        #pragma unroll
        for (int m = 0; m < FM; m++)
            af[m] = *(const bf16x8*)(As + (wm * WM + m * 16 + (lane & 15)) * 32 + (lane >> 4) * 8);
        #pragma unroll
        for (int n = 0; n < FN; n++)
            bfr[n] = *(const bf16x8*)(Bs + (wn * WN + n * 16 + (lane & 15)) * 32 + (lane >> 4) * 8);
        #pragma unroll
        for (int m = 0; m < FM; m++)
            #pragma unroll
            for (int n = 0; n < FN; n++)
                acc[m][n] = MFMA16(af[m], bfr[n], acc[m][n]);
        __syncthreads();
    }

    // bias + residual
    #pragma unroll
    for (int n = 0; n < FN; n++) {
        const int col = wn * WN + n * 16 + (lane & 15);
        const float bv = bias[col];
        #pragma unroll
        for (int m = 0; m < FM; m++) {
            #pragma unroll
            for (int r = 0; r < 4; r++) {
                const int rl = wm * WM + m * 16 + (lane >> 4) * 4 + r;
                acc[m][n][r] += bv + __bfloat162float(R[(size_t)(bm + rl) * 128 + col]);
            }
        }
    }

    // row sums
    #pragma unroll
    for (int m = 0; m < FM; m++) {
        #pragma unroll
        for (int r = 0; r < 4; r++) {
            float s = 0.f, q = 0.f;
            #pragma unroll
            for (int n = 0; n < FN; n++) { float v = acc[m][n][r]; s += v; q += v * v; }
            #pragma unroll
            for (int off = 1; off < 16; off <<= 1) {
                s += __shfl_xor(s, off);
                q += __shfl_xor(q, off);
            }
            const int rl = wm * WM + m * 16 + (lane >> 4) * 4 + r;
            if ((lane & 15) == 0) { rsum[rl][wn] = s; rsq[rl][wn] = q; }
        }
    }
    __syncthreads();

    #pragma unroll
    for (int m = 0; m < FM; m++) {
        #pragma unroll
        for (int r = 0; r < 4; r++) {
            const int rl = wm * WM + m * 16 + (lane >> 4) * 4 + r;
            const float S = rsum[rl][0] + rsum[rl][1];
            const float Q = rsq[rl][0] + rsq[rl][1];
            const float mean = S * (1.0f / 128.0f);
            const float var  = Q * (1.0f / 128.0f) - mean * mean;
            const float rstd = rsqrtf(var + 1e-5f);
            #pragma unroll
            for (int n = 0; n < FN; n++) {
                const int col = wn * WN + n * 16 + (lane & 15);
                const float y = (acc[m][n][r] - mean) * rstd * lng[col] + lnb[col];
                Y[(size_t)(bm + rl) * 128 + col] = __float2bfloat16(y);
            }
        }
    }
}

// ---------------------------------------------------------------------------
// FFN v4: Y = LN( A + (relu(A@W1^T+b1) @ W2^T + b2) ) [* head]
// Grid 256 x 512 threads. Block = 64 tokens; 8 waves = 4 token-tiles (tt) x
// 2 hidden-halves (hh). Hidden activations never leave registers.
// v4 vs v3: (1) W2s row-pair XOR swizzle (source-side) kills the 4.19M
// phase-2 bank conflicts; (2) reduce buffer aliases staging -> LDS 64 KB.
// ---------------------------------------------------------------------------
template<bool HEAD>
__global__ __launch_bounds__(512) void ffn_fused(
    const bf16* __restrict__ A,              // [M,128]  input = residual
    const bf16* __restrict__ W1, const float* __restrict__ b1,   // [2048,128],[2048]
    const bf16* __restrict__ W2, const float* __restrict__ b2,   // [128,2048],[128]
    const float* __restrict__ lng, const float* __restrict__ lnb,
    bf16* __restrict__ Y,                    // [M,128] (unused if HEAD)
    const float* __restrict__ hw, float* __restrict__ hout)
{
    __shared__ char smem[65536];
    // W1s[d][hx] = smem + d*16384 + hx*8192          (32 KB)
    // W2s[d][hx] = smem + 32768 + d*16384 + hx*8192  (32 KB)
    // Red (post-loop alias) = smem + tt*8192         (32 KB)

    const int tid  = threadIdx.x;
    const int lane = tid & 63;
    const int wv   = tid >> 6;               // 0..7
    const int tt   = wv & 3;                 // token tile (16 tokens)
    const int hh   = wv >> 2;                // hidden half
    const int l4   = lane & 15;
    const int g    = lane >> 4;
    const int bm   = blockIdx.x * 64;

    // token B-fragments (lane&15 = token col, k = j*32 + g*8), L2-hot
    bf16x8 tf[4];
    #pragma unroll
    for (int j = 0; j < 4; j++)
        tf[j] = *(const bf16x8*)(A + (size_t)(bm + tt * 16 + l4) * 128 + j * 32 + g * 8);

    // staging geometry (per thread, one 16B gld per buffer)
    const int q    = tid >> 4;                                   // W1 LDS row slot 0..31
    const int qq   = q & 15;
    const int piq  = (((qq >> 2) << 3) | (qq & 3)) + ((q >> 4) << 2);  // pi(q)
    const int w1cb = ((tid & 15) * 16) ^ ((q & 7) << 4);         // swizzled source byte
    const int w2row = tid >> 2;
    const int w2ce  = ((tid & 3) ^ ((w2row >> 1) & 3)) * 8;      // row-pair XOR source col

    f32x4 Oacc[8];
    #pragma unroll
    for (int ot = 0; ot < 8; ot++) Oacc[ot] = (f32x4){0.f, 0.f, 0.f, 0.f};

    const f32x4 zz = (f32x4){0.f, 0.f, 0.f, 0.f};
    const int xsw = (l4 & 7) << 4;
    const int w2rsw = (l4 >> 1) & 3;         // read-side W2 swizzle term

    auto STAGE = [&](int d, int s) {
        #pragma unroll
        for (int hx = 0; hx < 2; hx++) {
            const int c0 = hx * 1024 + s * 32;
            GLD_LDS16((const char*)W1 + (size_t)(c0 + piq) * 256 + w1cb,
                      smem + d * 16384 + hx * 8192 + tid * 16);
            GLD_LDS16(W2 + (size_t)w2row * 2048 + c0 + w2ce,
                      smem + 32768 + d * 16384 + hx * 8192 + tid * 16);
        }
    };

    STAGE(0, 0);
    for (int s = 0; s < 32; s++) {
        __syncthreads();                     // drains staged loads for buf s&1
        if (s < 31) STAGE((s + 1) & 1, s + 1);   // async, flies during compute
        const int d  = s & 1;
        const int c0 = hh * 1024 + s * 32;
        const char* w1b = smem + d * 16384 + hh * 8192;
        const char* w2b = smem + 32768 + d * 16384 + hh * 8192;

        // phase 1: H^T for 32 hidden cols (rows pi-permuted in LDS)
        f32x4 sa0 = zz, sa1 = zz;
        #pragma unroll
        for (int j = 0; j < 4; j++) {
            const int xo = (j * 64 + g * 16) ^ xsw;
            bf16x8 w10 = *(const bf16x8*)(w1b + l4 * 256 + xo);
            bf16x8 w11 = *(const bf16x8*)(w1b + (16 + l4) * 256 + xo);
            sa0 = MFMA16(w10, tf[j], sa0);
            sa1 = MFMA16(w11, tf[j], sa1);
        }
        // bias + relu + pack: lane holds hidden cols c0 + 8g + {0..7}
        float4 bv0 = *(const float4*)(b1 + c0 + g * 8);
        float4 bv1 = *(const float4*)(b1 + c0 + g * 8 + 4);
        bf16x8 pf;
        pf[0] = f2bs(fmaxf(sa0[0] + bv0.x, 0.f));
        pf[1] = f2bs(fmaxf(sa0[1] + bv0.y, 0.f));
        pf[2] = f2bs(fmaxf(sa0[2] + bv0.z, 0.f));
        pf[3] = f2bs(fmaxf(sa0[3] + bv0.w, 0.f));
        pf[4] = f2bs(fmaxf(sa1[0] + bv1.x, 0.f));
        pf[5] = f2bs(fmaxf(sa1[1] + bv1.y, 0.f));
        pf[6] = f2bs(fmaxf(sa1[2] + bv1.z, 0.f));
        pf[7] = f2bs(fmaxf(sa1[3] + bv1.w, 0.f));

        // phase 2: accumulate all 128 output cols over this k-window
        #pragma unroll
        for (int ot = 0; ot < 8; ot++) {
            bf16x8 w2f = *(const bf16x8*)(w2b + (ot * 16 + l4) * 64 + ((g ^ w2rsw) << 4));
            Oacc[ot] = MFMA16(pf, w2f, Oacc[ot]);
        }
    }

    // ---- reduce hidden halves (Red aliases the staging space) ----
    __syncthreads();
    if (hh == 1) {
        #pragma unroll
        for (int ot = 0; ot < 8; ot++)
            *(f32x4*)(smem + tt * 8192 + ot * 1024 + lane * 16) = Oacc[ot];
    }
    __syncthreads();
    if (hh == 0) {
        #pragma unroll
        for (int ot = 0; ot < 8; ot++) {
            f32x4 o2 = *(const f32x4*)(smem + tt * 8192 + ot * 1024 + lane * 16);
            Oacc[ot][0] += o2[0]; Oacc[ot][1] += o2[1];
            Oacc[ot][2] += o2[2]; Oacc[ot][3] += o2[3];
        }

        // bias + residual;  lane: col = ot*16 + l4, token = tt*16 + 4g + r
        float vv[8][4];
        #pragma unroll
        for (int ot = 0; ot < 8; ot++) {
            const int col = ot * 16 + l4;
            const float bv = b2[col];
            #pragma unroll
            for (int r = 0; r < 4; r++) {
                const int trow = bm + tt * 16 + 4 * g + r;
                vv[ot][r] = Oacc[ot][r] + bv
                          + __bfloat162float(A[(size_t)trow * 128 + col]);
            }
        }

        // LN row stats: in-lane over ot, shfl over 16-lane col group
        #pragma unroll
        for (int r = 0; r < 4; r++) {
            float sm = 0.f, qs = 0.f;
            #pragma unroll
            for (int ot = 0; ot < 8; ot++) { float v = vv[ot][r]; sm += v; qs += v * v; }
            #pragma unroll
            for (int off = 1; off < 16; off <<= 1) {
                sm += __shfl_xor(sm, off);
                qs += __shfl_xor(qs, off);
            }
            const float mean = sm * (1.0f / 128.0f);
            const float var  = qs * (1.0f / 128.0f) - mean * mean;
            const float rstd = rsqrtf(var + 1e-5f);
            const int trow = bm + tt * 16 + 4 * g + r;
            float hacc = 0.f;
            #pragma unroll
            for (int ot = 0; ot < 8; ot++) {
                const int col = ot * 16 + l4;
                const float y = (vv[ot][r] - mean) * rstd * lng[col] + lnb[col];
                if (HEAD) hacc += y * hw[col];
                else Y[(size_t)trow * 128 + col] = __float2bfloat16(y);
            }
            if (HEAD) {
                #pragma unroll
                for (int off = 1; off < 16; off <<= 1) hacc += __shfl_xor(hacc, off);
                if (l4 == 0) hout[trow] = hacc;
            }
        }
    }
}

// ---------------------------------------------------------------------------
// Merged fp32->bf16 conversion of all weights + x, plus t2v table (segment 9).
// ---------------------------------------------------------------------------
struct ConvDesc {
    const float *x, *s1, *s2, *s3, *s4, *s5, *s6, *s7, *s8;
    bf16 *dx, *d1, *d2, *d3, *d4, *d5, *d6, *d7, *d8;
    const float *w, *b, *w0, *b0;
    float* tbl;
};

__device__ inline void cvt4(const float* s, bf16* d, int j) {
    float4 v = ((const float4*)s)[j];
    ushort4 o;
    o.x = (unsigned short)f2bs(v.x); o.y = (unsigned short)f2bs(v.y);
    o.z = (unsigned short)f2bs(v.z); o.w = (unsigned short)f2bs(v.w);
    *(ushort4*)((unsigned short*)d + j * 4) = o;
}

// prefix sums in float4 units
#define CP0 524288   // x            (2097152)
#define CP1 536576   // enc_in_w     (49152)
#define CP2 540672   // enc_out_w    (16384)
#define CP3 606208   // enc_l1w      (262144)
#define CP4 671744   // enc_l2w      (262144)
#define CP5 696320   // qk_in_w      (98304)
#define CP6 704512   // qk_out_w     (32768)
#define CP7 835584   // qk_l1w       (524288)
#define CP8 966656   // qk_l2w       (524288)
#define CP9 967680   // t2v table    (4096 fp32)

__global__ __launch_bounds__(256) void conv_all_kernel(ConvDesc cd)
{
    int i = blockIdx.x * 256 + threadIdx.x;
    if (i < CP0)      cvt4(cd.x,  cd.dx, i);
    else if (i < CP1) cvt4(cd.s1, cd.d1, i - CP0);
    else if (i < CP2) cvt4(cd.s2, cd.d2, i - CP1);
    else if (i < CP3) cvt4(cd.s3, cd.d3, i - CP2);
    else if (i < CP4) cvt4(cd.s4, cd.d4, i - CP3);
    else if (i < CP5) cvt4(cd.s5, cd.d5, i - CP4);
    else if (i < CP6) cvt4(cd.s6, cd.d6, i - CP5);
    else if (i < CP7) cvt4(cd.s7, cd.d7, i - CP6);
    else if (i < CP8) cvt4(cd.s8, cd.d8, i - CP7);
    else if (i < CP9) {
        int e = (i - CP8) * 4;
        int t = e >> 7;
        float tau = (float)(t + 1);
        float4 o;
        #pragma unroll
        for (int k = 0; k < 4; k++) {
            int d = (e + k) & 127;
            ((float*)&o)[k] = (d < 127) ? sinf(tau * cd.w[d] + cd.b[d])
                                        : (tau * cd.w0[0] + cd.b0[0]);
        }
        *(float4*)(cd.tbl + e) = o;
    }
}

// ---------------------------------------------------------------------------
// Stage-1 attention via MFMA (flash, maxless). One block per (t,h).
// ---------------------------------------------------------------------------
__global__ __launch_bounds__(256) void attn_full_mfma(
    const bf16* __restrict__ Qkv, bf16* __restrict__ C)
{
    __shared__ bf16 Qs[512 * 16];
    __shared__ bf16 Ks[512 * 16];
    __shared__ bf16 Vt[16 * 520];
    __shared__ bf16 Zero[32];          // 64B broadcast zero block

    const int t = blockIdx.x >> 3;
    const int h = blockIdx.x & 7;
    const int tid = threadIdx.x;

    if (tid < 32) ((unsigned short*)Zero)[tid] = 0;

    for (int n = tid; n < 512; n += 256) {
        const unsigned short* row = (const unsigned short*)Qkv + (size_t)(t * 512 + n) * 384 + h * 16;
        uint4 q0 = *(const uint4*)(row);
        uint4 q1 = *(const uint4*)(row + 8);
        uint4 k0 = *(const uint4*)(row + 128);
        uint4 k1 = *(const uint4*)(row + 136);
        uint4 v0 = *(const uint4*)(row + 256);
        uint4 v1 = *(const uint4*)(row + 264);
        *(uint4*)((unsigned short*)Qs + n * 16)     = q0;
        *(uint4*)((unsigned short*)Qs + n * 16 + 8) = q1;
        *(uint4*)((unsigned short*)Ks + n * 16)     = k0;
        *(uint4*)((unsigned short*)Ks + n * 16 + 8) = k1;
        union { uint4 u[2]; unsigned short s[16]; } vb;
        vb.u[0] = v0; vb.u[1] = v1;
        #pragma unroll
        for (int f = 0; f < 16; f++)
            ((unsigned short*)Vt)[f * 520 + n] = vb.s[f];
    }
    __syncthreads();

    const int lane = tid & 63;
    const int wv   = tid >> 6;
    const int l4   = lane & 15;
    const int g    = lane >> 4;
    const int qbase = wv * 128;
    const bf16* zp = Zero + (g & 1) * 8;
    const int p0 = ((l4 >> 2) << 3) | (l4 & 3);      // pi0 key permutation

    bf16x8 qf[8];
    #pragma unroll
    for (int qt = 0; qt < 8; qt++) {
        const bf16* ap = (g < 2) ? (Qs + (qbase + qt * 16 + l4) * 16 + g * 8) : zp;
        qf[qt] = *(const bf16x8*)ap;
    }

    f32x4 Oacc[8];
    float lsum[8];
    #pragma unroll
    for (int qt = 0; qt < 8; qt++) { Oacc[qt] = (f32x4){0.f,0.f,0.f,0.f}; lsum[qt] = 0.f; }

    const float cexp = 0.25f * 1.44269504088896f;   // scale * log2(e)

    for (int kt = 0; kt < 16; kt++) {               // 32 keys per iteration
        const bf16* k0p = (g < 2) ? (Ks + (kt * 32 + p0)     * 16 + g * 8) : zp;
        const bf16* k1p = (g < 2) ? (Ks + (kt * 32 + p0 + 4) * 16 + g * 8) : zp;
        bf16x8 kf0 = *(const bf16x8*)k0p;
        bf16x8 kf1 = *(const bf16x8*)k1p;
        bf16x8 vf  = *(const bf16x8*)(Vt + l4 * 520 + kt * 32 + g * 8);

        #pragma unroll
        for (int qt = 0; qt < 8; qt++) {
            f32x4 z = (f32x4){0.f,0.f,0.f,0.f};
            f32x4 s0 = MFMA16(kf0, qf[qt], z);
            f32x4 s1 = MFMA16(kf1, qf[qt], z);
            float e[8];
            #pragma unroll
            for (int r = 0; r < 4; r++) {
                e[r]     = exp2f(s0[r] * cexp);
                e[4 + r] = exp2f(s1[r] * cexp);
            }
            lsum[qt] += ((e[0]+e[1])+(e[2]+e[3])) + ((e[4]+e[5])+(e[6]+e[7]));
            bf16x8 pf;
            #pragma unroll
            for (int i = 0; i < 8; i++) pf[i] = f2bs(e[i]);
            Oacc[qt] = MFMA16(pf, vf, Oacc[qt]);
        }
    }

    #pragma unroll
    for (int qt = 0; qt < 8; qt++) {
        float ls = lsum[qt];
        ls += __shfl_xor(ls, 16);
        ls += __shfl_xor(ls, 32);
        #pragma unroll
        for (int r = 0; r < 4; r++) {
            float lq = __shfl(ls, g * 4 + r);
            float o = Oacc[qt][r] / lq;
            int qrow = t * 512 + qbase + qt * 16 + g * 4 + r;
            C[(size_t)qrow * 128 + h * 16 + l4] = __float2bfloat16(o);
        }
    }
}

// ---------------------------------------------------------------------------
// Stage-3 banded attention: window j in [i-7, i]. bf16 q/k/v in, bf16 out.
// ---------------------------------------------------------------------------
__global__ __launch_bounds__(256) void attn_banded_kernel(
    const bf16* __restrict__ Qkv, const bf16* __restrict__ Vb, bf16* __restrict__ C)
{
    __shared__ float Qs[TT][129];
    __shared__ float Ksh[TT][129];
    __shared__ float Vs[TT][129];
    const int n = blockIdx.x;
    const int tid = threadIdx.x;

    for (int e = tid; e < TT * DD; e += 256) {
        int t = e >> 7, d = e & 127;
        const bf16* row = Qkv + (size_t)(t * NN + n) * 384;
        Qs[t][d]  = __bfloat162float(row[d]);
        Ksh[t][d] = __bfloat162float(row[128 + d]);
        Vs[t][d]  = __bfloat162float(Vb[(size_t)(t * NN + n) * DD + d]);
    }
    __syncthreads();

    const int h = tid >> 5, i = tid & 31;
    const int hb = h * DH;

    float s[WND_];
    #pragma unroll
    for (int kk = 0; kk < WND_; kk++) {
        int j = i - (WND_ - 1) + kk;
        int jc = j < 0 ? 0 : j;
        float d = 0.f;
        #pragma unroll
        for (int f = 0; f < DH; f++) d += Qs[i][hb + f] * Ksh[jc][hb + f];
        s[kk] = (j >= 0) ? d * 0.25f : -1e30f;
    }
    float m = s[0];
    #pragma unroll
    for (int kk = 1; kk < WND_; kk++) m = fmaxf(m, s[kk]);
    float l = 0.f, p[WND_];
    #pragma unroll
    for (int kk = 0; kk < WND_; kk++) { p[kk] = __expf(s[kk] - m); l += p[kk]; }
    float inv = 1.f / l;
    float acc[DH] = {};
    #pragma unroll
    for (int kk = 0; kk < WND_; kk++) {
        int j = i - (WND_ - 1) + kk;
        int jc = j < 0 ? 0 : j;
        float pw = p[kk] * inv;
        #pragma unroll
        for (int f = 0; f < DH; f++) acc[f] += pw * Vs[jc][hb + f];
    }
    bf16* cp = C + (size_t)(i * NN + n) * DD + hb;
    #pragma unroll
    for (int f = 0; f < DH; f++) cp[f] = __float2bfloat16(acc[f]);
}

// ---------------------------------------------------------------------------
// time2vec add: Y = bf16(x + tbl[t, d])
// ---------------------------------------------------------------------------
__global__ __launch_bounds__(256) void t2v_add_kernel(
    const float* __restrict__ x, const float* __restrict__ tbl, bf16* __restrict__ Y)
{
    int i = blockIdx.x * 256 + threadIdx.x;     // float4 groups
    int e = i * 4;
    float4 xv = ((const float4*)x)[i];
    int ti = ((e >> 16) << 7) | (e & 127);
    float4 tv = *(const float4*)(tbl + ti);
    ushort4 o;
    o.x = (unsigned short)f2bs(xv.x + tv.x);
    o.y = (unsigned short)f2bs(xv.y + tv.y);
    o.z = (unsigned short)f2bs(xv.z + tv.z);
    o.w = (unsigned short)f2bs(xv.w + tv.w);
    *(ushort4*)((unsigned short*)Y + e) = o;
}

// ---------------------------------------------------------------------------

extern "C" void kernel_launch(void* const* d_in, const int* in_sizes, int n_in,
                              void* d_out, int out_size, void* d_ws, size_t ws_size,
                              hipStream_t stream) {
    const float* x           = (const float*)d_in[0];
    const float* enc_in_w    = (const float*)d_in[1];
    const float* enc_in_b    = (const float*)d_in[2];
    const float* enc_out_w   = (const float*)d_in[3];
    const float* enc_out_b   = (const float*)d_in[4];
    const float* enc_l1w     = (const float*)d_in[5];
    const float* enc_l1b     = (const float*)d_in[6];
    const float* enc_l2w     = (const float*)d_in[7];
    const float* enc_l2b     = (const float*)d_in[8];
    const float* enc_ln1w    = (const float*)d_in[9];
    const float* enc_ln1b    = (const float*)d_in[10];
    const float* enc_ln2w    = (const float*)d_in[11];
    const float* enc_ln2b    = (const float*)d_in[12];
    const float* qk_in_w     = (const float*)d_in[13];
    const float* qk_in_b     = (const float*)d_in[14];
    const float* qk_out_w    = (const float*)d_in[15];
    const float* qk_out_b    = (const float*)d_in[16];
    const float* qk_l1w      = (const float*)d_in[17];
    const float* qk_l1b      = (const float*)d_in[18];
    const float* qk_l2w      = (const float*)d_in[19];
    const float* qk_l2b      = (const float*)d_in[20];
    const float* qk_ln1w     = (const float*)d_in[21];
    const float* qk_ln1b     = (const float*)d_in[22];
    const float* qk_ln2w     = (const float*)d_in[23];
    const float* qk_ln2b     = (const float*)d_in[24];
    const float* t2v_w       = (const float*)d_in[25];
    const float* t2v_b       = (const float*)d_in[26];
    const float* t2v_w0      = (const float*)d_in[27];
    const float* t2v_b0      = (const float*)d_in[28];
    const float* out_w       = (const float*)d_in[29];
    float* out = (float*)d_out;

    // ---------------- workspace layout (bytes) ------------------------------
    char* ws = (char*)d_ws;
    const size_t TOKD = (size_t)TOK * DD;
    size_t off = 0;
    auto alloc = [&](size_t bytes) { char* p = ws + off; off += (bytes + 255) & ~(size_t)255; return p; };

    bf16*  Qb   = (bf16*)alloc((size_t)TOK * 384 * 2);   // qkv bf16
    bf16*  Vb   = (bf16*)alloc(TOKD * 2);                // v-projection bf16
    bf16*  xb   = (bf16*)alloc(TOKD * 2);                // bf16 copy of x
    bf16*  bufA = (bf16*)alloc(TOKD * 2);                // residual stream bf16
    bf16*  Zb   = (bf16*)alloc(TOKD * 2);                // outs_zs bf16
    bf16*  Cb   = (bf16*)alloc(TOKD * 2);                // attn context bf16
    float* t2vt = (float*)alloc((size_t)TT * DD * 4);    // time2vec table
    bf16* enc_in_wb  = (bf16*)alloc(384 * DD * 2);
    bf16* enc_out_wb = (bf16*)alloc(DD * DD * 2);
    bf16* enc_l1wb   = (bf16*)alloc((size_t)FF_ * DD * 2);
    bf16* enc_l2wb   = (bf16*)alloc((size_t)DD * FF_ * 2);
    bf16* qk_in_wb   = (bf16*)alloc((size_t)LL * 384 * DD * 2);
    bf16* qk_out_wb  = (bf16*)alloc((size_t)LL * DD * DD * 2);
    bf16* qk_l1wb    = (bf16*)alloc((size_t)LL * FF_ * DD * 2);
    bf16* qk_l2wb    = (bf16*)alloc((size_t)LL * DD * FF_ * 2);

    // ---------------- one-shot conversion of all weights + x + t2v table ----
    ConvDesc cd;
    cd.x  = x;        cd.dx = xb;
    cd.s1 = enc_in_w; cd.d1 = enc_in_wb;
    cd.s2 = enc_out_w;cd.d2 = enc_out_wb;
    cd.s3 = enc_l1w;  cd.d3 = enc_l1wb;
    cd.s4 = enc_l2w;  cd.d4 = enc_l2wb;
    cd.s5 = qk_in_w;  cd.d5 = qk_in_wb;
    cd.s6 = qk_out_w; cd.d6 = qk_out_wb;
    cd.s7 = qk_l1w;   cd.d7 = qk_l1wb;
    cd.s8 = qk_l2w;   cd.d8 = qk_l2wb;
    cd.w = t2v_w; cd.b = t2v_b; cd.w0 = t2v_w0; cd.b0 = t2v_b0; cd.tbl = t2vt;
    conv_all_kernel<<<(CP9 + 255) / 256, 256, 0, stream>>>(cd);

    auto gemm128 = [&](const bf16* A, int lda, const bf16* W, const float* bias,
                       bf16* C, int ldc, int M, int N, int K, int relu) {
        dim3 grid(N / 128, M / 128);
        mfma_gemm<128, 128><<<grid, 256, 0, stream>>>(A, lda, W, bias, C, ldc, K, relu);
    };
    auto gemm64 = [&](const bf16* A, int lda, const bf16* W, const float* bias,
                      bf16* C, int ldc, int M, int N, int K, int relu) {
        dim3 grid(N / 64, M / 64);
        mfma_gemm<64, 64><<<grid, 256, 0, stream>>>(A, lda, W, bias, C, ldc, K, relu);
    };
    auto gemm_ln = [&](const bf16* A, int lda, const bf16* W, const float* bias,
                       const bf16* R, const float* lng, const float* lnb,
                       bf16* Y, int M, int K) {
        mfma_gemm_ln<<<M / 64, 256, 0, stream>>>(A, lda, W, bias, R, lng, lnb, Y, K);
    };

    // ---------------- stage 1: plain encoder (attend over N, batch T) -------
    gemm128(xb, DD, enc_in_wb, enc_in_b, Qb, 384, TOK, 384, DD, 0);
    attn_full_mfma<<<TT * HH, 256, 0, stream>>>(Qb, Cb);
    gemm_ln(Cb, DD, enc_out_wb, enc_out_b, xb, enc_ln1w, enc_ln1b, bufA, TOK, DD);
    ffn_fused<false><<<TOK / 64, 512, 0, stream>>>(
        bufA, enc_l1wb, enc_l1b, enc_l2wb, enc_l2b,
        enc_ln2w, enc_ln2b, Zb, nullptr, nullptr);

    // ---------------- stage 2: time2vec -------------------------------------
    t2v_add_kernel<<<(TOK * DD / 4) / 256, 256, 0, stream>>>(x, t2vt, bufA);

    // ---------------- stage 3: qk encoder stack (banded window attn) ---------
    for (int l = 0; l < LL; l++) {
        const bf16* iw   = qk_in_wb  + (size_t)l * 384 * DD;
        const float* ib  = qk_in_b   + (size_t)l * 384;
        const bf16* owt  = qk_out_wb + (size_t)l * DD * DD;
        const float* ob  = qk_out_b  + (size_t)l * DD;
        const bf16* l1w  = qk_l1wb   + (size_t)l * FF_ * DD;
        const float* l1b = qk_l1b    + (size_t)l * FF_;
        const bf16* l2w  = qk_l2wb   + (size_t)l * DD * FF_;
        const float* l2b = qk_l2b    + (size_t)l * DD;

        gemm128(bufA, DD, iw, ib, Qb, 384, TOK, 256, DD, 0);
        gemm64(Zb, DD, iw + (size_t)256 * DD, ib + 256, Vb, DD, TOK, DD, DD, 0);
        attn_banded_kernel<<<NN, 256, 0, stream>>>(Qb, Vb, Cb);
        gemm_ln(Cb, DD, owt, ob, bufA, qk_ln1w + l * DD, qk_ln1b + l * DD, bufA, TOK, DD);
        if (l == LL - 1) {
            ffn_fused<true><<<TOK / 64, 512, 0, stream>>>(
                bufA, l1w, l1b, l2w, l2b,
                qk_ln2w + l * DD, qk_ln2b + l * DD, nullptr, out_w, out);
        } else {
            ffn_fused<false><<<TOK / 64, 512, 0, stream>>>(
                bufA, l1w, l1b, l2w, l2b,
                qk_ln2w + l * DD, qk_ln2b + l * DD, bufA, nullptr, nullptr);
        }
    }
}

// Round 10
// 222.901 us; speedup vs baseline: 1.5659x; 1.0149x over previous
//
#include <hip/hip_runtime.h>
#include <hip/hip_bf16.h>
#include <math.h>

// Problem constants
#define TT 32
#define NN 512
#define DD 128
#define FF_ 2048
#define HH 8
#define LL 2
#define WND_ 8
#define TOK (TT*NN)          // 16384 tokens
#define DH 16                // head dim

typedef __hip_bfloat16 bf16;
typedef __attribute__((ext_vector_type(8))) short bf16x8;   // 8 bf16 (4 VGPRs)
typedef __attribute__((ext_vector_type(4))) float f32x4;    // 4 fp32

// global_load_lds: 16B per lane, LDS dest = wave-uniform base + lane*16 (linear)
#define GLD_LDS16(gp, lp) __builtin_amdgcn_global_load_lds( \
    (const __attribute__((address_space(1))) unsigned int*)(gp), \
    (__attribute__((address_space(3))) unsigned int*)(lp), 16, 0, 0)

#define MFMA16(a, b, c) __builtin_amdgcn_mfma_f32_16x16x32_bf16((a), (b), (c), 0, 0, 0)

__device__ inline short f2bs(float f) {
    __hip_bfloat16 h = __float2bfloat16(f);
    return *reinterpret_cast<short*>(&h);
}

// ---------------------------------------------------------------------------
// bf16 MFMA GEMM: C[M,N] = A[M,K] @ W[N,K]^T + bias (+relu). Output bf16.
// Tile BM x BN, BK=32, 256 threads = 4 waves in 2x2.
// ---------------------------------------------------------------------------
template<int BM, int BN>
__global__ __launch_bounds__(256) void mfma_gemm(
    const bf16* __restrict__ A, int lda,
    const bf16* __restrict__ W,              // [N,K] row-major (= B^T)
    const float* __restrict__ bias,          // [N]
    bf16* __restrict__ C, int ldc,
    int K, int relu)
{
    constexpr int WM = BM / 2, WN = BN / 2;
    constexpr int FM = WM / 16, FN = WN / 16;
    constexpr int LA = (BM * 64) / (256 * 16);
    constexpr int LB = (BN * 64) / (256 * 16);

    __shared__ bf16 As[BM * 32];
    __shared__ bf16 Bs[BN * 32];

    const int tid  = threadIdx.x;
    const int lane = tid & 63;
    const int wave = tid >> 6;
    const int wm = wave >> 1, wn = wave & 1;
    const int bm = blockIdx.y * BM, bn = blockIdx.x * BN;

    f32x4 acc[FM][FN];
    #pragma unroll
    for (int m = 0; m < FM; m++)
        #pragma unroll
        for (int n = 0; n < FN; n++)
            acc[m][n] = (f32x4){0.f, 0.f, 0.f, 0.f};

    for (int k0 = 0; k0 < K; k0 += 32) {
        #pragma unroll
        for (int i = 0; i < LA; i++) {
            const int o = (tid + i * 256) * 16;
            const int row = o >> 6;
            const int ce  = (o & 63) >> 1;
            GLD_LDS16(A + (size_t)(bm + row) * lda + k0 + ce, (char*)As + o);
        }
        #pragma unroll
        for (int i = 0; i < LB; i++) {
            const int o = (tid + i * 256) * 16;
            const int row = o >> 6;
            const int ce  = (o & 63) >> 1;
            GLD_LDS16(W + (size_t)(bn + row) * K + k0 + ce, (char*)Bs + o);
        }
        __syncthreads();

        bf16x8 af[FM], bfr[FN];
        #pragma unroll
        for (int m = 0; m < FM; m++)
            af[m] = *(const bf16x8*)(As + (wm * WM + m * 16 + (lane & 15)) * 32 + (lane >> 4) * 8);
        #pragma unroll
        for (int n = 0; n < FN; n++)
            bfr[n] = *(const bf16x8*)(Bs + (wn * WN + n * 16 + (lane & 15)) * 32 + (lane >> 4) * 8);
        #pragma unroll
        for (int m = 0; m < FM; m++)
            #pragma unroll
            for (int n = 0; n < FN; n++)
                acc[m][n] = MFMA16(af[m], bfr[n], acc[m][n]);
        __syncthreads();
    }

    // C/D layout: col = lane&15, row = (lane>>4)*4 + reg
    #pragma unroll
    for (int n = 0; n < FN; n++) {
        const int col = bn + wn * WN + n * 16 + (lane & 15);
        const float bv = bias[col];
        #pragma unroll
        for (int m = 0; m < FM; m++) {
            #pragma unroll
            for (int r = 0; r < 4; r++) {
                const int row = bm + wm * WM + m * 16 + (lane >> 4) * 4 + r;
                float v = acc[m][n][r] + bv;
                if (relu) v = fmaxf(v, 0.f);
                C[(size_t)row * ldc + col] = __float2bfloat16(v);
            }
        }
    }
}

// ---------------------------------------------------------------------------
// Fused GEMM + bias + residual + LayerNorm (out_proj path, K small).
// BM=64, BN=128 (full LN row). 256 threads, waves 2x2, each wave 32x64.
// ---------------------------------------------------------------------------
__global__ __launch_bounds__(256) void mfma_gemm_ln(
    const bf16* __restrict__ A, int lda,
    const bf16* __restrict__ W,              // [128,K]
    const float* __restrict__ bias,          // [128]
    const bf16* __restrict__ R,              // residual [M,128] bf16
    const float* __restrict__ lng, const float* __restrict__ lnb,
    bf16* __restrict__ Y,                    // [M,128] bf16
    int K)
{
    constexpr int BM = 64, WM = 32, WN = 64, FM = 2, FN = 4;

    __shared__ bf16 As[BM * 32];
    __shared__ bf16 Bs[128 * 32];
    __shared__ float rsum[BM][2];
    __shared__ float rsq[BM][2];

    const int tid  = threadIdx.x;
    const int lane = tid & 63;
    const int wave = tid >> 6;
    const int wm = wave >> 1, wn = wave & 1;
    const int bm = blockIdx.x * BM;

    f32x4 acc[FM][FN];
    #pragma unroll
    for (int m = 0; m < FM; m++)
        #pragma unroll
        for (int n = 0; n < FN; n++)
            acc[m][n] = (f32x4){0.f, 0.f, 0.f, 0.f};

    for (int k0 = 0; k0 < K; k0 += 32) {
        {   // A tile: 64 rows x 32 cols
            const int o = tid * 16;
            const int row = o >> 6;
            const int ce  = (o & 63) >> 1;
            GLD_LDS16(A + (size_t)(bm + row) * lda + k0 + ce, (char*)As + o);
        }
        #pragma unroll
        for (int i = 0; i < 2; i++) {       // B tile: 128 rows
            const int o = (tid + i * 256) * 16;
            const int row = o >> 6;
            const int ce  = (o & 63) >> 1;
            GLD_LDS16(W + (size_t)row * K + k0 + ce, (char*)Bs + o);
        }
        __syncthreads();

        bf16x8 af[FM], bfr[FN];
        #pragma unroll
        for (int m = 0; m < FM; m++)
            af[m] = *(const bf16x8*)(As + (wm * WM + m * 16 + (lane & 15)) * 32 + (lane >> 4) * 8);
        #pragma unroll
        for (int n = 0; n < FN; n++)
            bfr[n] = *(const bf16x8*)(Bs + (wn * WN + n * 16 + (lane & 15)) * 32 + (lane >> 4) * 8);
        #pragma unroll
        for (int m = 0; m < FM; m++)
            #pragma unroll
            for (int n = 0; n < FN; n++)
                acc[m][n] = MFMA16(af[m], bfr[n], acc[m][n]);
        __syncthreads();
    }

    // bias + residual
    #pragma unroll
    for (int n = 0; n < FN; n++) {
        const int col = wn * WN + n * 16 + (lane & 15);
        const float bv = bias[col];
        #pragma unroll
        for (int m = 0; m < FM; m++) {
            #pragma unroll
            for (int r = 0; r < 4; r++) {
                const int rl = wm * WM + m * 16 + (lane >> 4) * 4 + r;
                acc[m][n][r] += bv + __bfloat162float(R[(size_t)(bm + rl) * 128 + col]);
            }
        }
    }

    // row sums
    #pragma unroll
    for (int m = 0; m < FM; m++) {
        #pragma unroll
        for (int r = 0; r < 4; r++) {
            float s = 0.f, q = 0.f;
            #pragma unroll
            for (int n = 0; n < FN; n++) { float v = acc[m][n][r]; s += v; q += v * v; }
            #pragma unroll
            for (int off = 1; off < 16; off <<= 1) {
                s += __shfl_xor(s, off);
                q += __shfl_xor(q, off);
            }
            const int rl = wm * WM + m * 16 + (lane >> 4) * 4 + r;
            if ((lane & 15) == 0) { rsum[rl][wn] = s; rsq[rl][wn] = q; }
        }
    }
    __syncthreads();

    #pragma unroll
    for (int m = 0; m < FM; m++) {
        #pragma unroll
        for (int r = 0; r < 4; r++) {
            const int rl = wm * WM + m * 16 + (lane >> 4) * 4 + r;
            const float S = rsum[rl][0] + rsum[rl][1];
            const float Q = rsq[rl][0] + rsq[rl][1];
            const float mean = S * (1.0f / 128.0f);
            const float var  = Q * (1.0f / 128.0f) - mean * mean;
            const float rstd = rsqrtf(var + 1e-5f);
            #pragma unroll
            for (int n = 0; n < FN; n++) {
                const int col = wn * WN + n * 16 + (lane & 15);
                const float y = (acc[m][n][r] - mean) * rstd * lng[col] + lnb[col];
                Y[(size_t)(bm + rl) * 128 + col] = __float2bfloat16(y);
            }
        }
    }
}

// ---------------------------------------------------------------------------
// FFN v5: Y = LN( A + (relu(A@W1^T+b1) @ W2^T + b2) ) [* head]
// Grid 256 x 512 threads. Block = 64 tokens; 8 waves = 2 token-groups (tg,
// 32 tokens = 2 sub-tiles) x 4 hidden-quarters (hq, 512 cols each).
// v5 vs v4: waves regrouped so each W1/W2 LDS fragment feeds 2 MFMAs
// (one per token sub-tile) -> W-read redundancy 4x -> 2x, total LDS traffic
// 5 MB -> 3 MB per block. 16 iterations x 128 hidden cols (32 per hq),
// staging 64 KB/iter double-buffered (128 KB LDS; grid=256 was already
// 1 block/CU). pi-permuted W1 staging (phase-1 output = phase-2 A-fragment),
// W1 source-XOR swizzle, W2 row-pair XOR swizzle all carried from v4
// (verified). 4 quarter-partials reduced via 96 KB aliased onto dead
// staging buffers after the final barrier.
// ---------------------------------------------------------------------------
template<bool HEAD>
__global__ __launch_bounds__(512) void ffn_fused(
    const bf16* __restrict__ A,              // [M,128]  input = residual
    const bf16* __restrict__ W1, const float* __restrict__ b1,   // [2048,128],[2048]
    const bf16* __restrict__ W2, const float* __restrict__ b2,   // [128,2048],[128]
    const float* __restrict__ lng, const float* __restrict__ lnb,
    bf16* __restrict__ Y,                    // [M,128] (unused if HEAD)
    const float* __restrict__ hw, float* __restrict__ hout)
{
    __shared__ char smem[131072];
    // W1s[d][hx] = smem + d*32768 + hx*8192           (64 KB)
    // W2s[d][hx] = smem + 65536 + d*32768 + hx*8192   (64 KB)
    // Red (post-loop alias): smem + tg*49152 + (hq-1)*16384 + (sub*8+ot)*1024

    const int tid  = threadIdx.x;
    const int lane = tid & 63;
    const int wv   = tid >> 6;               // 0..7
    const int tg   = wv & 1;                 // token group (32 tokens)
    const int hq   = wv >> 1;                // hidden quarter (512 cols)
    const int l4   = lane & 15;
    const int g    = lane >> 4;
    const int bm   = blockIdx.x * 64;

    // token B-fragments for this group's 2 sub-tiles (lane&15 = token col)
    bf16x8 tf[2][4];
    #pragma unroll
    for (int sub = 0; sub < 2; sub++)
        #pragma unroll
        for (int j = 0; j < 4; j++)
            tf[sub][j] = *(const bf16x8*)(A + (size_t)(bm + (tg * 2 + sub) * 16 + l4) * 128
                                          + j * 32 + g * 8);

    // staging geometry (per thread, one 16B gld per buffer region)
    const int q    = tid >> 4;                                   // W1 LDS row slot 0..31
    const int qq   = q & 15;
    const int piq  = (((qq >> 2) << 3) | (qq & 3)) + ((q >> 4) << 2);  // pi(q)
    const int w1cb = ((tid & 15) * 16) ^ ((q & 7) << 4);         // swizzled source byte
    const int w2row = tid >> 2;                                  // 0..127
    const int w2ce  = ((tid & 3) ^ ((w2row >> 1) & 3)) * 8;      // row-pair XOR source col

    auto STAGE = [&](int d, int s) {
        #pragma unroll
        for (int hx = 0; hx < 4; hx++) {
            const int c0 = hx * 512 + s * 32;
            GLD_LDS16((const char*)W1 + (size_t)(c0 + piq) * 256 + w1cb,
                      smem + d * 32768 + hx * 8192 + tid * 16);
            GLD_LDS16(W2 + (size_t)w2row * 2048 + c0 + w2ce,
                      smem + 65536 + d * 32768 + hx * 8192 + tid * 16);
        }
    };

    f32x4 Oacc[2][8];
    #pragma unroll
    for (int sub = 0; sub < 2; sub++)
        #pragma unroll
        for (int ot = 0; ot < 8; ot++)
            Oacc[sub][ot] = (f32x4){0.f, 0.f, 0.f, 0.f};

    const f32x4 zz = (f32x4){0.f, 0.f, 0.f, 0.f};
    const int xsw = (l4 & 7) << 4;
    const int w2rsw = (l4 >> 1) & 3;         // read-side W2 swizzle term

    STAGE(0, 0);
    for (int s = 0; s < 16; s++) {
        __syncthreads();                     // drains staged loads for buf s&1
        if (s < 15) STAGE((s + 1) & 1, s + 1);   // async, flies during compute
        const int d  = s & 1;
        const int c0 = hq * 512 + s * 32;
        const char* w1b = smem + d * 32768 + hq * 8192;
        const char* w2b = smem + 65536 + d * 32768 + hq * 8192;

        // phase 1: H^T for 32 hidden cols x 2 token sub-tiles
        f32x4 sa00 = zz, sa01 = zz, sa10 = zz, sa11 = zz;
        #pragma unroll
        for (int j = 0; j < 4; j++) {
            const int xo = (j * 64 + g * 16) ^ xsw;
            bf16x8 w10 = *(const bf16x8*)(w1b + l4 * 256 + xo);
            bf16x8 w11 = *(const bf16x8*)(w1b + (16 + l4) * 256 + xo);
            sa00 = MFMA16(w10, tf[0][j], sa00);
            sa01 = MFMA16(w10, tf[1][j], sa01);
            sa10 = MFMA16(w11, tf[0][j], sa10);
            sa11 = MFMA16(w11, tf[1][j], sa11);
        }
        // bias + relu + pack: lane holds hidden cols c0 + 8g + {0..7} per sub
        float4 bv0 = *(const float4*)(b1 + c0 + g * 8);
        float4 bv1 = *(const float4*)(b1 + c0 + g * 8 + 4);
        bf16x8 pf0, pf1;
        pf0[0] = f2bs(fmaxf(sa00[0] + bv0.x, 0.f));
        pf0[1] = f2bs(fmaxf(sa00[1] + bv0.y, 0.f));
        pf0[2] = f2bs(fmaxf(sa00[2] + bv0.z, 0.f));
        pf0[3] = f2bs(fmaxf(sa00[3] + bv0.w, 0.f));
        pf0[4] = f2bs(fmaxf(sa10[0] + bv1.x, 0.f));
        pf0[5] = f2bs(fmaxf(sa10[1] + bv1.y, 0.f));
        pf0[6] = f2bs(fmaxf(sa10[2] + bv1.z, 0.f));
        pf0[7] = f2bs(fmaxf(sa10[3] + bv1.w, 0.f));
        pf1[0] = f2bs(fmaxf(sa01[0] + bv0.x, 0.f));
        pf1[1] = f2bs(fmaxf(sa01[1] + bv0.y, 0.f));
        pf1[2] = f2bs(fmaxf(sa01[2] + bv0.z, 0.f));
        pf1[3] = f2bs(fmaxf(sa01[3] + bv0.w, 0.f));
        pf1[4] = f2bs(fmaxf(sa11[0] + bv1.x, 0.f));
        pf1[5] = f2bs(fmaxf(sa11[1] + bv1.y, 0.f));
        pf1[6] = f2bs(fmaxf(sa11[2] + bv1.z, 0.f));
        pf1[7] = f2bs(fmaxf(sa11[3] + bv1.w, 0.f));

        // phase 2: accumulate all 128 output cols over this k-window;
        // each W2 fragment feeds BOTH token sub-tiles (the v5 point)
        #pragma unroll
        for (int ot = 0; ot < 8; ot++) {
            bf16x8 w2f = *(const bf16x8*)(w2b + (ot * 16 + l4) * 64 + ((g ^ w2rsw) << 4));
            Oacc[0][ot] = MFMA16(pf0, w2f, Oacc[0][ot]);
            Oacc[1][ot] = MFMA16(pf1, w2f, Oacc[1][ot]);
        }
    }

    // ---- reduce hidden quarters (Red aliases dead staging space) ----
    __syncthreads();
    if (hq != 0) {
        #pragma unroll
        for (int sub = 0; sub < 2; sub++)
            #pragma unroll
            for (int ot = 0; ot < 8; ot++)
                *(f32x4*)(smem + tg * 49152 + (hq - 1) * 16384 + (sub * 8 + ot) * 1024
                          + lane * 16) = Oacc[sub][ot];
    }
    __syncthreads();
    if (hq == 0) {
        #pragma unroll
        for (int p = 0; p < 3; p++)
            #pragma unroll
            for (int sub = 0; sub < 2; sub++)
                #pragma unroll
                for (int ot = 0; ot < 8; ot++) {
                    f32x4 o2 = *(const f32x4*)(smem + tg * 49152 + p * 16384
                                               + (sub * 8 + ot) * 1024 + lane * 16);
                    Oacc[sub][ot][0] += o2[0]; Oacc[sub][ot][1] += o2[1];
                    Oacc[sub][ot][2] += o2[2]; Oacc[sub][ot][3] += o2[3];
                }

        #pragma unroll
        for (int sub = 0; sub < 2; sub++) {
            // bias + residual;  lane: col = ot*16 + l4, token = (tg*2+sub)*16 + 4g + r
            float vv[8][4];
            #pragma unroll
            for (int ot = 0; ot < 8; ot++) {
                const int col = ot * 16 + l4;
                const float bv = b2[col];
                #pragma unroll
                for (int r = 0; r < 4; r++) {
                    const int trow = bm + (tg * 2 + sub) * 16 + 4 * g + r;
                    vv[ot][r] = Oacc[sub][ot][r] + bv
                              + __bfloat162float(A[(size_t)trow * 128 + col]);
                }
            }

            // LN row stats: in-lane over ot, shfl over 16-lane col group
            #pragma unroll
            for (int r = 0; r < 4; r++) {
                float sm = 0.f, qs = 0.f;
                #pragma unroll
                for (int ot = 0; ot < 8; ot++) { float v = vv[ot][r]; sm += v; qs += v * v; }
                #pragma unroll
                for (int off = 1; off < 16; off <<= 1) {
                    sm += __shfl_xor(sm, off);
                    qs += __shfl_xor(qs, off);
                }
                const float mean = sm * (1.0f / 128.0f);
                const float var  = qs * (1.0f / 128.0f) - mean * mean;
                const float rstd = rsqrtf(var + 1e-5f);
                const int trow = bm + (tg * 2 + sub) * 16 + 4 * g + r;
                float hacc = 0.f;
                #pragma unroll
                for (int ot = 0; ot < 8; ot++) {
                    const int col = ot * 16 + l4;
                    const float y = (vv[ot][r] - mean) * rstd * lng[col] + lnb[col];
                    if (HEAD) hacc += y * hw[col];
                    else Y[(size_t)trow * 128 + col] = __float2bfloat16(y);
                }
                if (HEAD) {
                    #pragma unroll
                    for (int off = 1; off < 16; off <<= 1) hacc += __shfl_xor(hacc, off);
                    if (l4 == 0) hout[trow] = hacc;
                }
            }
        }
    }
}

// ---------------------------------------------------------------------------
// Merged fp32->bf16 conversion of all weights + x, plus t2v table (segment 9).
// ---------------------------------------------------------------------------
struct ConvDesc {
    const float *x, *s1, *s2, *s3, *s4, *s5, *s6, *s7, *s8;
    bf16 *dx, *d1, *d2, *d3, *d4, *d5, *d6, *d7, *d8;
    const float *w, *b, *w0, *b0;
    float* tbl;
};

__device__ inline void cvt4(const float* s, bf16* d, int j) {
    float4 v = ((const float4*)s)[j];
    ushort4 o;
    o.x = (unsigned short)f2bs(v.x); o.y = (unsigned short)f2bs(v.y);
    o.z = (unsigned short)f2bs(v.z); o.w = (unsigned short)f2bs(v.w);
    *(ushort4*)((unsigned short*)d + j * 4) = o;
}

// prefix sums in float4 units
#define CP0 524288   // x            (2097152)
#define CP1 536576   // enc_in_w     (49152)
#define CP2 540672   // enc_out_w    (16384)
#define CP3 606208   // enc_l1w      (262144)
#define CP4 671744   // enc_l2w      (262144)
#define CP5 696320   // qk_in_w      (98304)
#define CP6 704512   // qk_out_w     (32768)
#define CP7 835584   // qk_l1w       (524288)
#define CP8 966656   // qk_l2w       (524288)
#define CP9 967680   // t2v table    (4096 fp32)

__global__ __launch_bounds__(256) void conv_all_kernel(ConvDesc cd)
{
    int i = blockIdx.x * 256 + threadIdx.x;
    if (i < CP0)      cvt4(cd.x,  cd.dx, i);
    else if (i < CP1) cvt4(cd.s1, cd.d1, i - CP0);
    else if (i < CP2) cvt4(cd.s2, cd.d2, i - CP1);
    else if (i < CP3) cvt4(cd.s3, cd.d3, i - CP2);
    else if (i < CP4) cvt4(cd.s4, cd.d4, i - CP3);
    else if (i < CP5) cvt4(cd.s5, cd.d5, i - CP4);
    else if (i < CP6) cvt4(cd.s6, cd.d6, i - CP5);
    else if (i < CP7) cvt4(cd.s7, cd.d7, i - CP6);
    else if (i < CP8) cvt4(cd.s8, cd.d8, i - CP7);
    else if (i < CP9) {
        int e = (i - CP8) * 4;
        int t = e >> 7;
        float tau = (float)(t + 1);
        float4 o;
        #pragma unroll
        for (int k = 0; k < 4; k++) {
            int d = (e + k) & 127;
            ((float*)&o)[k] = (d < 127) ? sinf(tau * cd.w[d] + cd.b[d])
                                        : (tau * cd.w0[0] + cd.b0[0]);
        }
        *(float4*)(cd.tbl + e) = o;
    }
}

// ---------------------------------------------------------------------------
// Stage-1 attention via MFMA (flash, maxless). One block per (t,h).
// ---------------------------------------------------------------------------
__global__ __launch_bounds__(256) void attn_full_mfma(
    const bf16* __restrict__ Qkv, bf16* __restrict__ C)
{
    __shared__ bf16 Qs[512 * 16];
    __shared__ bf16 Ks[512 * 16];
    __shared__ bf16 Vt[16 * 520];
    __shared__ bf16 Zero[32];          // 64B broadcast zero block

    const int t = blockIdx.x >> 3;
    const int h = blockIdx.x & 7;
    const int tid = threadIdx.x;

    if (tid < 32) ((unsigned short*)Zero)[tid] = 0;

    for (int n = tid; n < 512; n += 256) {
        const unsigned short* row = (const unsigned short*)Qkv + (size_t)(t * 512 + n) * 384 + h * 16;
        uint4 q0 = *(const uint4*)(row);
        uint4 q1 = *(const uint4*)(row + 8);
        uint4 k0 = *(const uint4*)(row + 128);
        uint4 k1 = *(const uint4*)(row + 136);
        uint4 v0 = *(const uint4*)(row + 256);
        uint4 v1 = *(const uint4*)(row + 264);
        *(uint4*)((unsigned short*)Qs + n * 16)     = q0;
        *(uint4*)((unsigned short*)Qs + n * 16 + 8) = q1;
        *(uint4*)((unsigned short*)Ks + n * 16)     = k0;
        *(uint4*)((unsigned short*)Ks + n * 16 + 8) = k1;
        union { uint4 u[2]; unsigned short s[16]; } vb;
        vb.u[0] = v0; vb.u[1] = v1;
        #pragma unroll
        for (int f = 0; f < 16; f++)
            ((unsigned short*)Vt)[f * 520 + n] = vb.s[f];
    }
    __syncthreads();

    const int lane = tid & 63;
    const int wv   = tid >> 6;
    const int l4   = lane & 15;
    const int g    = lane >> 4;
    const int qbase = wv * 128;
    const bf16* zp = Zero + (g & 1) * 8;
    const int p0 = ((l4 >> 2) << 3) | (l4 & 3);      // pi0 key permutation

    bf16x8 qf[8];
    #pragma unroll
    for (int qt = 0; qt < 8; qt++) {
        const bf16* ap = (g < 2) ? (Qs + (qbase + qt * 16 + l4) * 16 + g * 8) : zp;
        qf[qt] = *(const bf16x8*)ap;
    }

    f32x4 Oacc[8];
    float lsum[8];
    #pragma unroll
    for (int qt = 0; qt < 8; qt++) { Oacc[qt] = (f32x4){0.f,0.f,0.f,0.f}; lsum[qt] = 0.f; }

    const float cexp = 0.25f * 1.44269504088896f;   // scale * log2(e)

    for (int kt = 0; kt < 16; kt++) {               // 32 keys per iteration
        const bf16* k0p = (g < 2) ? (Ks + (kt * 32 + p0)     * 16 + g * 8) : zp;
        const bf16* k1p = (g < 2) ? (Ks + (kt * 32 + p0 + 4) * 16 + g * 8) : zp;
        bf16x8 kf0 = *(const bf16x8*)k0p;
        bf16x8 kf1 = *(const bf16x8*)k1p;
        bf16x8 vf  = *(const bf16x8*)(Vt + l4 * 520 + kt * 32 + g * 8);

        #pragma unroll
        for (int qt = 0; qt < 8; qt++) {
            f32x4 z = (f32x4){0.f,0.f,0.f,0.f};
            f32x4 s0 = MFMA16(kf0, qf[qt], z);
            f32x4 s1 = MFMA16(kf1, qf[qt], z);
            float e[8];
            #pragma unroll
            for (int r = 0; r < 4; r++) {
                e[r]     = exp2f(s0[r] * cexp);
                e[4 + r] = exp2f(s1[r] * cexp);
            }
            lsum[qt] += ((e[0]+e[1])+(e[2]+e[3])) + ((e[4]+e[5])+(e[6]+e[7]));
            bf16x8 pf;
            #pragma unroll
            for (int i = 0; i < 8; i++) pf[i] = f2bs(e[i]);
            Oacc[qt] = MFMA16(pf, vf, Oacc[qt]);
        }
    }

    #pragma unroll
    for (int qt = 0; qt < 8; qt++) {
        float ls = lsum[qt];
        ls += __shfl_xor(ls, 16);
        ls += __shfl_xor(ls, 32);
        #pragma unroll
        for (int r = 0; r < 4; r++) {
            float lq = __shfl(ls, g * 4 + r);
            float o = Oacc[qt][r] / lq;
            int qrow = t * 512 + qbase + qt * 16 + g * 4 + r;
            C[(size_t)qrow * 128 + h * 16 + l4] = __float2bfloat16(o);
        }
    }
}

// ---------------------------------------------------------------------------
// Stage-3 banded attention: window j in [i-7, i]. bf16 q/k/v in, bf16 out.
// ---------------------------------------------------------------------------
__global__ __launch_bounds__(256) void attn_banded_kernel(
    const bf16* __restrict__ Qkv, const bf16* __restrict__ Vb, bf16* __restrict__ C)
{
    __shared__ float Qs[TT][129];
    __shared__ float Ksh[TT][129];
    __shared__ float Vs[TT][129];
    const int n = blockIdx.x;
    const int tid = threadIdx.x;

    for (int e = tid; e < TT * DD; e += 256) {
        int t = e >> 7, d = e & 127;
        const bf16* row = Qkv + (size_t)(t * NN + n) * 384;
        Qs[t][d]  = __bfloat162float(row[d]);
        Ksh[t][d] = __bfloat162float(row[128 + d]);
        Vs[t][d]  = __bfloat162float(Vb[(size_t)(t * NN + n) * DD + d]);
    }
    __syncthreads();

    const int h = tid >> 5, i = tid & 31;
    const int hb = h * DH;

    float s[WND_];
    #pragma unroll
    for (int kk = 0; kk < WND_; kk++) {
        int j = i - (WND_ - 1) + kk;
        int jc = j < 0 ? 0 : j;
        float d = 0.f;
        #pragma unroll
        for (int f = 0; f < DH; f++) d += Qs[i][hb + f] * Ksh[jc][hb + f];
        s[kk] = (j >= 0) ? d * 0.25f : -1e30f;
    }
    float m = s[0];
    #pragma unroll
    for (int kk = 1; kk < WND_; kk++) m = fmaxf(m, s[kk]);
    float l = 0.f, p[WND_];
    #pragma unroll
    for (int kk = 0; kk < WND_; kk++) { p[kk] = __expf(s[kk] - m); l += p[kk]; }
    float inv = 1.f / l;
    float acc[DH] = {};
    #pragma unroll
    for (int kk = 0; kk < WND_; kk++) {
        int j = i - (WND_ - 1) + kk;
        int jc = j < 0 ? 0 : j;
        float pw = p[kk] * inv;
        #pragma unroll
        for (int f = 0; f < DH; f++) acc[f] += pw * Vs[jc][hb + f];
    }
    bf16* cp = C + (size_t)(i * NN + n) * DD + hb;
    #pragma unroll
    for (int f = 0; f < DH; f++) cp[f] = __float2bfloat16(acc[f]);
}

// ---------------------------------------------------------------------------
// time2vec add: Y = bf16(x + tbl[t, d])
// ---------------------------------------------------------------------------
__global__ __launch_bounds__(256) void t2v_add_kernel(
    const float* __restrict__ x, const float* __restrict__ tbl, bf16* __restrict__ Y)
{
    int i = blockIdx.x * 256 + threadIdx.x;     // float4 groups
    int e = i * 4;
    float4 xv = ((const float4*)x)[i];
    int ti = ((e >> 16) << 7) | (e & 127);
    float4 tv = *(const float4*)(tbl + ti);
    ushort4 o;
    o.x = (unsigned short)f2bs(xv.x + tv.x);
    o.y = (unsigned short)f2bs(xv.y + tv.y);
    o.z = (unsigned short)f2bs(xv.z + tv.z);
    o.w = (unsigned short)f2bs(xv.w + tv.w);
    *(ushort4*)((unsigned short*)Y + e) = o;
}

// ---------------------------------------------------------------------------

extern "C" void kernel_launch(void* const* d_in, const int* in_sizes, int n_in,
                              void* d_out, int out_size, void* d_ws, size_t ws_size,
                              hipStream_t stream) {
    const float* x           = (const float*)d_in[0];
    const float* enc_in_w    = (const float*)d_in[1];
    const float* enc_in_b    = (const float*)d_in[2];
    const float* enc_out_w   = (const float*)d_in[3];
    const float* enc_out_b   = (const float*)d_in[4];
    const float* enc_l1w     = (const float*)d_in[5];
    const float* enc_l1b     = (const float*)d_in[6];
    const float* enc_l2w     = (const float*)d_in[7];
    const float* enc_l2b     = (const float*)d_in[8];
    const float* enc_ln1w    = (const float*)d_in[9];
    const float* enc_ln1b    = (const float*)d_in[10];
    const float* enc_ln2w    = (const float*)d_in[11];
    const float* enc_ln2b    = (const float*)d_in[12];
    const float* qk_in_w     = (const float*)d_in[13];
    const float* qk_in_b     = (const float*)d_in[14];
    const float* qk_out_w    = (const float*)d_in[15];
    const float* qk_out_b    = (const float*)d_in[16];
    const float* qk_l1w      = (const float*)d_in[17];
    const float* qk_l1b      = (const float*)d_in[18];
    const float* qk_l2w      = (const float*)d_in[19];
    const float* qk_l2b      = (const float*)d_in[20];
    const float* qk_ln1w     = (const float*)d_in[21];
    const float* qk_ln1b     = (const float*)d_in[22];
    const float* qk_ln2w     = (const float*)d_in[23];
    const float* qk_ln2b     = (const float*)d_in[24];
    const float* t2v_w       = (const float*)d_in[25];
    const float* t2v_b       = (const float*)d_in[26];
    const float* t2v_w0      = (const float*)d_in[27];
    const float* t2v_b0      = (const float*)d_in[28];
    const float* out_w       = (const float*)d_in[29];
    float* out = (float*)d_out;

    // ---------------- workspace layout (bytes) ------------------------------
    char* ws = (char*)d_ws;
    const size_t TOKD = (size_t)TOK * DD;
    size_t off = 0;
    auto alloc = [&](size_t bytes) { char* p = ws + off; off += (bytes + 255) & ~(size_t)255; return p; };

    bf16*  Qb   = (bf16*)alloc((size_t)TOK * 384 * 2);   // qkv bf16
    bf16*  Vb   = (bf16*)alloc(TOKD * 2);                // v-projection bf16
    bf16*  xb   = (bf16*)alloc(TOKD * 2);                // bf16 copy of x
    bf16*  bufA = (bf16*)alloc(TOKD * 2);                // residual stream bf16
    bf16*  Zb   = (bf16*)alloc(TOKD * 2);                // outs_zs bf16
    bf16*  Cb   = (bf16*)alloc(TOKD * 2);                // attn context bf16
    float* t2vt = (float*)alloc((size_t)TT * DD * 4);    // time2vec table
    bf16* enc_in_wb  = (bf16*)alloc(384 * DD * 2);
    bf16* enc_out_wb = (bf16*)alloc(DD * DD * 2);
    bf16* enc_l1wb   = (bf16*)alloc((size_t)FF_ * DD * 2);
    bf16* enc_l2wb   = (bf16*)alloc((size_t)DD * FF_ * 2);
    bf16* qk_in_wb   = (bf16*)alloc((size_t)LL * 384 * DD * 2);
    bf16* qk_out_wb  = (bf16*)alloc((size_t)LL * DD * DD * 2);
    bf16* qk_l1wb    = (bf16*)alloc((size_t)LL * FF_ * DD * 2);
    bf16* qk_l2wb    = (bf16*)alloc((size_t)LL * DD * FF_ * 2);

    // ---------------- one-shot conversion of all weights + x + t2v table ----
    ConvDesc cd;
    cd.x  = x;        cd.dx = xb;
    cd.s1 = enc_in_w; cd.d1 = enc_in_wb;
    cd.s2 = enc_out_w;cd.d2 = enc_out_wb;
    cd.s3 = enc_l1w;  cd.d3 = enc_l1wb;
    cd.s4 = enc_l2w;  cd.d4 = enc_l2wb;
    cd.s5 = qk_in_w;  cd.d5 = qk_in_wb;
    cd.s6 = qk_out_w; cd.d6 = qk_out_wb;
    cd.s7 = qk_l1w;   cd.d7 = qk_l1wb;
    cd.s8 = qk_l2w;   cd.d8 = qk_l2wb;
    cd.w = t2v_w; cd.b = t2v_b; cd.w0 = t2v_w0; cd.b0 = t2v_b0; cd.tbl = t2vt;
    conv_all_kernel<<<(CP9 + 255) / 256, 256, 0, stream>>>(cd);

    auto gemm128 = [&](const bf16* A, int lda, const bf16* W, const float* bias,
                       bf16* C, int ldc, int M, int N, int K, int relu) {
        dim3 grid(N / 128, M / 128);
        mfma_gemm<128, 128><<<grid, 256, 0, stream>>>(A, lda, W, bias, C, ldc, K, relu);
    };
    auto gemm64 = [&](const bf16* A, int lda, const bf16* W, const float* bias,
                      bf16* C, int ldc, int M, int N, int K, int relu) {
        dim3 grid(N / 64, M / 64);
        mfma_gemm<64, 64><<<grid, 256, 0, stream>>>(A, lda, W, bias, C, ldc, K, relu);
    };
    auto gemm_ln = [&](const bf16* A, int lda, const bf16* W, const float* bias,
                       const bf16* R, const float* lng, const float* lnb,
                       bf16* Y, int M, int K) {
        mfma_gemm_ln<<<M / 64, 256, 0, stream>>>(A, lda, W, bias, R, lng, lnb, Y, K);
    };

    // ---------------- stage 1: plain encoder (attend over N, batch T) -------
    gemm128(xb, DD, enc_in_wb, enc_in_b, Qb, 384, TOK, 384, DD, 0);
    attn_full_mfma<<<TT * HH, 256, 0, stream>>>(Qb, Cb);
    gemm_ln(Cb, DD, enc_out_wb, enc_out_b, xb, enc_ln1w, enc_ln1b, bufA, TOK, DD);
    ffn_fused<false><<<TOK / 64, 512, 0, stream>>>(
        bufA, enc_l1wb, enc_l1b, enc_l2wb, enc_l2b,
        enc_ln2w, enc_ln2b, Zb, nullptr, nullptr);

    // ---------------- stage 2: time2vec -------------------------------------
    t2v_add_kernel<<<(TOK * DD / 4) / 256, 256, 0, stream>>>(x, t2vt, bufA);

    // ---------------- stage 3: qk encoder stack (banded window attn) ---------
    for (int l = 0; l < LL; l++) {
        const bf16* iw   = qk_in_wb  + (size_t)l * 384 * DD;
        const float* ib  = qk_in_b   + (size_t)l * 384;
        const bf16* owt  = qk_out_wb + (size_t)l * DD * DD;
        const float* ob  = qk_out_b  + (size_t)l * DD;
        const bf16* l1w  = qk_l1wb   + (size_t)l * FF_ * DD;
        const float* l1b = qk_l1b    + (size_t)l * FF_;
        const bf16* l2w  = qk_l2wb   + (size_t)l * DD * FF_;
        const float* l2b = qk_l2b    + (size_t)l * DD;

        gemm128(bufA, DD, iw, ib, Qb, 384, TOK, 256, DD, 0);
        gemm64(Zb, DD, iw + (size_t)256 * DD, ib + 256, Vb, DD, TOK, DD, DD, 0);
        attn_banded_kernel<<<NN, 256, 0, stream>>>(Qb, Vb, Cb);
        gemm_ln(Cb, DD, owt, ob, bufA, qk_ln1w + l * DD, qk_ln1b + l * DD, bufA, TOK, DD);
        if (l == LL - 1) {
            ffn_fused<true><<<TOK / 64, 512, 0, stream>>>(
                bufA, l1w, l1b, l2w, l2b,
                qk_ln2w + l * DD, qk_ln2b + l * DD, nullptr, out_w, out);
        } else {
            ffn_fused<false><<<TOK / 64, 512, 0, stream>>>(
                bufA, l1w, l1b, l2w, l2b,
                qk_ln2w + l * DD, qk_ln2b + l * DD, bufA, nullptr, nullptr);
        }
    }
}

// Round 11
// 214.987 us; speedup vs baseline: 1.6236x; 1.0368x over previous
//
#include <hip/hip_runtime.h>
#include <hip/hip_bf16.h>
#include <math.h>

// Problem constants
#define TT 32
#define NN 512
#define DD 128
#define FF_ 2048
#define HH 8
#define LL 2
#define WND_ 8
#define TOK (TT*NN)          // 16384 tokens
#define DH 16                // head dim

typedef __hip_bfloat16 bf16;
typedef __attribute__((ext_vector_type(8))) short bf16x8;   // 8 bf16 (4 VGPRs)
typedef __attribute__((ext_vector_type(4))) float f32x4;    // 4 fp32

// global_load_lds: 16B per lane, LDS dest = wave-uniform base + lane*16 (linear)
#define GLD_LDS16(gp, lp) __builtin_amdgcn_global_load_lds( \
    (const __attribute__((address_space(1))) unsigned int*)(gp), \
    (__attribute__((address_space(3))) unsigned int*)(lp), 16, 0, 0)

#define MFMA16(a, b, c) __builtin_amdgcn_mfma_f32_16x16x32_bf16((a), (b), (c), 0, 0, 0)

__device__ inline short f2bs(float f) {
    __hip_bfloat16 h = __float2bfloat16(f);
    return *reinterpret_cast<short*>(&h);
}

// ---------------------------------------------------------------------------
// bf16 MFMA GEMM: C[M,N] = A[M,K] @ W[N,K]^T + bias (+relu). Output bf16.
// Tile BM x BN, BK=32, 256 threads = 4 waves in 2x2.
// ---------------------------------------------------------------------------
template<int BM, int BN>
__global__ __launch_bounds__(256) void mfma_gemm(
    const bf16* __restrict__ A, int lda,
    const bf16* __restrict__ W,              // [N,K] row-major (= B^T)
    const float* __restrict__ bias,          // [N]
    bf16* __restrict__ C, int ldc,
    int K, int relu)
{
    constexpr int WM = BM / 2, WN = BN / 2;
    constexpr int FM = WM / 16, FN = WN / 16;
    constexpr int LA = (BM * 64) / (256 * 16);
    constexpr int LB = (BN * 64) / (256 * 16);

    __shared__ bf16 As[BM * 32];
    __shared__ bf16 Bs[BN * 32];

    const int tid  = threadIdx.x;
    const int lane = tid & 63;
    const int wave = tid >> 6;
    const int wm = wave >> 1, wn = wave & 1;
    const int bm = blockIdx.y * BM, bn = blockIdx.x * BN;

    f32x4 acc[FM][FN];
    #pragma unroll
    for (int m = 0; m < FM; m++)
        #pragma unroll
        for (int n = 0; n < FN; n++)
            acc[m][n] = (f32x4){0.f, 0.f, 0.f, 0.f};

    for (int k0 = 0; k0 < K; k0 += 32) {
        #pragma unroll
        for (int i = 0; i < LA; i++) {
            const int o = (tid + i * 256) * 16;
            const int row = o >> 6;
            const int ce  = (o & 63) >> 1;
            GLD_LDS16(A + (size_t)(bm + row) * lda + k0 + ce, (char*)As + o);
        }
        #pragma unroll
        for (int i = 0; i < LB; i++) {
            const int o = (tid + i * 256) * 16;
            const int row = o >> 6;
            const int ce  = (o & 63) >> 1;
            GLD_LDS16(W + (size_t)(bn + row) * K + k0 + ce, (char*)Bs + o);
        }
        __syncthreads();

        bf16x8 af[FM], bfr[FN];
        #pragma unroll
        for (int m = 0; m < FM; m++)
            af[m] = *(const bf16x8*)(As + (wm * WM + m * 16 + (lane & 15)) * 32 + (lane >> 4) * 8);
        #pragma unroll
        for (int n = 0; n < FN; n++)
            bfr[n] = *(const bf16x8*)(Bs + (wn * WN + n * 16 + (lane & 15)) * 32 + (lane >> 4) * 8);
        #pragma unroll
        for (int m = 0; m < FM; m++)
            #pragma unroll
            for (int n = 0; n < FN; n++)
                acc[m][n] = MFMA16(af[m], bfr[n], acc[m][n]);
        __syncthreads();
    }

    // C/D layout: col = lane&15, row = (lane>>4)*4 + reg
    #pragma unroll
    for (int n = 0; n < FN; n++) {
        const int col = bn + wn * WN + n * 16 + (lane & 15);
        const float bv = bias[col];
        #pragma unroll
        for (int m = 0; m < FM; m++) {
            #pragma unroll
            for (int r = 0; r < 4; r++) {
                const int row = bm + wm * WM + m * 16 + (lane >> 4) * 4 + r;
                float v = acc[m][n][r] + bv;
                if (relu) v = fmaxf(v, 0.f);
                C[(size_t)row * ldc + col] = __float2bfloat16(v);
            }
        }
    }
}

// ---------------------------------------------------------------------------
// Merged stage-3 projection: grid (3, TOK/128). Column tiles 0,1 compute q,k
// from A1 (bufA) -> Qb [TOK,384] cols 0..255; tile 2 computes v from A2 (Zb)
// -> Vb [TOK,128]. Same body as mfma_gemm<128,128>, K=128.
// ---------------------------------------------------------------------------
__global__ __launch_bounds__(256) void qkv_proj(
    const bf16* __restrict__ A1, const bf16* __restrict__ A2,
    const bf16* __restrict__ W,              // [384,128]
    const float* __restrict__ bias,          // [384]
    bf16* __restrict__ Qb, bf16* __restrict__ Vb)
{
    constexpr int BM = 128, BN = 128, WM = 64, WN = 64, FM = 4, FN = 4;

    __shared__ bf16 As[BM * 32];
    __shared__ bf16 Bs[BN * 32];

    const int tid  = threadIdx.x;
    const int lane = tid & 63;
    const int wave = tid >> 6;
    const int wm = wave >> 1, wn = wave & 1;
    const int bnb = blockIdx.x;              // 0,1 = q,k ; 2 = v
    const int bm  = blockIdx.y * BM;

    const bf16* A  = (bnb == 2) ? A2 : A1;
    const bf16* Wb = W + (size_t)bnb * 128 * 128;

    f32x4 acc[FM][FN];
    #pragma unroll
    for (int m = 0; m < FM; m++)
        #pragma unroll
        for (int n = 0; n < FN; n++)
            acc[m][n] = (f32x4){0.f, 0.f, 0.f, 0.f};

    for (int k0 = 0; k0 < 128; k0 += 32) {
        #pragma unroll
        for (int i = 0; i < 2; i++) {
            const int o = (tid + i * 256) * 16;
            const int row = o >> 6;
            const int ce  = (o & 63) >> 1;
            GLD_LDS16(A + (size_t)(bm + row) * 128 + k0 + ce, (char*)As + o);
        }
        #pragma unroll
        for (int i = 0; i < 2; i++) {
            const int o = (tid + i * 256) * 16;
            const int row = o >> 6;
            const int ce  = (o & 63) >> 1;
            GLD_LDS16(Wb + (size_t)row * 128 + k0 + ce, (char*)Bs + o);
        }
        __syncthreads();

        bf16x8 af[FM], bfr[FN];
        #pragma unroll
        for (int m = 0; m < FM; m++)
            af[m] = *(const bf16x8*)(As + (wm * WM + m * 16 + (lane & 15)) * 32 + (lane >> 4) * 8);
        #pragma unroll
        for (int n = 0; n < FN; n++)
            bfr[n] = *(const bf16x8*)(Bs + (wn * WN + n * 16 + (lane & 15)) * 32 + (lane >> 4) * 8);
        #pragma unroll
        for (int m = 0; m < FM; m++)
            #pragma unroll
            for (int n = 0; n < FN; n++)
                acc[m][n] = MFMA16(af[m], bfr[n], acc[m][n]);
        __syncthreads();
    }

    #pragma unroll
    for (int n = 0; n < FN; n++) {
        const int cl = wn * WN + n * 16 + (lane & 15);     // local col 0..127
        const float bv = bias[bnb * 128 + cl];
        #pragma unroll
        for (int m = 0; m < FM; m++) {
            #pragma unroll
            for (int r = 0; r < 4; r++) {
                const int row = bm + wm * WM + m * 16 + (lane >> 4) * 4 + r;
                const float v = acc[m][n][r] + bv;
                if (bnb == 2) Vb[(size_t)row * 128 + cl] = __float2bfloat16(v);
                else          Qb[(size_t)row * 384 + bnb * 128 + cl] = __float2bfloat16(v);
            }
        }
    }
}

// ---------------------------------------------------------------------------
// Fused GEMM + bias + residual + LayerNorm (stage-1 out_proj path, K=128).
// BM=64, BN=128 (full LN row). 256 threads, waves 2x2, each wave 32x64.
// ---------------------------------------------------------------------------
__global__ __launch_bounds__(256) void mfma_gemm_ln(
    const bf16* __restrict__ A, int lda,
    const bf16* __restrict__ W,              // [128,K]
    const float* __restrict__ bias,          // [128]
    const bf16* __restrict__ R,              // residual [M,128] bf16
    const float* __restrict__ lng, const float* __restrict__ lnb,
    bf16* __restrict__ Y,                    // [M,128] bf16
    int K)
{
    constexpr int BM = 64, WM = 32, WN = 64, FM = 2, FN = 4;

    __shared__ bf16 As[BM * 32];
    __shared__ bf16 Bs[128 * 32];
    __shared__ float rsum[BM][2];
    __shared__ float rsq[BM][2];

    const int tid  = threadIdx.x;
    const int lane = tid & 63;
    const int wave = tid >> 6;
    const int wm = wave >> 1, wn = wave & 1;
    const int bm = blockIdx.x * BM;

    f32x4 acc[FM][FN];
    #pragma unroll
    for (int m = 0; m < FM; m++)
        #pragma unroll
        for (int n = 0; n < FN; n++)
            acc[m][n] = (f32x4){0.f, 0.f, 0.f, 0.f};

    for (int k0 = 0; k0 < K; k0 += 32) {
        {   // A tile: 64 rows x 32 cols
            const int o = tid * 16;
            const int row = o >> 6;
            const int ce  = (o & 63) >> 1;
            GLD_LDS16(A + (size_t)(bm + row) * lda + k0 + ce, (char*)As + o);
        }
        #pragma unroll
        for (int i = 0; i < 2; i++) {       // B tile: 128 rows
            const int o = (tid + i * 256) * 16;
            const int row = o >> 6;
            const int ce  = (o & 63) >> 1;
            GLD_LDS16(W + (size_t)row * K + k0 + ce, (char*)Bs + o);
        }
        __syncthreads();

        bf16x8 af[FM], bfr[FN];
        #pragma unroll
        for (int m = 0; m < FM; m++)
            af[m] = *(const bf16x8*)(As + (wm * WM + m * 16 + (lane & 15)) * 32 + (lane >> 4) * 8);
        #pragma unroll
        for (int n = 0; n < FN; n++)
            bfr[n] = *(const bf16x8*)(Bs + (wn * WN + n * 16 + (lane & 15)) * 32 + (lane >> 4) * 8);
        #pragma unroll
        for (int m = 0; m < FM; m++)
            #pragma unroll
            for (int n = 0; n < FN; n++)
                acc[m][n] = MFMA16(af[m], bfr[n], acc[m][n]);
        __syncthreads();
    }

    // bias + residual
    #pragma unroll
    for (int n = 0; n < FN; n++) {
        const int col = wn * WN + n * 16 + (lane & 15);
        const float bv = bias[col];
        #pragma unroll
        for (int m = 0; m < FM; m++) {
            #pragma unroll
            for (int r = 0; r < 4; r++) {
                const int rl = wm * WM + m * 16 + (lane >> 4) * 4 + r;
                acc[m][n][r] += bv + __bfloat162float(R[(size_t)(bm + rl) * 128 + col]);
            }
        }
    }

    // row sums
    #pragma unroll
    for (int m = 0; m < FM; m++) {
        #pragma unroll
        for (int r = 0; r < 4; r++) {
            float s = 0.f, q = 0.f;
            #pragma unroll
            for (int n = 0; n < FN; n++) { float v = acc[m][n][r]; s += v; q += v * v; }
            #pragma unroll
            for (int off = 1; off < 16; off <<= 1) {
                s += __shfl_xor(s, off);
                q += __shfl_xor(q, off);
            }
            const int rl = wm * WM + m * 16 + (lane >> 4) * 4 + r;
            if ((lane & 15) == 0) { rsum[rl][wn] = s; rsq[rl][wn] = q; }
        }
    }
    __syncthreads();

    #pragma unroll
    for (int m = 0; m < FM; m++) {
        #pragma unroll
        for (int r = 0; r < 4; r++) {
            const int rl = wm * WM + m * 16 + (lane >> 4) * 4 + r;
            const float S = rsum[rl][0] + rsum[rl][1];
            const float Q = rsq[rl][0] + rsq[rl][1];
            const float mean = S * (1.0f / 128.0f);
            const float var  = Q * (1.0f / 128.0f) - mean * mean;
            const float rstd = rsqrtf(var + 1e-5f);
            #pragma unroll
            for (int n = 0; n < FN; n++) {
                const int col = wn * WN + n * 16 + (lane & 15);
                const float y = (acc[m][n][r] - mean) * rstd * lng[col] + lnb[col];
                Y[(size_t)(bm + rl) * 128 + col] = __float2bfloat16(y);
            }
        }
    }
}

// ---------------------------------------------------------------------------
// FFN v5 (unchanged from round 10): Y = LN(A + FFN(A)) [* head]
// ---------------------------------------------------------------------------
template<bool HEAD>
__global__ __launch_bounds__(512) void ffn_fused(
    const bf16* __restrict__ A,
    const bf16* __restrict__ W1, const float* __restrict__ b1,
    const bf16* __restrict__ W2, const float* __restrict__ b2,
    const float* __restrict__ lng, const float* __restrict__ lnb,
    bf16* __restrict__ Y,
    const float* __restrict__ hw, float* __restrict__ hout)
{
    __shared__ char smem[131072];

    const int tid  = threadIdx.x;
    const int lane = tid & 63;
    const int wv   = tid >> 6;
    const int tg   = wv & 1;
    const int hq   = wv >> 1;
    const int l4   = lane & 15;
    const int g    = lane >> 4;
    const int bm   = blockIdx.x * 64;

    bf16x8 tf[2][4];
    #pragma unroll
    for (int sub = 0; sub < 2; sub++)
        #pragma unroll
        for (int j = 0; j < 4; j++)
            tf[sub][j] = *(const bf16x8*)(A + (size_t)(bm + (tg * 2 + sub) * 16 + l4) * 128
                                          + j * 32 + g * 8);

    const int q    = tid >> 4;
    const int qq   = q & 15;
    const int piq  = (((qq >> 2) << 3) | (qq & 3)) + ((q >> 4) << 2);
    const int w1cb = ((tid & 15) * 16) ^ ((q & 7) << 4);
    const int w2row = tid >> 2;
    const int w2ce  = ((tid & 3) ^ ((w2row >> 1) & 3)) * 8;

    auto STAGE = [&](int d, int s) {
        #pragma unroll
        for (int hx = 0; hx < 4; hx++) {
            const int c0 = hx * 512 + s * 32;
            GLD_LDS16((const char*)W1 + (size_t)(c0 + piq) * 256 + w1cb,
                      smem + d * 32768 + hx * 8192 + tid * 16);
            GLD_LDS16(W2 + (size_t)w2row * 2048 + c0 + w2ce,
                      smem + 65536 + d * 32768 + hx * 8192 + tid * 16);
        }
    };

    f32x4 Oacc[2][8];
    #pragma unroll
    for (int sub = 0; sub < 2; sub++)
        #pragma unroll
        for (int ot = 0; ot < 8; ot++)
            Oacc[sub][ot] = (f32x4){0.f, 0.f, 0.f, 0.f};

    const f32x4 zz = (f32x4){0.f, 0.f, 0.f, 0.f};
    const int xsw = (l4 & 7) << 4;
    const int w2rsw = (l4 >> 1) & 3;

    STAGE(0, 0);
    for (int s = 0; s < 16; s++) {
        __syncthreads();
        if (s < 15) STAGE((s + 1) & 1, s + 1);
        const int d  = s & 1;
        const int c0 = hq * 512 + s * 32;
        const char* w1b = smem + d * 32768 + hq * 8192;
        const char* w2b = smem + 65536 + d * 32768 + hq * 8192;

        f32x4 sa00 = zz, sa01 = zz, sa10 = zz, sa11 = zz;
        #pragma unroll
        for (int j = 0; j < 4; j++) {
            const int xo = (j * 64 + g * 16) ^ xsw;
            bf16x8 w10 = *(const bf16x8*)(w1b + l4 * 256 + xo);
            bf16x8 w11 = *(const bf16x8*)(w1b + (16 + l4) * 256 + xo);
            sa00 = MFMA16(w10, tf[0][j], sa00);
            sa01 = MFMA16(w10, tf[1][j], sa01);
            sa10 = MFMA16(w11, tf[0][j], sa10);
            sa11 = MFMA16(w11, tf[1][j], sa11);
        }
        float4 bv0 = *(const float4*)(b1 + c0 + g * 8);
        float4 bv1 = *(const float4*)(b1 + c0 + g * 8 + 4);
        bf16x8 pf0, pf1;
        pf0[0] = f2bs(fmaxf(sa00[0] + bv0.x, 0.f));
        pf0[1] = f2bs(fmaxf(sa00[1] + bv0.y, 0.f));
        pf0[2] = f2bs(fmaxf(sa00[2] + bv0.z, 0.f));
        pf0[3] = f2bs(fmaxf(sa00[3] + bv0.w, 0.f));
        pf0[4] = f2bs(fmaxf(sa10[0] + bv1.x, 0.f));
        pf0[5] = f2bs(fmaxf(sa10[1] + bv1.y, 0.f));
        pf0[6] = f2bs(fmaxf(sa10[2] + bv1.z, 0.f));
        pf0[7] = f2bs(fmaxf(sa10[3] + bv1.w, 0.f));
        pf1[0] = f2bs(fmaxf(sa01[0] + bv0.x, 0.f));
        pf1[1] = f2bs(fmaxf(sa01[1] + bv0.y, 0.f));
        pf1[2] = f2bs(fmaxf(sa01[2] + bv0.z, 0.f));
        pf1[3] = f2bs(fmaxf(sa01[3] + bv0.w, 0.f));
        pf1[4] = f2bs(fmaxf(sa11[0] + bv1.x, 0.f));
        pf1[5] = f2bs(fmaxf(sa11[1] + bv1.y, 0.f));
        pf1[6] = f2bs(fmaxf(sa11[2] + bv1.z, 0.f));
        pf1[7] = f2bs(fmaxf(sa11[3] + bv1.w, 0.f));

        #pragma unroll
        for (int ot = 0; ot < 8; ot++) {
            bf16x8 w2f = *(const bf16x8*)(w2b + (ot * 16 + l4) * 64 + ((g ^ w2rsw) << 4));
            Oacc[0][ot] = MFMA16(pf0, w2f, Oacc[0][ot]);
            Oacc[1][ot] = MFMA16(pf1, w2f, Oacc[1][ot]);
        }
    }

    __syncthreads();
    if (hq != 0) {
        #pragma unroll
        for (int sub = 0; sub < 2; sub++)
            #pragma unroll
            for (int ot = 0; ot < 8; ot++)
                *(f32x4*)(smem + tg * 49152 + (hq - 1) * 16384 + (sub * 8 + ot) * 1024
                          + lane * 16) = Oacc[sub][ot];
    }
    __syncthreads();
    if (hq == 0) {
        #pragma unroll
        for (int p = 0; p < 3; p++)
            #pragma unroll
            for (int sub = 0; sub < 2; sub++)
                #pragma unroll
                for (int ot = 0; ot < 8; ot++) {
                    f32x4 o2 = *(const f32x4*)(smem + tg * 49152 + p * 16384
                                               + (sub * 8 + ot) * 1024 + lane * 16);
                    Oacc[sub][ot][0] += o2[0]; Oacc[sub][ot][1] += o2[1];
                    Oacc[sub][ot][2] += o2[2]; Oacc[sub][ot][3] += o2[3];
                }

        #pragma unroll
        for (int sub = 0; sub < 2; sub++) {
            float vv[8][4];
            #pragma unroll
            for (int ot = 0; ot < 8; ot++) {
                const int col = ot * 16 + l4;
                const float bv = b2[col];
                #pragma unroll
                for (int r = 0; r < 4; r++) {
                    const int trow = bm + (tg * 2 + sub) * 16 + 4 * g + r;
                    vv[ot][r] = Oacc[sub][ot][r] + bv
                              + __bfloat162float(A[(size_t)trow * 128 + col]);
                }
            }

            #pragma unroll
            for (int r = 0; r < 4; r++) {
                float sm = 0.f, qs = 0.f;
                #pragma unroll
                for (int ot = 0; ot < 8; ot++) { float v = vv[ot][r]; sm += v; qs += v * v; }
                #pragma unroll
                for (int off = 1; off < 16; off <<= 1) {
                    sm += __shfl_xor(sm, off);
                    qs += __shfl_xor(qs, off);
                }
                const float mean = sm * (1.0f / 128.0f);
                const float var  = qs * (1.0f / 128.0f) - mean * mean;
                const float rstd = rsqrtf(var + 1e-5f);
                const int trow = bm + (tg * 2 + sub) * 16 + 4 * g + r;
                float hacc = 0.f;
                #pragma unroll
                for (int ot = 0; ot < 8; ot++) {
                    const int col = ot * 16 + l4;
                    const float y = (vv[ot][r] - mean) * rstd * lng[col] + lnb[col];
                    if (HEAD) hacc += y * hw[col];
                    else Y[(size_t)trow * 128 + col] = __float2bfloat16(y);
                }
                if (HEAD) {
                    #pragma unroll
                    for (int off = 1; off < 16; off <<= 1) hacc += __shfl_xor(hacc, off);
                    if (l4 == 0) hout[trow] = hacc;
                }
            }
        }
    }
}

// ---------------------------------------------------------------------------
// Merged fp32->bf16 conversion of all weights + x, plus t2v table (segment 9).
// ---------------------------------------------------------------------------
struct ConvDesc {
    const float *x, *s1, *s2, *s3, *s4, *s5, *s6, *s7, *s8;
    bf16 *dx, *d1, *d2, *d3, *d4, *d5, *d6, *d7, *d8;
    const float *w, *b, *w0, *b0;
    float* tbl;
};

__device__ inline void cvt4(const float* s, bf16* d, int j) {
    float4 v = ((const float4*)s)[j];
    ushort4 o;
    o.x = (unsigned short)f2bs(v.x); o.y = (unsigned short)f2bs(v.y);
    o.z = (unsigned short)f2bs(v.z); o.w = (unsigned short)f2bs(v.w);
    *(ushort4*)((unsigned short*)d + j * 4) = o;
}

// prefix sums in float4 units
#define CP0 524288   // x            (2097152)
#define CP1 536576   // enc_in_w     (49152)
#define CP2 540672   // enc_out_w    (16384)
#define CP3 606208   // enc_l1w      (262144)
#define CP4 671744   // enc_l2w      (262144)
#define CP5 696320   // qk_in_w      (98304)
#define CP6 704512   // qk_out_w     (32768)
#define CP7 835584   // qk_l1w       (524288)
#define CP8 966656   // qk_l2w       (524288)
#define CP9 967680   // t2v table    (4096 fp32)

__global__ __launch_bounds__(256) void conv_all_kernel(ConvDesc cd)
{
    int i = blockIdx.x * 256 + threadIdx.x;
    if (i < CP0)      cvt4(cd.x,  cd.dx, i);
    else if (i < CP1) cvt4(cd.s1, cd.d1, i - CP0);
    else if (i < CP2) cvt4(cd.s2, cd.d2, i - CP1);
    else if (i < CP3) cvt4(cd.s3, cd.d3, i - CP2);
    else if (i < CP4) cvt4(cd.s4, cd.d4, i - CP3);
    else if (i < CP5) cvt4(cd.s5, cd.d5, i - CP4);
    else if (i < CP6) cvt4(cd.s6, cd.d6, i - CP5);
    else if (i < CP7) cvt4(cd.s7, cd.d7, i - CP6);
    else if (i < CP8) cvt4(cd.s8, cd.d8, i - CP7);
    else if (i < CP9) {
        int e = (i - CP8) * 4;
        int t = e >> 7;
        float tau = (float)(t + 1);
        float4 o;
        #pragma unroll
        for (int k = 0; k < 4; k++) {
            int d = (e + k) & 127;
            ((float*)&o)[k] = (d < 127) ? sinf(tau * cd.w[d] + cd.b[d])
                                        : (tau * cd.w0[0] + cd.b0[0]);
        }
        *(float4*)(cd.tbl + e) = o;
    }
}

// ---------------------------------------------------------------------------
// Stage-1 attention via MFMA (flash, maxless). One block per (t,h).
// ---------------------------------------------------------------------------
__global__ __launch_bounds__(256) void attn_full_mfma(
    const bf16* __restrict__ Qkv, bf16* __restrict__ C)
{
    __shared__ bf16 Qs[512 * 16];
    __shared__ bf16 Ks[512 * 16];
    __shared__ bf16 Vt[16 * 520];
    __shared__ bf16 Zero[32];          // 64B broadcast zero block

    const int t = blockIdx.x >> 3;
    const int h = blockIdx.x & 7;
    const int tid = threadIdx.x;

    if (tid < 32) ((unsigned short*)Zero)[tid] = 0;

    for (int n = tid; n < 512; n += 256) {
        const unsigned short* row = (const unsigned short*)Qkv + (size_t)(t * 512 + n) * 384 + h * 16;
        uint4 q0 = *(const uint4*)(row);
        uint4 q1 = *(const uint4*)(row + 8);
        uint4 k0 = *(const uint4*)(row + 128);
        uint4 k1 = *(const uint4*)(row + 136);
        uint4 v0 = *(const uint4*)(row + 256);
        uint4 v1 = *(const uint4*)(row + 264);
        *(uint4*)((unsigned short*)Qs + n * 16)     = q0;
        *(uint4*)((unsigned short*)Qs + n * 16 + 8) = q1;
        *(uint4*)((unsigned short*)Ks + n * 16)     = k0;
        *(uint4*)((unsigned short*)Ks + n * 16 + 8) = k1;
        union { uint4 u[2]; unsigned short s[16]; } vb;
        vb.u[0] = v0; vb.u[1] = v1;
        #pragma unroll
        for (int f = 0; f < 16; f++)
            ((unsigned short*)Vt)[f * 520 + n] = vb.s[f];
    }
    __syncthreads();

    const int lane = tid & 63;
    const int wv   = tid >> 6;
    const int l4   = lane & 15;
    const int g    = lane >> 4;
    const int qbase = wv * 128;
    const bf16* zp = Zero + (g & 1) * 8;
    const int p0 = ((l4 >> 2) << 3) | (l4 & 3);      // pi0 key permutation

    bf16x8 qf[8];
    #pragma unroll
    for (int qt = 0; qt < 8; qt++) {
        const bf16* ap = (g < 2) ? (Qs + (qbase + qt * 16 + l4) * 16 + g * 8) : zp;
        qf[qt] = *(const bf16x8*)ap;
    }

    f32x4 Oacc[8];
    float lsum[8];
    #pragma unroll
    for (int qt = 0; qt < 8; qt++) { Oacc[qt] = (f32x4){0.f,0.f,0.f,0.f}; lsum[qt] = 0.f; }

    const float cexp = 0.25f * 1.44269504088896f;   // scale * log2(e)

    for (int kt = 0; kt < 16; kt++) {               // 32 keys per iteration
        const bf16* k0p = (g < 2) ? (Ks + (kt * 32 + p0)     * 16 + g * 8) : zp;
        const bf16* k1p = (g < 2) ? (Ks + (kt * 32 + p0 + 4) * 16 + g * 8) : zp;
        bf16x8 kf0 = *(const bf16x8*)k0p;
        bf16x8 kf1 = *(const bf16x8*)k1p;
        bf16x8 vf  = *(const bf16x8*)(Vt + l4 * 520 + kt * 32 + g * 8);

        #pragma unroll
        for (int qt = 0; qt < 8; qt++) {
            f32x4 z = (f32x4){0.f,0.f,0.f,0.f};
            f32x4 s0 = MFMA16(kf0, qf[qt], z);
            f32x4 s1 = MFMA16(kf1, qf[qt], z);
            float e[8];
            #pragma unroll
            for (int r = 0; r < 4; r++) {
                e[r]     = exp2f(s0[r] * cexp);
                e[4 + r] = exp2f(s1[r] * cexp);
            }
            lsum[qt] += ((e[0]+e[1])+(e[2]+e[3])) + ((e[4]+e[5])+(e[6]+e[7]));
            bf16x8 pf;
            #pragma unroll
            for (int i = 0; i < 8; i++) pf[i] = f2bs(e[i]);
            Oacc[qt] = MFMA16(pf, vf, Oacc[qt]);
        }
    }

    #pragma unroll
    for (int qt = 0; qt < 8; qt++) {
        float ls = lsum[qt];
        ls += __shfl_xor(ls, 16);
        ls += __shfl_xor(ls, 32);
        #pragma unroll
        for (int r = 0; r < 4; r++) {
            float lq = __shfl(ls, g * 4 + r);
            float o = Oacc[qt][r] / lq;
            int qrow = t * 512 + qbase + qt * 16 + g * 4 + r;
            C[(size_t)qrow * 128 + h * 16 + l4] = __float2bfloat16(o);
        }
    }
}

// ---------------------------------------------------------------------------
// FUSED stage-3 per-n kernel: banded attention (window j in [i-7,i]) +
// out_proj MFMA + bias + residual + LayerNorm. One block per n (512 blocks),
// 256 threads. Context tile [32 tok][128] kept in swizzled LDS (ffn's
// (row&7)<<4 XOR pattern, verified); W_o fragments read from L2-hot global.
// In-place Y==R is safe: each element's residual read precedes its own write
// in the same thread and no other block touches these rows.
// ---------------------------------------------------------------------------
__global__ __launch_bounds__(256) void attn_banded_oln(
    const bf16* __restrict__ Qkv,    // [TOK,384] (q at 0, k at +128)
    const bf16* __restrict__ Vb,     // [TOK,128]
    const bf16* __restrict__ Wo,     // [128,128]
    const float* __restrict__ ob,    // [128]
    const bf16* __restrict__ R,      // residual [TOK,128]
    const float* __restrict__ lng, const float* __restrict__ lnb,
    bf16* __restrict__ Y)            // [TOK,128] (may alias R)
{
    __shared__ float Qs[TT][129];
    __shared__ float Ksh[TT][129];
    __shared__ float Vs[TT][129];
    __shared__ bf16 Ctx[32 * 128];   // swizzled
    __shared__ float rsum[32][2];
    __shared__ float rsq[32][2];

    const int n = blockIdx.x;
    const int tid = threadIdx.x;

    for (int e = tid; e < TT * DD; e += 256) {
        int t = e >> 7, d = e & 127;
        const bf16* row = Qkv + (size_t)(t * NN + n) * 384;
        Qs[t][d]  = __bfloat162float(row[d]);
        Ksh[t][d] = __bfloat162float(row[128 + d]);
        Vs[t][d]  = __bfloat162float(Vb[(size_t)(t * NN + n) * DD + d]);
    }
    __syncthreads();

    // ---- banded attention (8 heads x 32 queries) -> Ctx LDS ----
    {
        const int h = tid >> 5, i = tid & 31;
        const int hb = h * DH;

        float s[WND_];
        #pragma unroll
        for (int kk = 0; kk < WND_; kk++) {
            int j = i - (WND_ - 1) + kk;
            int jc = j < 0 ? 0 : j;
            float d = 0.f;
            #pragma unroll
            for (int f = 0; f < DH; f++) d += Qs[i][hb + f] * Ksh[jc][hb + f];
            s[kk] = (j >= 0) ? d * 0.25f : -1e30f;
        }
        float m = s[0];
        #pragma unroll
        for (int kk = 1; kk < WND_; kk++) m = fmaxf(m, s[kk]);
        float l = 0.f, p[WND_];
        #pragma unroll
        for (int kk = 0; kk < WND_; kk++) { p[kk] = __expf(s[kk] - m); l += p[kk]; }
        float inv = 1.f / l;
        float acc[DH] = {};
        #pragma unroll
        for (int kk = 0; kk < WND_; kk++) {
            int j = i - (WND_ - 1) + kk;
            int jc = j < 0 ? 0 : j;
            float pw = p[kk] * inv;
            #pragma unroll
            for (int f = 0; f < DH; f++) acc[f] += pw * Vs[jc][hb + f];
        }
        union { unsigned short s16[16]; uint4 u[2]; } pk;
        #pragma unroll
        for (int f = 0; f < DH; f++) pk.s16[f] = (unsigned short)f2bs(acc[f]);
        const int base = i * 256 + hb * 2;         // byte offset, 32B aligned
        const int sx = (i & 7) << 4;
        *(uint4*)((char*)Ctx + ((base)      ^ sx)) = pk.u[0];
        *(uint4*)((char*)Ctx + ((base + 16) ^ sx)) = pk.u[1];
    }
    __syncthreads();

    // ---- out_proj: [32,128] @ Wo[128,128]^T, 4 waves 2x2 (16 rows x 64 cols) ----
    const int lane = tid & 63;
    const int wv   = tid >> 6;
    const int wm = wv >> 1, wn = wv & 1;
    const int l4 = lane & 15, g = lane >> 4;

    f32x4 acc2[4];
    #pragma unroll
    for (int n2 = 0; n2 < 4; n2++) acc2[n2] = (f32x4){0.f, 0.f, 0.f, 0.f};

    const int arow = wm * 16 + l4;
    const int axor = (arow & 7) << 4;
    #pragma unroll
    for (int ks = 0; ks < 4; ks++) {
        bf16x8 a = *(const bf16x8*)((const char*)Ctx + ((arow * 256 + ks * 64 + g * 16) ^ axor));
        #pragma unroll
        for (int n2 = 0; n2 < 4; n2++) {
            const int col = wn * 64 + n2 * 16 + l4;
            bf16x8 w = *(const bf16x8*)(Wo + (size_t)col * 128 + ks * 32 + g * 8);
            acc2[n2] = MFMA16(a, w, acc2[n2]);
        }
    }

    // ---- bias + residual + LN epilogue (rows = local tokens 0..31) ----
    float vv[4][4];
    #pragma unroll
    for (int n2 = 0; n2 < 4; n2++) {
        const int col = wn * 64 + n2 * 16 + l4;
        const float bv = ob[col];
        #pragma unroll
        for (int r = 0; r < 4; r++) {
            const int tloc = wm * 16 + g * 4 + r;
            vv[n2][r] = acc2[n2][r] + bv
                      + __bfloat162float(R[(size_t)(tloc * NN + n) * 128 + col]);
        }
    }

    #pragma unroll
    for (int r = 0; r < 4; r++) {
        float sm = 0.f, qs = 0.f;
        #pragma unroll
        for (int n2 = 0; n2 < 4; n2++) { float v = vv[n2][r]; sm += v; qs += v * v; }
        #pragma unroll
        for (int off = 1; off < 16; off <<= 1) {
            sm += __shfl_xor(sm, off);
            qs += __shfl_xor(qs, off);
        }
        const int tloc = wm * 16 + g * 4 + r;
        if (l4 == 0) { rsum[tloc][wn] = sm; rsq[tloc][wn] = qs; }
    }
    __syncthreads();

    #pragma unroll
    for (int r = 0; r < 4; r++) {
        const int tloc = wm * 16 + g * 4 + r;
        const float S = rsum[tloc][0] + rsum[tloc][1];
        const float Q = rsq[tloc][0] + rsq[tloc][1];
        const float mean = S * (1.0f / 128.0f);
        const float var  = Q * (1.0f / 128.0f) - mean * mean;
        const float rstd = rsqrtf(var + 1e-5f);
        #pragma unroll
        for (int n2 = 0; n2 < 4; n2++) {
            const int col = wn * 64 + n2 * 16 + l4;
            const float y = (vv[n2][r] - mean) * rstd * lng[col] + lnb[col];
            Y[(size_t)(tloc * NN + n) * 128 + col] = __float2bfloat16(y);
        }
    }
}

// ---------------------------------------------------------------------------
// time2vec add: Y = bf16(x + tbl[t, d])
// ---------------------------------------------------------------------------
__global__ __launch_bounds__(256) void t2v_add_kernel(
    const float* __restrict__ x, const float* __restrict__ tbl, bf16* __restrict__ Y)
{
    int i = blockIdx.x * 256 + threadIdx.x;     // float4 groups
    int e = i * 4;
    float4 xv = ((const float4*)x)[i];
    int ti = ((e >> 16) << 7) | (e & 127);
    float4 tv = *(const float4*)(tbl + ti);
    ushort4 o;
    o.x = (unsigned short)f2bs(xv.x + tv.x);
    o.y = (unsigned short)f2bs(xv.y + tv.y);
    o.z = (unsigned short)f2bs(xv.z + tv.z);
    o.w = (unsigned short)f2bs(xv.w + tv.w);
    *(ushort4*)((unsigned short*)Y + e) = o;
}

// ---------------------------------------------------------------------------

extern "C" void kernel_launch(void* const* d_in, const int* in_sizes, int n_in,
                              void* d_out, int out_size, void* d_ws, size_t ws_size,
                              hipStream_t stream) {
    const float* x           = (const float*)d_in[0];
    const float* enc_in_w    = (const float*)d_in[1];
    const float* enc_in_b    = (const float*)d_in[2];
    const float* enc_out_w   = (const float*)d_in[3];
    const float* enc_out_b   = (const float*)d_in[4];
    const float* enc_l1w     = (const float*)d_in[5];
    const float* enc_l1b     = (const float*)d_in[6];
    const float* enc_l2w     = (const float*)d_in[7];
    const float* enc_l2b     = (const float*)d_in[8];
    const float* enc_ln1w    = (const float*)d_in[9];
    const float* enc_ln1b    = (const float*)d_in[10];
    const float* enc_ln2w    = (const float*)d_in[11];
    const float* enc_ln2b    = (const float*)d_in[12];
    const float* qk_in_w     = (const float*)d_in[13];
    const float* qk_in_b     = (const float*)d_in[14];
    const float* qk_out_w    = (const float*)d_in[15];
    const float* qk_out_b    = (const float*)d_in[16];
    const float* qk_l1w      = (const float*)d_in[17];
    const float* qk_l1b      = (const float*)d_in[18];
    const float* qk_l2w      = (const float*)d_in[19];
    const float* qk_l2b      = (const float*)d_in[20];
    const float* qk_ln1w     = (const float*)d_in[21];
    const float* qk_ln1b     = (const float*)d_in[22];
    const float* qk_ln2w     = (const float*)d_in[23];
    const float* qk_ln2b     = (const float*)d_in[24];
    const float* t2v_w       = (const float*)d_in[25];
    const float* t2v_b       = (const float*)d_in[26];
    const float* t2v_w0      = (const float*)d_in[27];
    const float* t2v_b0      = (const float*)d_in[28];
    const float* out_w       = (const float*)d_in[29];
    float* out = (float*)d_out;

    // ---------------- workspace layout (bytes) ------------------------------
    char* ws = (char*)d_ws;
    const size_t TOKD = (size_t)TOK * DD;
    size_t off = 0;
    auto alloc = [&](size_t bytes) { char* p = ws + off; off += (bytes + 255) & ~(size_t)255; return p; };

    bf16*  Qb   = (bf16*)alloc((size_t)TOK * 384 * 2);   // qkv bf16
    bf16*  Vb   = (bf16*)alloc(TOKD * 2);                // v-projection bf16
    bf16*  xb   = (bf16*)alloc(TOKD * 2);                // bf16 copy of x
    bf16*  bufA = (bf16*)alloc(TOKD * 2);                // residual stream bf16
    bf16*  Zb   = (bf16*)alloc(TOKD * 2);                // outs_zs bf16
    bf16*  Cb   = (bf16*)alloc(TOKD * 2);                // attn context bf16 (stage 1)
    float* t2vt = (float*)alloc((size_t)TT * DD * 4);    // time2vec table
    bf16* enc_in_wb  = (bf16*)alloc(384 * DD * 2);
    bf16* enc_out_wb = (bf16*)alloc(DD * DD * 2);
    bf16* enc_l1wb   = (bf16*)alloc((size_t)FF_ * DD * 2);
    bf16* enc_l2wb   = (bf16*)alloc((size_t)DD * FF_ * 2);
    bf16* qk_in_wb   = (bf16*)alloc((size_t)LL * 384 * DD * 2);
    bf16* qk_out_wb  = (bf16*)alloc((size_t)LL * DD * DD * 2);
    bf16* qk_l1wb    = (bf16*)alloc((size_t)LL * FF_ * DD * 2);
    bf16* qk_l2wb    = (bf16*)alloc((size_t)LL * DD * FF_ * 2);

    // ---------------- one-shot conversion of all weights + x + t2v table ----
    ConvDesc cd;
    cd.x  = x;        cd.dx = xb;
    cd.s1 = enc_in_w; cd.d1 = enc_in_wb;
    cd.s2 = enc_out_w;cd.d2 = enc_out_wb;
    cd.s3 = enc_l1w;  cd.d3 = enc_l1wb;
    cd.s4 = enc_l2w;  cd.d4 = enc_l2wb;
    cd.s5 = qk_in_w;  cd.d5 = qk_in_wb;
    cd.s6 = qk_out_w; cd.d6 = qk_out_wb;
    cd.s7 = qk_l1w;   cd.d7 = qk_l1wb;
    cd.s8 = qk_l2w;   cd.d8 = qk_l2wb;
    cd.w = t2v_w; cd.b = t2v_b; cd.w0 = t2v_w0; cd.b0 = t2v_b0; cd.tbl = t2vt;
    conv_all_kernel<<<(CP9 + 255) / 256, 256, 0, stream>>>(cd);

    auto gemm128 = [&](const bf16* A, int lda, const bf16* W, const float* bias,
                       bf16* C, int ldc, int M, int N, int K, int relu) {
        dim3 grid(N / 128, M / 128);
        mfma_gemm<128, 128><<<grid, 256, 0, stream>>>(A, lda, W, bias, C, ldc, K, relu);
    };
    auto gemm_ln = [&](const bf16* A, int lda, const bf16* W, const float* bias,
                       const bf16* R, const float* lng, const float* lnb,
                       bf16* Y, int M, int K) {
        mfma_gemm_ln<<<M / 64, 256, 0, stream>>>(A, lda, W, bias, R, lng, lnb, Y, K);
    };

    // ---------------- stage 1: plain encoder (attend over N, batch T) -------
    gemm128(xb, DD, enc_in_wb, enc_in_b, Qb, 384, TOK, 384, DD, 0);
    attn_full_mfma<<<TT * HH, 256, 0, stream>>>(Qb, Cb);
    gemm_ln(Cb, DD, enc_out_wb, enc_out_b, xb, enc_ln1w, enc_ln1b, bufA, TOK, DD);
    ffn_fused<false><<<TOK / 64, 512, 0, stream>>>(
        bufA, enc_l1wb, enc_l1b, enc_l2wb, enc_l2b,
        enc_ln2w, enc_ln2b, Zb, nullptr, nullptr);

    // ---------------- stage 2: time2vec -------------------------------------
    t2v_add_kernel<<<(TOK * DD / 4) / 256, 256, 0, stream>>>(x, t2vt, bufA);

    // ---------------- stage 3: qk encoder stack (banded window attn) ---------
    for (int l = 0; l < LL; l++) {
        const bf16* iw   = qk_in_wb  + (size_t)l * 384 * DD;
        const float* ib  = qk_in_b   + (size_t)l * 384;
        const bf16* owt  = qk_out_wb + (size_t)l * DD * DD;
        const float* ob  = qk_out_b  + (size_t)l * DD;
        const bf16* l1w  = qk_l1wb   + (size_t)l * FF_ * DD;
        const float* l1b = qk_l1b    + (size_t)l * FF_;
        const bf16* l2w  = qk_l2wb   + (size_t)l * DD * FF_;
        const float* l2b = qk_l2b    + (size_t)l * DD;

        // merged q,k (from bufA) + v (from Zb) projection: one dispatch
        qkv_proj<<<dim3(3, TOK / 128), 256, 0, stream>>>(bufA, Zb, iw, ib, Qb, Vb);
        // fused banded attn + out_proj + residual + LN (in-place on bufA)
        attn_banded_oln<<<NN, 256, 0, stream>>>(Qb, Vb, owt, ob, bufA,
                                                qk_ln1w + l * DD, qk_ln1b + l * DD, bufA);
        if (l == LL - 1) {
            ffn_fused<true><<<TOK / 64, 512, 0, stream>>>(
                bufA, l1w, l1b, l2w, l2b,
                qk_ln2w + l * DD, qk_ln2b + l * DD, nullptr, out_w, out);
        } else {
            ffn_fused<false><<<TOK / 64, 512, 0, stream>>>(
                bufA, l1w, l1b, l2w, l2b,
                qk_ln2w + l * DD, qk_ln2b + l * DD, bufA, nullptr, nullptr);
        }
    }
}

// Round 12
// 212.039 us; speedup vs baseline: 1.6462x; 1.0139x over previous
//
#include <hip/hip_runtime.h>
#include <hip/hip_bf16.h>
#include <math.h>

// Problem constants
#define TT 32
#define NN 512
#define DD 128
#define FF_ 2048
#define HH 8
#define LL 2
#define WND_ 8
#define TOK (TT*NN)          // 16384 tokens
#define DH 16                // head dim

typedef __hip_bfloat16 bf16;
typedef __attribute__((ext_vector_type(8))) short bf16x8;   // 8 bf16 (4 VGPRs)
typedef __attribute__((ext_vector_type(4))) float f32x4;    // 4 fp32

// global_load_lds: 16B per lane, LDS dest = wave-uniform base + lane*16 (linear)
#define GLD_LDS16(gp, lp) __builtin_amdgcn_global_load_lds( \
    (const __attribute__((address_space(1))) unsigned int*)(gp), \
    (__attribute__((address_space(3))) unsigned int*)(lp), 16, 0, 0)

#define MFMA16(a, b, c) __builtin_amdgcn_mfma_f32_16x16x32_bf16((a), (b), (c), 0, 0, 0)

__device__ inline short f2bs(float f) {
    __hip_bfloat16 h = __float2bfloat16(f);
    return *reinterpret_cast<short*>(&h);
}

// ---------------------------------------------------------------------------
// bf16 MFMA GEMM: C[M,N] = A[M,K] @ W[N,K]^T + bias (+relu). Output bf16.
// Tile BM x BN, BK=32, 256 threads = 4 waves in 2x2.
// ---------------------------------------------------------------------------
template<int BM, int BN>
__global__ __launch_bounds__(256) void mfma_gemm(
    const bf16* __restrict__ A, int lda,
    const bf16* __restrict__ W,              // [N,K] row-major (= B^T)
    const float* __restrict__ bias,          // [N]
    bf16* __restrict__ C, int ldc,
    int K, int relu)
{
    constexpr int WM = BM / 2, WN = BN / 2;
    constexpr int FM = WM / 16, FN = WN / 16;
    constexpr int LA = (BM * 64) / (256 * 16);
    constexpr int LB = (BN * 64) / (256 * 16);

    __shared__ bf16 As[BM * 32];
    __shared__ bf16 Bs[BN * 32];

    const int tid  = threadIdx.x;
    const int lane = tid & 63;
    const int wave = tid >> 6;
    const int wm = wave >> 1, wn = wave & 1;
    const int bm = blockIdx.y * BM, bn = blockIdx.x * BN;

    f32x4 acc[FM][FN];
    #pragma unroll
    for (int m = 0; m < FM; m++)
        #pragma unroll
        for (int n = 0; n < FN; n++)
            acc[m][n] = (f32x4){0.f, 0.f, 0.f, 0.f};

    for (int k0 = 0; k0 < K; k0 += 32) {
        #pragma unroll
        for (int i = 0; i < LA; i++) {
            const int o = (tid + i * 256) * 16;
            const int row = o >> 6;
            const int ce  = (o & 63) >> 1;
            GLD_LDS16(A + (size_t)(bm + row) * lda + k0 + ce, (char*)As + o);
        }
        #pragma unroll
        for (int i = 0; i < LB; i++) {
            const int o = (tid + i * 256) * 16;
            const int row = o >> 6;
            const int ce  = (o & 63) >> 1;
            GLD_LDS16(W + (size_t)(bn + row) * K + k0 + ce, (char*)Bs + o);
        }
        __syncthreads();

        bf16x8 af[FM], bfr[FN];
        #pragma unroll
        for (int m = 0; m < FM; m++)
            af[m] = *(const bf16x8*)(As + (wm * WM + m * 16 + (lane & 15)) * 32 + (lane >> 4) * 8);
        #pragma unroll
        for (int n = 0; n < FN; n++)
            bfr[n] = *(const bf16x8*)(Bs + (wn * WN + n * 16 + (lane & 15)) * 32 + (lane >> 4) * 8);
        #pragma unroll
        for (int m = 0; m < FM; m++)
            #pragma unroll
            for (int n = 0; n < FN; n++)
                acc[m][n] = MFMA16(af[m], bfr[n], acc[m][n]);
        __syncthreads();
    }

    // C/D layout: col = lane&15, row = (lane>>4)*4 + reg
    #pragma unroll
    for (int n = 0; n < FN; n++) {
        const int col = bn + wn * WN + n * 16 + (lane & 15);
        const float bv = bias[col];
        #pragma unroll
        for (int m = 0; m < FM; m++) {
            #pragma unroll
            for (int r = 0; r < 4; r++) {
                const int row = bm + wm * WM + m * 16 + (lane >> 4) * 4 + r;
                float v = acc[m][n][r] + bv;
                if (relu) v = fmaxf(v, 0.f);
                C[(size_t)row * ldc + col] = __float2bfloat16(v);
            }
        }
    }
}

// ---------------------------------------------------------------------------
// Merged stage-3 projection: grid (3, TOK/128). Column tiles 0,1 compute q,k
// from A1 (bufA) -> Qb [TOK,384] cols 0..255; tile 2 computes v from A2 (Zb)
// -> Vb [TOK,128]. Same body as mfma_gemm<128,128>, K=128.
// ---------------------------------------------------------------------------
__global__ __launch_bounds__(256) void qkv_proj(
    const bf16* __restrict__ A1, const bf16* __restrict__ A2,
    const bf16* __restrict__ W,              // [384,128]
    const float* __restrict__ bias,          // [384]
    bf16* __restrict__ Qb, bf16* __restrict__ Vb)
{
    constexpr int BM = 128, WM = 64, WN = 64, FM = 4, FN = 4;

    __shared__ bf16 As[BM * 32];
    __shared__ bf16 Bs[128 * 32];

    const int tid  = threadIdx.x;
    const int lane = tid & 63;
    const int wave = tid >> 6;
    const int wm = wave >> 1, wn = wave & 1;
    const int bnb = blockIdx.x;              // 0,1 = q,k ; 2 = v
    const int bm  = blockIdx.y * BM;

    const bf16* A  = (bnb == 2) ? A2 : A1;
    const bf16* Wb = W + (size_t)bnb * 128 * 128;

    f32x4 acc[FM][FN];
    #pragma unroll
    for (int m = 0; m < FM; m++)
        #pragma unroll
        for (int n = 0; n < FN; n++)
            acc[m][n] = (f32x4){0.f, 0.f, 0.f, 0.f};

    for (int k0 = 0; k0 < 128; k0 += 32) {
        #pragma unroll
        for (int i = 0; i < 2; i++) {
            const int o = (tid + i * 256) * 16;
            const int row = o >> 6;
            const int ce  = (o & 63) >> 1;
            GLD_LDS16(A + (size_t)(bm + row) * 128 + k0 + ce, (char*)As + o);
        }
        #pragma unroll
        for (int i = 0; i < 2; i++) {
            const int o = (tid + i * 256) * 16;
            const int row = o >> 6;
            const int ce  = (o & 63) >> 1;
            GLD_LDS16(Wb + (size_t)row * 128 + k0 + ce, (char*)Bs + o);
        }
        __syncthreads();

        bf16x8 af[FM], bfr[FN];
        #pragma unroll
        for (int m = 0; m < FM; m++)
            af[m] = *(const bf16x8*)(As + (wm * WM + m * 16 + (lane & 15)) * 32 + (lane >> 4) * 8);
        #pragma unroll
        for (int n = 0; n < FN; n++)
            bfr[n] = *(const bf16x8*)(Bs + (wn * WN + n * 16 + (lane & 15)) * 32 + (lane >> 4) * 8);
        #pragma unroll
        for (int m = 0; m < FM; m++)
            #pragma unroll
            for (int n = 0; n < FN; n++)
                acc[m][n] = MFMA16(af[m], bfr[n], acc[m][n]);
        __syncthreads();
    }

    #pragma unroll
    for (int n = 0; n < FN; n++) {
        const int cl = wn * WN + n * 16 + (lane & 15);     // local col 0..127
        const float bv = bias[bnb * 128 + cl];
        #pragma unroll
        for (int m = 0; m < FM; m++) {
            #pragma unroll
            for (int r = 0; r < 4; r++) {
                const int row = bm + wm * WM + m * 16 + (lane >> 4) * 4 + r;
                const float v = acc[m][n][r] + bv;
                if (bnb == 2) Vb[(size_t)row * 128 + cl] = __float2bfloat16(v);
                else          Qb[(size_t)row * 384 + bnb * 128 + cl] = __float2bfloat16(v);
            }
        }
    }
}

// ---------------------------------------------------------------------------
// Fused GEMM + bias + residual + LayerNorm (stage-1 out_proj path, K=128).
// BM=64, BN=128 (full LN row). 256 threads, waves 2x2, each wave 32x64.
// ---------------------------------------------------------------------------
__global__ __launch_bounds__(256) void mfma_gemm_ln(
    const bf16* __restrict__ A, int lda,
    const bf16* __restrict__ W,              // [128,K]
    const float* __restrict__ bias,          // [128]
    const bf16* __restrict__ R,              // residual [M,128] bf16
    const float* __restrict__ lng, const float* __restrict__ lnb,
    bf16* __restrict__ Y,                    // [M,128] bf16
    int K)
{
    constexpr int BM = 64, WM = 32, WN = 64, FM = 2, FN = 4;

    __shared__ bf16 As[BM * 32];
    __shared__ bf16 Bs[128 * 32];
    __shared__ float rsum[BM][2];
    __shared__ float rsq[BM][2];

    const int tid  = threadIdx.x;
    const int lane = tid & 63;
    const int wave = tid >> 6;
    const int wm = wave >> 1, wn = wave & 1;
    const int bm = blockIdx.x * BM;

    f32x4 acc[FM][FN];
    #pragma unroll
    for (int m = 0; m < FM; m++)
        #pragma unroll
        for (int n = 0; n < FN; n++)
            acc[m][n] = (f32x4){0.f, 0.f, 0.f, 0.f};

    for (int k0 = 0; k0 < K; k0 += 32) {
        {   // A tile: 64 rows x 32 cols
            const int o = tid * 16;
            const int row = o >> 6;
            const int ce  = (o & 63) >> 1;
            GLD_LDS16(A + (size_t)(bm + row) * lda + k0 + ce, (char*)As + o);
        }
        #pragma unroll
        for (int i = 0; i < 2; i++) {       // B tile: 128 rows
            const int o = (tid + i * 256) * 16;
            const int row = o >> 6;
            const int ce  = (o & 63) >> 1;
            GLD_LDS16(W + (size_t)row * K + k0 + ce, (char*)Bs + o);
        }
        __syncthreads();

        bf16x8 af[FM], bfr[FN];
        #pragma unroll
        for (int m = 0; m < FM; m++)
            af[m] = *(const bf16x8*)(As + (wm * WM + m * 16 + (lane & 15)) * 32 + (lane >> 4) * 8);
        #pragma unroll
        for (int n = 0; n < FN; n++)
            bfr[n] = *(const bf16x8*)(Bs + (wn * WN + n * 16 + (lane & 15)) * 32 + (lane >> 4) * 8);
        #pragma unroll
        for (int m = 0; m < FM; m++)
            #pragma unroll
            for (int n = 0; n < FN; n++)
                acc[m][n] = MFMA16(af[m], bfr[n], acc[m][n]);
        __syncthreads();
    }

    // bias + residual
    #pragma unroll
    for (int n = 0; n < FN; n++) {
        const int col = wn * WN + n * 16 + (lane & 15);
        const float bv = bias[col];
        #pragma unroll
        for (int m = 0; m < FM; m++) {
            #pragma unroll
            for (int r = 0; r < 4; r++) {
                const int rl = wm * WM + m * 16 + (lane >> 4) * 4 + r;
                acc[m][n][r] += bv + __bfloat162float(R[(size_t)(bm + rl) * 128 + col]);
            }
        }
    }

    // row sums
    #pragma unroll
    for (int m = 0; m < FM; m++) {
        #pragma unroll
        for (int r = 0; r < 4; r++) {
            float s = 0.f, q = 0.f;
            #pragma unroll
            for (int n = 0; n < FN; n++) { float v = acc[m][n][r]; s += v; q += v * v; }
            #pragma unroll
            for (int off = 1; off < 16; off <<= 1) {
                s += __shfl_xor(s, off);
                q += __shfl_xor(q, off);
            }
            const int rl = wm * WM + m * 16 + (lane >> 4) * 4 + r;
            if ((lane & 15) == 0) { rsum[rl][wn] = s; rsq[rl][wn] = q; }
        }
    }
    __syncthreads();

    #pragma unroll
    for (int m = 0; m < FM; m++) {
        #pragma unroll
        for (int r = 0; r < 4; r++) {
            const int rl = wm * WM + m * 16 + (lane >> 4) * 4 + r;
            const float S = rsum[rl][0] + rsum[rl][1];
            const float Q = rsq[rl][0] + rsq[rl][1];
            const float mean = S * (1.0f / 128.0f);
            const float var  = Q * (1.0f / 128.0f) - mean * mean;
            const float rstd = rsqrtf(var + 1e-5f);
            #pragma unroll
            for (int n = 0; n < FN; n++) {
                const int col = wn * WN + n * 16 + (lane & 15);
                const float y = (acc[m][n][r] - mean) * rstd * lng[col] + lnb[col];
                Y[(size_t)(bm + rl) * 128 + col] = __float2bfloat16(y);
            }
        }
    }
}

// ---------------------------------------------------------------------------
// FFN v6: Y = LN( A + (relu(A@W1^T+b1) @ W2^T + b2) ) [* head]
// Grid 256 x 1024 threads. Block = 64 tokens; 16 waves = 4 token-tiles (tg,
// 16 tokens each) x 4 hidden-quarters (hq, 512 cols each).
// v6 vs v5: 16 waves (4/SIMD, was 2/SIMD at grid=256=1 block/CU) -> 2x the
// latency hiding for the barrier+vmcnt+dep-chain exposure that dominated
// (6000 cyc/iter vs ~1700 floor). Each wave owns ONE token sub-tile:
// phase1 8 MFMAs (sa0/sa1), pack 1 pf, phase2 8 MFMAs. W-fragment LDS reads
// are now shared by 4 tg-waves (2x more traffic than v5, still under the
// latency bound). All v5 swizzles carried verbatim (pi-permuted W1, W1
// source-XOR, W2 row-pair-XOR); staging split across threads via tid&511
// (4 x 16B loads/thread/iter). 3 hq-partials per tg reduced via 96 KB Red
// aliased onto dead staging buffers.
// ---------------------------------------------------------------------------
template<bool HEAD>
__global__ __launch_bounds__(1024) void ffn_fused(
    const bf16* __restrict__ A,              // [M,128]  input = residual
    const bf16* __restrict__ W1, const float* __restrict__ b1,   // [2048,128],[2048]
    const bf16* __restrict__ W2, const float* __restrict__ b2,   // [128,2048],[128]
    const float* __restrict__ lng, const float* __restrict__ lnb,
    bf16* __restrict__ Y,                    // [M,128] (unused if HEAD)
    const float* __restrict__ hw, float* __restrict__ hout)
{
    __shared__ char smem[131072];
    // W1s[d][hx] = smem + d*32768 + hx*8192           (64 KB)
    // W2s[d][hx] = smem + 65536 + d*32768 + hx*8192   (64 KB)
    // Red (post-loop alias): smem + tg*24576 + (hq-1)*8192 + ot*1024 + lane*16

    const int tid  = threadIdx.x;
    const int lane = tid & 63;
    const int wv   = tid >> 6;               // 0..15
    const int tg   = wv & 3;                 // token tile (16 tokens)
    const int hq   = wv >> 2;                // hidden quarter (512 cols)
    const int l4   = lane & 15;
    const int g    = lane >> 4;
    const int bm   = blockIdx.x * 64;

    // token B-fragments (lane&15 = token col, k = j*32 + g*8)
    bf16x8 tf[4];
    #pragma unroll
    for (int j = 0; j < 4; j++)
        tf[j] = *(const bf16x8*)(A + (size_t)(bm + tg * 16 + l4) * 128 + j * 32 + g * 8);

    // staging geometry: 1024 threads cover 4 hx regions; thread handles 2 hx
    const int tid9 = tid & 511;
    const int hbase = (tid >> 9) * 2;                             // 0 or 2
    const int q    = tid9 >> 4;                                   // W1 row slot 0..31
    const int qq   = q & 15;
    const int piq  = (((qq >> 2) << 3) | (qq & 3)) + ((q >> 4) << 2);  // pi(q)
    const int w1cb = ((tid9 & 15) * 16) ^ ((q & 7) << 4);         // swizzled source byte
    const int w2row = tid9 >> 2;                                  // 0..127
    const int w2ce  = ((tid9 & 3) ^ ((w2row >> 1) & 3)) * 8;      // row-pair XOR source col

    auto STAGE = [&](int d, int s) {
        #pragma unroll
        for (int hx2 = 0; hx2 < 2; hx2++) {
            const int hx = hbase + hx2;
            const int c0 = hx * 512 + s * 32;
            GLD_LDS16((const char*)W1 + (size_t)(c0 + piq) * 256 + w1cb,
                      smem + d * 32768 + hx * 8192 + tid9 * 16);
            GLD_LDS16(W2 + (size_t)w2row * 2048 + c0 + w2ce,
                      smem + 65536 + d * 32768 + hx * 8192 + tid9 * 16);
        }
    };

    f32x4 Oacc[8];
    #pragma unroll
    for (int ot = 0; ot < 8; ot++) Oacc[ot] = (f32x4){0.f, 0.f, 0.f, 0.f};

    const f32x4 zz = (f32x4){0.f, 0.f, 0.f, 0.f};
    const int xsw = (l4 & 7) << 4;
    const int w2rsw = (l4 >> 1) & 3;         // read-side W2 swizzle term

    STAGE(0, 0);
    for (int s = 0; s < 16; s++) {
        __syncthreads();                     // drains staged loads for buf s&1
        if (s < 15) STAGE((s + 1) & 1, s + 1);   // async, flies during compute
        const int d  = s & 1;
        const int c0 = hq * 512 + s * 32;
        const char* w1b = smem + d * 32768 + hq * 8192;
        const char* w2b = smem + 65536 + d * 32768 + hq * 8192;

        // phase 1: H^T for 32 hidden cols (rows pi-permuted in LDS)
        f32x4 sa0 = zz, sa1 = zz;
        #pragma unroll
        for (int j = 0; j < 4; j++) {
            const int xo = (j * 64 + g * 16) ^ xsw;
            bf16x8 w10 = *(const bf16x8*)(w1b + l4 * 256 + xo);
            bf16x8 w11 = *(const bf16x8*)(w1b + (16 + l4) * 256 + xo);
            sa0 = MFMA16(w10, tf[j], sa0);
            sa1 = MFMA16(w11, tf[j], sa1);
        }
        // bias + relu + pack: lane holds hidden cols c0 + 8g + {0..7}
        float4 bv0 = *(const float4*)(b1 + c0 + g * 8);
        float4 bv1 = *(const float4*)(b1 + c0 + g * 8 + 4);
        bf16x8 pf;
        pf[0] = f2bs(fmaxf(sa0[0] + bv0.x, 0.f));
        pf[1] = f2bs(fmaxf(sa0[1] + bv0.y, 0.f));
        pf[2] = f2bs(fmaxf(sa0[2] + bv0.z, 0.f));
        pf[3] = f2bs(fmaxf(sa0[3] + bv0.w, 0.f));
        pf[4] = f2bs(fmaxf(sa1[0] + bv1.x, 0.f));
        pf[5] = f2bs(fmaxf(sa1[1] + bv1.y, 0.f));
        pf[6] = f2bs(fmaxf(sa1[2] + bv1.z, 0.f));
        pf[7] = f2bs(fmaxf(sa1[3] + bv1.w, 0.f));

        // phase 2: accumulate all 128 output cols over this k-window
        #pragma unroll
        for (int ot = 0; ot < 8; ot++) {
            bf16x8 w2f = *(const bf16x8*)(w2b + (ot * 16 + l4) * 64 + ((g ^ w2rsw) << 4));
            Oacc[ot] = MFMA16(pf, w2f, Oacc[ot]);
        }
    }

    // ---- reduce hidden quarters (Red aliases dead staging space) ----
    __syncthreads();
    if (hq != 0) {
        #pragma unroll
        for (int ot = 0; ot < 8; ot++)
            *(f32x4*)(smem + tg * 24576 + (hq - 1) * 8192 + ot * 1024 + lane * 16) = Oacc[ot];
    }
    __syncthreads();
    if (hq == 0) {
        #pragma unroll
        for (int p = 0; p < 3; p++)
            #pragma unroll
            for (int ot = 0; ot < 8; ot++) {
                f32x4 o2 = *(const f32x4*)(smem + tg * 24576 + p * 8192 + ot * 1024 + lane * 16);
                Oacc[ot][0] += o2[0]; Oacc[ot][1] += o2[1];
                Oacc[ot][2] += o2[2]; Oacc[ot][3] += o2[3];
            }

        // bias + residual;  lane: col = ot*16 + l4, token = tg*16 + 4g + r
        float vv[8][4];
        #pragma unroll
        for (int ot = 0; ot < 8; ot++) {
            const int col = ot * 16 + l4;
            const float bv = b2[col];
            #pragma unroll
            for (int r = 0; r < 4; r++) {
                const int trow = bm + tg * 16 + 4 * g + r;
                vv[ot][r] = Oacc[ot][r] + bv
                          + __bfloat162float(A[(size_t)trow * 128 + col]);
            }
        }

        // LN row stats: in-lane over ot, shfl over 16-lane col group
        #pragma unroll
        for (int r = 0; r < 4; r++) {
            float sm = 0.f, qs = 0.f;
            #pragma unroll
            for (int ot = 0; ot < 8; ot++) { float v = vv[ot][r]; sm += v; qs += v * v; }
            #pragma unroll
            for (int off = 1; off < 16; off <<= 1) {
                sm += __shfl_xor(sm, off);
                qs += __shfl_xor(qs, off);
            }
            const float mean = sm * (1.0f / 128.0f);
            const float var  = qs * (1.0f / 128.0f) - mean * mean;
            const float rstd = rsqrtf(var + 1e-5f);
            const int trow = bm + tg * 16 + 4 * g + r;
            float hacc = 0.f;
            #pragma unroll
            for (int ot = 0; ot < 8; ot++) {
                const int col = ot * 16 + l4;
                const float y = (vv[ot][r] - mean) * rstd * lng[col] + lnb[col];
                if (HEAD) hacc += y * hw[col];
                else Y[(size_t)trow * 128 + col] = __float2bfloat16(y);
            }
            if (HEAD) {
                #pragma unroll
                for (int off = 1; off < 16; off <<= 1) hacc += __shfl_xor(hacc, off);
                if (l4 == 0) hout[trow] = hacc;
            }
        }
    }
}

// ---------------------------------------------------------------------------
// Merged fp32->bf16 conversion of all weights + x, plus t2v table (segment 9).
// ---------------------------------------------------------------------------
struct ConvDesc {
    const float *x, *s1, *s2, *s3, *s4, *s5, *s6, *s7, *s8;
    bf16 *dx, *d1, *d2, *d3, *d4, *d5, *d6, *d7, *d8;
    const float *w, *b, *w0, *b0;
    float* tbl;
};

__device__ inline void cvt4(const float* s, bf16* d, int j) {
    float4 v = ((const float4*)s)[j];
    ushort4 o;
    o.x = (unsigned short)f2bs(v.x); o.y = (unsigned short)f2bs(v.y);
    o.z = (unsigned short)f2bs(v.z); o.w = (unsigned short)f2bs(v.w);
    *(ushort4*)((unsigned short*)d + j * 4) = o;
}

// prefix sums in float4 units
#define CP0 524288   // x            (2097152)
#define CP1 536576   // enc_in_w     (49152)
#define CP2 540672   // enc_out_w    (16384)
#define CP3 606208   // enc_l1w      (262144)
#define CP4 671744   // enc_l2w      (262144)
#define CP5 696320   // qk_in_w      (98304)
#define CP6 704512   // qk_out_w     (32768)
#define CP7 835584   // qk_l1w       (524288)
#define CP8 966656   // qk_l2w       (524288)
#define CP9 967680   // t2v table    (4096 fp32)

__global__ __launch_bounds__(256) void conv_all_kernel(ConvDesc cd)
{
    int i = blockIdx.x * 256 + threadIdx.x;
    if (i < CP0)      cvt4(cd.x,  cd.dx, i);
    else if (i < CP1) cvt4(cd.s1, cd.d1, i - CP0);
    else if (i < CP2) cvt4(cd.s2, cd.d2, i - CP1);
    else if (i < CP3) cvt4(cd.s3, cd.d3, i - CP2);
    else if (i < CP4) cvt4(cd.s4, cd.d4, i - CP3);
    else if (i < CP5) cvt4(cd.s5, cd.d5, i - CP4);
    else if (i < CP6) cvt4(cd.s6, cd.d6, i - CP5);
    else if (i < CP7) cvt4(cd.s7, cd.d7, i - CP6);
    else if (i < CP8) cvt4(cd.s8, cd.d8, i - CP7);
    else if (i < CP9) {
        int e = (i - CP8) * 4;
        int t = e >> 7;
        float tau = (float)(t + 1);
        float4 o;
        #pragma unroll
        for (int k = 0; k < 4; k++) {
            int d = (e + k) & 127;
            ((float*)&o)[k] = (d < 127) ? sinf(tau * cd.w[d] + cd.b[d])
                                        : (tau * cd.w0[0] + cd.b0[0]);
        }
        *(float4*)(cd.tbl + e) = o;
    }
}

// ---------------------------------------------------------------------------
// Stage-1 attention via MFMA (flash, maxless). One block per (t,h).
// ---------------------------------------------------------------------------
__global__ __launch_bounds__(256) void attn_full_mfma(
    const bf16* __restrict__ Qkv, bf16* __restrict__ C)
{
    __shared__ bf16 Qs[512 * 16];
    __shared__ bf16 Ks[512 * 16];
    __shared__ bf16 Vt[16 * 520];
    __shared__ bf16 Zero[32];          // 64B broadcast zero block

    const int t = blockIdx.x >> 3;
    const int h = blockIdx.x & 7;
    const int tid = threadIdx.x;

    if (tid < 32) ((unsigned short*)Zero)[tid] = 0;

    for (int n = tid; n < 512; n += 256) {
        const unsigned short* row = (const unsigned short*)Qkv + (size_t)(t * 512 + n) * 384 + h * 16;
        uint4 q0 = *(const uint4*)(row);
        uint4 q1 = *(const uint4*)(row + 8);
        uint4 k0 = *(const uint4*)(row + 128);
        uint4 k1 = *(const uint4*)(row + 136);
        uint4 v0 = *(const uint4*)(row + 256);
        uint4 v1 = *(const uint4*)(row + 264);
        *(uint4*)((unsigned short*)Qs + n * 16)     = q0;
        *(uint4*)((unsigned short*)Qs + n * 16 + 8) = q1;
        *(uint4*)((unsigned short*)Ks + n * 16)     = k0;
        *(uint4*)((unsigned short*)Ks + n * 16 + 8) = k1;
        union { uint4 u[2]; unsigned short s[16]; } vb;
        vb.u[0] = v0; vb.u[1] = v1;
        #pragma unroll
        for (int f = 0; f < 16; f++)
            ((unsigned short*)Vt)[f * 520 + n] = vb.s[f];
    }
    __syncthreads();

    const int lane = tid & 63;
    const int wv   = tid >> 6;
    const int l4   = lane & 15;
    const int g    = lane >> 4;
    const int qbase = wv * 128;
    const bf16* zp = Zero + (g & 1) * 8;
    const int p0 = ((l4 >> 2) << 3) | (l4 & 3);      // pi0 key permutation

    bf16x8 qf[8];
    #pragma unroll
    for (int qt = 0; qt < 8; qt++) {
        const bf16* ap = (g < 2) ? (Qs + (qbase + qt * 16 + l4) * 16 + g * 8) : zp;
        qf[qt] = *(const bf16x8*)ap;
    }

    f32x4 Oacc[8];
    float lsum[8];
    #pragma unroll
    for (int qt = 0; qt < 8; qt++) { Oacc[qt] = (f32x4){0.f,0.f,0.f,0.f}; lsum[qt] = 0.f; }

    const float cexp = 0.25f * 1.44269504088896f;   // scale * log2(e)

    for (int kt = 0; kt < 16; kt++) {               // 32 keys per iteration
        const bf16* k0p = (g < 2) ? (Ks + (kt * 32 + p0)     * 16 + g * 8) : zp;
        const bf16* k1p = (g < 2) ? (Ks + (kt * 32 + p0 + 4) * 16 + g * 8) : zp;
        bf16x8 kf0 = *(const bf16x8*)k0p;
        bf16x8 kf1 = *(const bf16x8*)k1p;
        bf16x8 vf  = *(const bf16x8*)(Vt + l4 * 520 + kt * 32 + g * 8);

        #pragma unroll
        for (int qt = 0; qt < 8; qt++) {
            f32x4 z = (f32x4){0.f,0.f,0.f,0.f};
            f32x4 s0 = MFMA16(kf0, qf[qt], z);
            f32x4 s1 = MFMA16(kf1, qf[qt], z);
            float e[8];
            #pragma unroll
            for (int r = 0; r < 4; r++) {
                e[r]     = exp2f(s0[r] * cexp);
                e[4 + r] = exp2f(s1[r] * cexp);
            }
            lsum[qt] += ((e[0]+e[1])+(e[2]+e[3])) + ((e[4]+e[5])+(e[6]+e[7]));
            bf16x8 pf;
            #pragma unroll
            for (int i = 0; i < 8; i++) pf[i] = f2bs(e[i]);
            Oacc[qt] = MFMA16(pf, vf, Oacc[qt]);
        }
    }

    #pragma unroll
    for (int qt = 0; qt < 8; qt++) {
        float ls = lsum[qt];
        ls += __shfl_xor(ls, 16);
        ls += __shfl_xor(ls, 32);
        #pragma unroll
        for (int r = 0; r < 4; r++) {
            float lq = __shfl(ls, g * 4 + r);
            float o = Oacc[qt][r] / lq;
            int qrow = t * 512 + qbase + qt * 16 + g * 4 + r;
            C[(size_t)qrow * 128 + h * 16 + l4] = __float2bfloat16(o);
        }
    }
}

// ---------------------------------------------------------------------------
// FUSED stage-3 per-n kernel: banded attention (window j in [i-7,i]) +
// out_proj MFMA + bias + residual + LayerNorm. One block per n (512 blocks),
// 256 threads. Context tile [32 tok][128] kept in swizzled LDS.
// In-place Y==R is safe (each element's residual read precedes its write).
// ---------------------------------------------------------------------------
__global__ __launch_bounds__(256) void attn_banded_oln(
    const bf16* __restrict__ Qkv,    // [TOK,384] (q at 0, k at +128)
    const bf16* __restrict__ Vb,     // [TOK,128]
    const bf16* __restrict__ Wo,     // [128,128]
    const float* __restrict__ ob,    // [128]
    const bf16* __restrict__ R,      // residual [TOK,128]
    const float* __restrict__ lng, const float* __restrict__ lnb,
    bf16* __restrict__ Y)            // [TOK,128] (may alias R)
{
    __shared__ float Qs[TT][129];
    __shared__ float Ksh[TT][129];
    __shared__ float Vs[TT][129];
    __shared__ bf16 Ctx[32 * 128];   // swizzled
    __shared__ float rsum[32][2];
    __shared__ float rsq[32][2];

    const int n = blockIdx.x;
    const int tid = threadIdx.x;

    for (int e = tid; e < TT * DD; e += 256) {
        int t = e >> 7, d = e & 127;
        const bf16* row = Qkv + (size_t)(t * NN + n) * 384;
        Qs[t][d]  = __bfloat162float(row[d]);
        Ksh[t][d] = __bfloat162float(row[128 + d]);
        Vs[t][d]  = __bfloat162float(Vb[(size_t)(t * NN + n) * DD + d]);
    }
    __syncthreads();

    // ---- banded attention (8 heads x 32 queries) -> Ctx LDS ----
    {
        const int h = tid >> 5, i = tid & 31;
        const int hb = h * DH;

        float s[WND_];
        #pragma unroll
        for (int kk = 0; kk < WND_; kk++) {
            int j = i - (WND_ - 1) + kk;
            int jc = j < 0 ? 0 : j;
            float d = 0.f;
            #pragma unroll
            for (int f = 0; f < DH; f++) d += Qs[i][hb + f] * Ksh[jc][hb + f];
            s[kk] = (j >= 0) ? d * 0.25f : -1e30f;
        }
        float m = s[0];
        #pragma unroll
        for (int kk = 1; kk < WND_; kk++) m = fmaxf(m, s[kk]);
        float l = 0.f, p[WND_];
        #pragma unroll
        for (int kk = 0; kk < WND_; kk++) { p[kk] = __expf(s[kk] - m); l += p[kk]; }
        float inv = 1.f / l;
        float acc[DH] = {};
        #pragma unroll
        for (int kk = 0; kk < WND_; kk++) {
            int j = i - (WND_ - 1) + kk;
            int jc = j < 0 ? 0 : j;
            float pw = p[kk] * inv;
            #pragma unroll
            for (int f = 0; f < DH; f++) acc[f] += pw * Vs[jc][hb + f];
        }
        union { unsigned short s16[16]; uint4 u[2]; } pk;
        #pragma unroll
        for (int f = 0; f < DH; f++) pk.s16[f] = (unsigned short)f2bs(acc[f]);
        const int base = i * 256 + hb * 2;         // byte offset, 32B aligned
        const int sx = (i & 7) << 4;
        *(uint4*)((char*)Ctx + ((base)      ^ sx)) = pk.u[0];
        *(uint4*)((char*)Ctx + ((base + 16) ^ sx)) = pk.u[1];
    }
    __syncthreads();

    // ---- out_proj: [32,128] @ Wo[128,128]^T, 4 waves 2x2 (16 rows x 64 cols) ----
    const int lane = tid & 63;
    const int wv   = tid >> 6;
    const int wm = wv >> 1, wn = wv & 1;
    const int l4 = lane & 15, g = lane >> 4;

    f32x4 acc2[4];
    #pragma unroll
    for (int n2 = 0; n2 < 4; n2++) acc2[n2] = (f32x4){0.f, 0.f, 0.f, 0.f};

    const int arow = wm * 16 + l4;
    const int axor = (arow & 7) << 4;
    #pragma unroll
    for (int ks = 0; ks < 4; ks++) {
        bf16x8 a = *(const bf16x8*)((const char*)Ctx + ((arow * 256 + ks * 64 + g * 16) ^ axor));
        #pragma unroll
        for (int n2 = 0; n2 < 4; n2++) {
            const int col = wn * 64 + n2 * 16 + l4;
            bf16x8 w = *(const bf16x8*)(Wo + (size_t)col * 128 + ks * 32 + g * 8);
            acc2[n2] = MFMA16(a, w, acc2[n2]);
        }
    }

    // ---- bias + residual + LN epilogue (rows = local tokens 0..31) ----
    float vv[4][4];
    #pragma unroll
    for (int n2 = 0; n2 < 4; n2++) {
        const int col = wn * 64 + n2 * 16 + l4;
        const float bv = ob[col];
        #pragma unroll
        for (int r = 0; r < 4; r++) {
            const int tloc = wm * 16 + g * 4 + r;
            vv[n2][r] = acc2[n2][r] + bv
                      + __bfloat162float(R[(size_t)(tloc * NN + n) * 128 + col]);
        }
    }

    #pragma unroll
    for (int r = 0; r < 4; r++) {
        float sm = 0.f, qs = 0.f;
        #pragma unroll
        for (int n2 = 0; n2 < 4; n2++) { float v = vv[n2][r]; sm += v; qs += v * v; }
        #pragma unroll
        for (int off = 1; off < 16; off <<= 1) {
            sm += __shfl_xor(sm, off);
            qs += __shfl_xor(qs, off);
        }
        const int tloc = wm * 16 + g * 4 + r;
        if (l4 == 0) { rsum[tloc][wn] = sm; rsq[tloc][wn] = qs; }
    }
    __syncthreads();

    #pragma unroll
    for (int r = 0; r < 4; r++) {
        const int tloc = wm * 16 + g * 4 + r;
        const float S = rsum[tloc][0] + rsum[tloc][1];
        const float Q = rsq[tloc][0] + rsq[tloc][1];
        const float mean = S * (1.0f / 128.0f);
        const float var  = Q * (1.0f / 128.0f) - mean * mean;
        const float rstd = rsqrtf(var + 1e-5f);
        #pragma unroll
        for (int n2 = 0; n2 < 4; n2++) {
            const int col = wn * 64 + n2 * 16 + l4;
            const float y = (vv[n2][r] - mean) * rstd * lng[col] + lnb[col];
            Y[(size_t)(tloc * NN + n) * 128 + col] = __float2bfloat16(y);
        }
    }
}

// ---------------------------------------------------------------------------
// time2vec add: Y = bf16(x + tbl[t, d])
// ---------------------------------------------------------------------------
__global__ __launch_bounds__(256) void t2v_add_kernel(
    const float* __restrict__ x, const float* __restrict__ tbl, bf16* __restrict__ Y)
{
    int i = blockIdx.x * 256 + threadIdx.x;     // float4 groups
    int e = i * 4;
    float4 xv = ((const float4*)x)[i];
    int ti = ((e >> 16) << 7) | (e & 127);
    float4 tv = *(const float4*)(tbl + ti);
    ushort4 o;
    o.x = (unsigned short)f2bs(xv.x + tv.x);
    o.y = (unsigned short)f2bs(xv.y + tv.y);
    o.z = (unsigned short)f2bs(xv.z + tv.z);
    o.w = (unsigned short)f2bs(xv.w + tv.w);
    *(ushort4*)((unsigned short*)Y + e) = o;
}

// ---------------------------------------------------------------------------

extern "C" void kernel_launch(void* const* d_in, const int* in_sizes, int n_in,
                              void* d_out, int out_size, void* d_ws, size_t ws_size,
                              hipStream_t stream) {
    const float* x           = (const float*)d_in[0];
    const float* enc_in_w    = (const float*)d_in[1];
    const float* enc_in_b    = (const float*)d_in[2];
    const float* enc_out_w   = (const float*)d_in[3];
    const float* enc_out_b   = (const float*)d_in[4];
    const float* enc_l1w     = (const float*)d_in[5];
    const float* enc_l1b     = (const float*)d_in[6];
    const float* enc_l2w     = (const float*)d_in[7];
    const float* enc_l2b     = (const float*)d_in[8];
    const float* enc_ln1w    = (const float*)d_in[9];
    const float* enc_ln1b    = (const float*)d_in[10];
    const float* enc_ln2w    = (const float*)d_in[11];
    const float* enc_ln2b    = (const float*)d_in[12];
    const float* qk_in_w     = (const float*)d_in[13];
    const float* qk_in_b     = (const float*)d_in[14];
    const float* qk_out_w    = (const float*)d_in[15];
    const float* qk_out_b    = (const float*)d_in[16];
    const float* qk_l1w      = (const float*)d_in[17];
    const float* qk_l1b      = (const float*)d_in[18];
    const float* qk_l2w      = (const float*)d_in[19];
    const float* qk_l2b      = (const float*)d_in[20];
    const float* qk_ln1w     = (const float*)d_in[21];
    const float* qk_ln1b     = (const float*)d_in[22];
    const float* qk_ln2w     = (const float*)d_in[23];
    const float* qk_ln2b     = (const float*)d_in[24];
    const float* t2v_w       = (const float*)d_in[25];
    const float* t2v_b       = (const float*)d_in[26];
    const float* t2v_w0      = (const float*)d_in[27];
    const float* t2v_b0      = (const float*)d_in[28];
    const float* out_w       = (const float*)d_in[29];
    float* out = (float*)d_out;

    // ---------------- workspace layout (bytes) ------------------------------
    char* ws = (char*)d_ws;
    const size_t TOKD = (size_t)TOK * DD;
    size_t off = 0;
    auto alloc = [&](size_t bytes) { char* p = ws + off; off += (bytes + 255) & ~(size_t)255; return p; };

    bf16*  Qb   = (bf16*)alloc((size_t)TOK * 384 * 2);   // qkv bf16
    bf16*  Vb   = (bf16*)alloc(TOKD * 2);                // v-projection bf16
    bf16*  xb   = (bf16*)alloc(TOKD * 2);                // bf16 copy of x
    bf16*  bufA = (bf16*)alloc(TOKD * 2);                // residual stream bf16
    bf16*  Zb   = (bf16*)alloc(TOKD * 2);                // outs_zs bf16
    bf16*  Cb   = (bf16*)alloc(TOKD * 2);                // attn context bf16 (stage 1)
    float* t2vt = (float*)alloc((size_t)TT * DD * 4);    // time2vec table
    bf16* enc_in_wb  = (bf16*)alloc(384 * DD * 2);
    bf16* enc_out_wb = (bf16*)alloc(DD * DD * 2);
    bf16* enc_l1wb   = (bf16*)alloc((size_t)FF_ * DD * 2);
    bf16* enc_l2wb   = (bf16*)alloc((size_t)DD * FF_ * 2);
    bf16* qk_in_wb   = (bf16*)alloc((size_t)LL * 384 * DD * 2);
    bf16* qk_out_wb  = (bf16*)alloc((size_t)LL * DD * DD * 2);
    bf16* qk_l1wb    = (bf16*)alloc((size_t)LL * FF_ * DD * 2);
    bf16* qk_l2wb    = (bf16*)alloc((size_t)LL * DD * FF_ * 2);

    // ---------------- one-shot conversion of all weights + x + t2v table ----
    ConvDesc cd;
    cd.x  = x;        cd.dx = xb;
    cd.s1 = enc_in_w; cd.d1 = enc_in_wb;
    cd.s2 = enc_out_w;cd.d2 = enc_out_wb;
    cd.s3 = enc_l1w;  cd.d3 = enc_l1wb;
    cd.s4 = enc_l2w;  cd.d4 = enc_l2wb;
    cd.s5 = qk_in_w;  cd.d5 = qk_in_wb;
    cd.s6 = qk_out_w; cd.d6 = qk_out_wb;
    cd.s7 = qk_l1w;   cd.d7 = qk_l1wb;
    cd.s8 = qk_l2w;   cd.d8 = qk_l2wb;
    cd.w = t2v_w; cd.b = t2v_b; cd.w0 = t2v_w0; cd.b0 = t2v_b0; cd.tbl = t2vt;
    conv_all_kernel<<<(CP9 + 255) / 256, 256, 0, stream>>>(cd);

    auto gemm128 = [&](const bf16* A, int lda, const bf16* W, const float* bias,
                       bf16* C, int ldc, int M, int N, int K, int relu) {
        dim3 grid(N / 128, M / 128);
        mfma_gemm<128, 128><<<grid, 256, 0, stream>>>(A, lda, W, bias, C, ldc, K, relu);
    };
    auto gemm_ln = [&](const bf16* A, int lda, const bf16* W, const float* bias,
                       const bf16* R, const float* lng, const float* lnb,
                       bf16* Y, int M, int K) {
        mfma_gemm_ln<<<M / 64, 256, 0, stream>>>(A, lda, W, bias, R, lng, lnb, Y, K);
    };

    // ---------------- stage 1: plain encoder (attend over N, batch T) -------
    gemm128(xb, DD, enc_in_wb, enc_in_b, Qb, 384, TOK, 384, DD, 0);
    attn_full_mfma<<<TT * HH, 256, 0, stream>>>(Qb, Cb);
    gemm_ln(Cb, DD, enc_out_wb, enc_out_b, xb, enc_ln1w, enc_ln1b, bufA, TOK, DD);
    ffn_fused<false><<<TOK / 64, 1024, 0, stream>>>(
        bufA, enc_l1wb, enc_l1b, enc_l2wb, enc_l2b,
        enc_ln2w, enc_ln2b, Zb, nullptr, nullptr);

    // ---------------- stage 2: time2vec -------------------------------------
    t2v_add_kernel<<<(TOK * DD / 4) / 256, 256, 0, stream>>>(x, t2vt, bufA);

    // ---------------- stage 3: qk encoder stack (banded window attn) ---------
    for (int l = 0; l < LL; l++) {
        const bf16* iw   = qk_in_wb  + (size_t)l * 384 * DD;
        const float* ib  = qk_in_b   + (size_t)l * 384;
        const bf16* owt  = qk_out_wb + (size_t)l * DD * DD;
        const float* ob  = qk_out_b  + (size_t)l * DD;
        const bf16* l1w  = qk_l1wb   + (size_t)l * FF_ * DD;
        const float* l1b = qk_l1b    + (size_t)l * FF_;
        const bf16* l2w  = qk_l2wb   + (size_t)l * DD * FF_;
        const float* l2b = qk_l2b    + (size_t)l * DD;

        // merged q,k (from bufA) + v (from Zb) projection: one dispatch
        qkv_proj<<<dim3(3, TOK / 128), 256, 0, stream>>>(bufA, Zb, iw, ib, Qb, Vb);
        // fused banded attn + out_proj + residual + LN (in-place on bufA)
        attn_banded_oln<<<NN, 256, 0, stream>>>(Qb, Vb, owt, ob, bufA,
                                                qk_ln1w + l * DD, qk_ln1b + l * DD, bufA);
        if (l == LL - 1) {
            ffn_fused<true><<<TOK / 64, 1024, 0, stream>>>(
                bufA, l1w, l1b, l2w, l2b,
                qk_ln2w + l * DD, qk_ln2b + l * DD, nullptr, out_w, out);
        } else {
            ffn_fused<false><<<TOK / 64, 1024, 0, stream>>>(
                bufA, l1w, l1b, l2w, l2b,
                qk_ln2w + l * DD, qk_ln2b + l * DD, bufA, nullptr, nullptr);
        }
    }
}